// Round 2
// baseline (800.791 us; speedup 1.0000x reference)
//
#include <hip/hip_runtime.h>
#include <hip/hip_bf16.h>

constexpr int B = 2;
constexpr int L = 2048;
constexpr int DIN = 80;
constexpr int DM = 512;
constexpr int DI = 1024;
constexpr int DS = 64;
constexpr int KC = 7;
constexpr int HD = 64;
constexpr int NH = 16;                    // DI/HD
constexpr int CONVC = DI + 2 * DS;        // 1152
constexpr int DPROJ = 2 * DI + 2 * DS + NH; // 2192
constexpr int BL = B * L;                 // 4096
constexpr int CHUNK = 64;
constexpr int NC = L / CHUNK;             // 32
constexpr int NG = 2 * B * NH;            // 64 scan groups (dir,b,head)

// ---------------- fp32 tiled GEMM with bias: C[M,N] = A[M,K]*Bm[K,N] + bias[N]
constexpr int GBM = 128, GBN = 128, GBK = 16;

__global__ __launch_bounds__(256) void gemm_bias(
    const float* __restrict__ A, const float* __restrict__ Bm,
    const float* __restrict__ bias, float* __restrict__ C,
    int M, int N, int K) {
  __shared__ float As[GBK][GBM + 4];
  __shared__ float Bs[GBK][GBN + 4];
  const int m0 = blockIdx.x * GBM;
  const int n0 = blockIdx.y * GBN;
  const int tid = threadIdx.x;
  const int tm = tid >> 4, tn = tid & 15;
  float acc[8][8] = {};
  const int arow = tid >> 2, acol = (tid & 3) << 2;   // A: 64 rows x 16 cols per pass
  const int brow = tid >> 5, bcol = (tid & 31) << 2;  // B: 8 rows x 128 cols per pass
  for (int k0 = 0; k0 < K; k0 += GBK) {
#pragma unroll
    for (int r = 0; r < 2; ++r) {
      int m = m0 + arow + r * 64;
      float4 v = make_float4(0.f, 0.f, 0.f, 0.f);
      if (m < M) v = *(const float4*)(A + (size_t)m * K + k0 + acol);
      As[acol + 0][arow + r * 64] = v.x;
      As[acol + 1][arow + r * 64] = v.y;
      As[acol + 2][arow + r * 64] = v.z;
      As[acol + 3][arow + r * 64] = v.w;
    }
#pragma unroll
    for (int r = 0; r < 2; ++r) {
      int kk = brow + r * 8;
      int n = n0 + bcol;
      float4 v = make_float4(0.f, 0.f, 0.f, 0.f);
      if (n < N) v = *(const float4*)(Bm + (size_t)(k0 + kk) * N + n);
      *(float4*)&Bs[kk][bcol] = v;
    }
    __syncthreads();
#pragma unroll
    for (int k = 0; k < GBK; ++k) {
      float a[8], bb[8];
#pragma unroll
      for (int i = 0; i < 8; ++i) a[i] = As[k][tm * 8 + i];
#pragma unroll
      for (int j = 0; j < 8; ++j) bb[j] = Bs[k][tn * 8 + j];
#pragma unroll
      for (int i = 0; i < 8; ++i)
#pragma unroll
        for (int j = 0; j < 8; ++j)
          acc[i][j] = fmaf(a[i], bb[j], acc[i][j]);
    }
    __syncthreads();
  }
#pragma unroll
  for (int i = 0; i < 8; ++i) {
    int m = m0 + tm * 8 + i;
    if (m >= M) continue;
#pragma unroll
    for (int j = 0; j < 8; ++j) {
      int n = n0 + tn * 8 + j;
      if (n < N) C[(size_t)m * N + n] = acc[i][j] + bias[n];
    }
  }
}

// ---------------- conv (both directions) + silu ----------------
// xconv[dir][b][s][c] in SCAN order for each direction.
__global__ void prep_conv(const float* __restrict__ zx, const float* __restrict__ cw,
                          const float* __restrict__ cb, float* __restrict__ xconv) {
  const int idx = blockIdx.x * 256 + threadIdx.x;
  if (idx >= 2 * BL * CONVC) return;
  const int c = idx % CONVC;
  int rest = idx / CONVC;
  const int s = rest % L;
  rest /= L;
  const int bb = rest % B;
  const int d = rest / B;
  float acc = cb[c];
  if (d == 0) {
#pragma unroll
    for (int k = 0; k < KC; ++k) {
      const int t = s - (KC - 1) + k;
      if (t >= 0) acc = fmaf(cw[c * KC + k], zx[((size_t)(bb * L + t)) * DPROJ + DI + c], acc);
    }
  } else {
    const int torig = L - 1 - s;
#pragma unroll
    for (int j = 0; j < KC; ++j) {
      const int t = torig + j;
      if (t < L) acc = fmaf(cw[c * KC + (KC - 1 - j)], zx[((size_t)(bb * L + t)) * DPROJ + DI + c], acc);
    }
  }
  xconv[idx] = acc / (1.f + expf(-acc));  // silu
}

// ---------------- dt / dA (scan order per direction) ----------------
__global__ void prep_dt(const float* __restrict__ zx, const float* __restrict__ dt_bias,
                        const float* __restrict__ A_log, float* __restrict__ dtb,
                        float* __restrict__ dab) {
  const int idx = blockIdx.x * 256 + threadIdx.x;
  if (idx >= 2 * BL * NH) return;
  const int h = idx % NH;
  int rest = idx / NH;
  const int s = rest % L;
  rest /= L;
  const int bb = rest % B;
  const int d = rest / B;
  const int torig = d ? (L - 1 - s) : s;
  const float raw = zx[((size_t)(bb * L + torig)) * DPROJ + DI + CONVC + h] + dt_bias[h];
  const float dt = (raw > 20.f) ? raw : log1pf(expf(raw));
  dtb[idx] = dt;
  dab[idx] = expf(-expf(A_log[h]) * dt);
}

// ---------------- scan phase A: per-chunk local final state + decay product ----
__global__ __launch_bounds__(64) void scan_phaseA(
    const float* __restrict__ xconv, const float* __restrict__ dtb,
    const float* __restrict__ dab, float* __restrict__ Sbuf,
    float* __restrict__ Pbuf) {
  const int g = blockIdx.x;   // (d*B+b)*NH + h
  const int c = blockIdx.y;   // chunk
  const int lane = threadIdx.x; // p
  const int hh = g % NH;
  const int db = g / NH;      // d*B+b
  float S[DS];
#pragma unroll
  for (int n = 0; n < DS; ++n) S[n] = 0.f;
  float P = 1.f;
  const float* xbase = xconv + (size_t)db * L * CONVC;
  for (int i = 0; i < CHUNK; ++i) {
    const int s = c * CHUNK + i;
    const float* row = xbase + (size_t)s * CONVC;
    const float xv = row[hh * HD + lane];
    const int di = (db * L + s) * NH + hh;
    const float dtv = dtb[di];
    const float dav = dab[di];
    P *= dav;
    const float a = dtv * xv;
    const float* Bt = row + DI;
#pragma unroll
    for (int n = 0; n < DS; ++n) S[n] = dav * S[n] + a * Bt[n];
  }
  float* o = Sbuf + (((size_t)g * NC + c) * HD + lane) * DS;
#pragma unroll
  for (int n = 0; n < DS; ++n) o[n] = S[n];
  if (lane == 0) Pbuf[g * NC + c] = P;
}

// ---------------- chain: turn local states into incoming states (in-place) ----
__global__ void scan_chain(float* __restrict__ Sbuf, const float* __restrict__ Pbuf) {
  const int idx = blockIdx.x * 256 + threadIdx.x;  // g*4096 + e
  const int g = idx >> 12;
  const int e = idx & 4095;
  float run = 0.f;
  float* base = Sbuf + (size_t)g * NC * 4096 + e;
  for (int c = 0; c < NC; ++c) {
    const float sc = base[(size_t)c * 4096];
    const float pc = Pbuf[g * NC + c];
    base[(size_t)c * 4096] = run;
    run = pc * run + sc;
  }
}

// ---------------- scan phase C: replay chunk with incoming state, emit y -------
__global__ __launch_bounds__(64) void scan_phaseC(
    const float* __restrict__ xconv, const float* __restrict__ dtb,
    const float* __restrict__ dab, const float* __restrict__ Dpar,
    const float* __restrict__ Sbuf, float* __restrict__ yraw) {
  const int g = blockIdx.x;
  const int c = blockIdx.y;
  const int lane = threadIdx.x;
  const int hh = g % NH;
  const int db = g / NH;
  float S[DS];
  const float* in = Sbuf + (((size_t)g * NC + c) * HD + lane) * DS;
#pragma unroll
  for (int n = 0; n < DS; ++n) S[n] = in[n];
  const float dp = Dpar[hh];
  const float* xbase = xconv + (size_t)db * L * CONVC;
  for (int i = 0; i < CHUNK; ++i) {
    const int s = c * CHUNK + i;
    const float* row = xbase + (size_t)s * CONVC;
    const float xv = row[hh * HD + lane];
    const int di = (db * L + s) * NH + hh;
    const float dtv = dtb[di];
    const float dav = dab[di];
    const float a = dtv * xv;
    const float* Bt = row + DI;
    const float* Ct = row + DI + DS;
    float acc = 0.f;
#pragma unroll
    for (int n = 0; n < DS; ++n) {
      S[n] = dav * S[n] + a * Bt[n];
      acc = fmaf(S[n], Ct[n], acc);
    }
    yraw[((size_t)db * L + s) * DI + hh * HD + lane] = acc + dp * xv;
  }
}

// ---------------- gate (silu(z)) + per-dir RMSNorm + sum dirs -------------------
__global__ __launch_bounds__(256) void gate_norm(
    const float* __restrict__ zx, const float* __restrict__ yraw,
    const float* __restrict__ nw, float* __restrict__ ycomb) {
  const int bt = blockIdx.x;   // b*L + t (original time order)
  const int b = bt / L, t = bt % L;
  const int tid = threadIdx.x;
  const float* z = zx + (size_t)bt * DPROJ;
  const float* y0 = yraw + ((size_t)b * L + t) * DI;                  // fwd dir, s=t
  const float* y1 = yraw + ((size_t)(B + b) * L + (L - 1 - t)) * DI;  // bwd dir, s=L-1-t
  float a0[4], a1[4];
  float s0 = 0.f, s1 = 0.f;
#pragma unroll
  for (int r = 0; r < 4; ++r) {
    const int cc = r * 256 + tid;
    const float zv = z[cc];
    const float gz = zv / (1.f + expf(-zv));
    a0[r] = y0[cc] * gz;
    a1[r] = y1[cc] * gz;
    s0 += a0[r] * a0[r];
    s1 += a1[r] * a1[r];
  }
#pragma unroll
  for (int off = 32; off > 0; off >>= 1) {
    s0 += __shfl_down(s0, off);
    s1 += __shfl_down(s1, off);
  }
  __shared__ float rs0[4], rs1[4];
  const int w = tid >> 6;
  if ((tid & 63) == 0) { rs0[w] = s0; rs1[w] = s1; }
  __syncthreads();
  s0 = rs0[0] + rs0[1] + rs0[2] + rs0[3];
  s1 = rs1[0] + rs1[1] + rs1[2] + rs1[3];
  const float r0 = rsqrtf(s0 * (1.f / DI) + 1e-5f);
  const float r1 = rsqrtf(s1 * (1.f / DI) + 1e-5f);
  float* oc = ycomb + (size_t)bt * DI;
#pragma unroll
  for (int r = 0; r < 4; ++r) {
    const int cc = r * 256 + tid;
    oc[cc] = nw[cc] * (a0[r] * r0 + a1[r] * r1);
  }
}

// ---------------- fold W_out @ Wp_out -> Wc (1024x80) --------------------------
__global__ void fuse_out(const float* __restrict__ Wo, const float* __restrict__ Wpo,
                         float* __restrict__ Wc) {
  const int idx = blockIdx.x * 256 + threadIdx.x;
  if (idx >= DI * DIN) return;
  const int c = idx / DIN, d = idx % DIN;
  float acc = 0.f;
  for (int m = 0; m < DM; ++m)
    acc = fmaf(Wo[(size_t)c * DM + m], Wpo[(size_t)m * DIN + d], acc);
  Wc[idx] = acc;
}

extern "C" void kernel_launch(void* const* d_in, const int* in_sizes, int n_in,
                              void* d_out, int out_size, void* d_ws, size_t ws_size,
                              hipStream_t stream) {
  const float* x       = (const float*)d_in[0];
  const float* Wp_in   = (const float*)d_in[1];
  const float* bp_in   = (const float*)d_in[2];
  const float* W_in    = (const float*)d_in[3];
  const float* b_in    = (const float*)d_in[4];
  const float* conv_w  = (const float*)d_in[5];
  const float* conv_b  = (const float*)d_in[6];
  const float* dt_bias = (const float*)d_in[7];
  const float* A_log   = (const float*)d_in[8];
  const float* Dpar    = (const float*)d_in[9];
  const float* norm_w  = (const float*)d_in[10];
  const float* W_out   = (const float*)d_in[11];
  const float* Wp_out  = (const float*)d_in[12];
  const float* bp_out  = (const float*)d_in[13];
  float* out = (float*)d_out;

  float* W = (float*)d_ws;
  float* h     = W;                                   // BL*DM
  float* zx    = h + (size_t)BL * DM;                 // BL*DPROJ
  float* xconv = zx + (size_t)BL * DPROJ;             // 2*BL*CONVC
  float* dtb   = xconv + (size_t)2 * BL * CONVC;      // 2*BL*NH
  float* dab   = dtb + (size_t)2 * BL * NH;           // 2*BL*NH
  float* Sbuf  = dab + (size_t)2 * BL * NH;           // NG*NC*HD*DS
  float* Pbuf  = Sbuf + (size_t)NG * NC * HD * DS;    // NG*NC
  float* yraw  = Pbuf + (size_t)NG * NC;              // 2*BL*DI
  float* ycomb = yraw + (size_t)2 * BL * DI;          // BL*DI
  float* Wc    = ycomb + (size_t)BL * DI;             // DI*DIN
  (void)ws_size; (void)in_sizes; (void)n_in; (void)out_size;

  // 1. h = x @ Wp_in + bp_in
  gemm_bias<<<dim3(BL / GBM, (DM + GBN - 1) / GBN), 256, 0, stream>>>(
      x, Wp_in, bp_in, h, BL, DM, DIN);
  // 2. zxbcdt = h @ W_in + b_in  (shared by both directions)
  gemm_bias<<<dim3(BL / GBM, (DPROJ + GBN - 1) / GBN), 256, 0, stream>>>(
      h, W_in, b_in, zx, BL, DPROJ, DM);
  // 3. conv + silu for both directions; dt/dA
  prep_conv<<<(2 * BL * CONVC + 255) / 256, 256, 0, stream>>>(zx, conv_w, conv_b, xconv);
  prep_dt<<<(2 * BL * NH + 255) / 256, 256, 0, stream>>>(zx, dt_bias, A_log, dtb, dab);
  // 4. chunked scan
  scan_phaseA<<<dim3(NG, NC), 64, 0, stream>>>(xconv, dtb, dab, Sbuf, Pbuf);
  scan_chain<<<(NG * HD * DS) / 256, 256, 0, stream>>>(Sbuf, Pbuf);
  scan_phaseC<<<dim3(NG, NC), 64, 0, stream>>>(xconv, dtb, dab, Dpar, Sbuf, yraw);
  // 5. gate + RMSNorm + combine directions
  gate_norm<<<BL, 256, 0, stream>>>(zx, yraw, norm_w, ycomb);
  // 6. Wc = W_out @ Wp_out
  fuse_out<<<(DI * DIN + 255) / 256, 256, 0, stream>>>(W_out, Wp_out, Wc);
  // 7. out = ycomb @ Wc + bp_out
  gemm_bias<<<dim3(BL / GBM, (DIN + GBN - 1) / GBN), 256, 0, stream>>>(
      ycomb, Wc, bp_out, out, BL, DIN, DI);
}

// Round 3
// 647.144 us; speedup vs baseline: 1.2374x; 1.2374x over previous
//
#include <hip/hip_runtime.h>
#include <hip/hip_bf16.h>

constexpr int B = 2;
constexpr int L = 2048;
constexpr int DIN = 80;
constexpr int DM = 512;
constexpr int DI = 1024;
constexpr int DS = 64;
constexpr int KC = 7;
constexpr int HD = 64;
constexpr int NH = 16;                    // DI/HD
constexpr int CONVC = DI + 2 * DS;        // 1152
constexpr int DPROJ = 2 * DI + 2 * DS + NH; // 2192
constexpr int NPAD = 2304;                // DPROJ padded to 18*128
constexpr int BL = B * L;                 // 4096
constexpr int CHUNK = 64;
constexpr int NC = L / CHUNK;             // 32
constexpr int NG = 2 * B * NH;            // 64 scan groups (dir,b,head)

typedef __attribute__((ext_vector_type(8))) short bf16x8;
typedef __attribute__((ext_vector_type(4))) float f32x4;

// ---------------- fp32 tiled GEMM with bias: C[M,N] = A[M,K]*Bm[K,N] + bias[N]
constexpr int GBM = 128, GBN = 128, GBK = 16;

template <typename OutT>
__global__ __launch_bounds__(256) void gemm_bias(
    const float* __restrict__ A, const float* __restrict__ Bm,
    const float* __restrict__ bias, OutT* __restrict__ C,
    int M, int N, int K) {
  __shared__ float As[GBK][GBM + 4];
  __shared__ float Bs[GBK][GBN + 4];
  const int m0 = blockIdx.x * GBM;
  const int n0 = blockIdx.y * GBN;
  const int tid = threadIdx.x;
  const int tm = tid >> 4, tn = tid & 15;
  float acc[8][8] = {};
  const int arow = tid >> 2, acol = (tid & 3) << 2;   // A: 64 rows x 16 cols per pass
  const int brow = tid >> 5, bcol = (tid & 31) << 2;  // B: 8 rows x 128 cols per pass
  for (int k0 = 0; k0 < K; k0 += GBK) {
#pragma unroll
    for (int r = 0; r < 2; ++r) {
      int m = m0 + arow + r * 64;
      float4 v = make_float4(0.f, 0.f, 0.f, 0.f);
      if (m < M) v = *(const float4*)(A + (size_t)m * K + k0 + acol);
      As[acol + 0][arow + r * 64] = v.x;
      As[acol + 1][arow + r * 64] = v.y;
      As[acol + 2][arow + r * 64] = v.z;
      As[acol + 3][arow + r * 64] = v.w;
    }
#pragma unroll
    for (int r = 0; r < 2; ++r) {
      int kk = brow + r * 8;
      int n = n0 + bcol;
      float4 v = make_float4(0.f, 0.f, 0.f, 0.f);
      if (n < N) v = *(const float4*)(Bm + (size_t)(k0 + kk) * N + n);
      *(float4*)&Bs[kk][bcol] = v;
    }
    __syncthreads();
#pragma unroll
    for (int k = 0; k < GBK; ++k) {
      float a[8], bb[8];
#pragma unroll
      for (int i = 0; i < 8; ++i) a[i] = As[k][tm * 8 + i];
#pragma unroll
      for (int j = 0; j < 8; ++j) bb[j] = Bs[k][tn * 8 + j];
#pragma unroll
      for (int i = 0; i < 8; ++i)
#pragma unroll
        for (int j = 0; j < 8; ++j)
          acc[i][j] = fmaf(a[i], bb[j], acc[i][j]);
    }
    __syncthreads();
  }
#pragma unroll
  for (int i = 0; i < 8; ++i) {
    int m = m0 + tm * 8 + i;
    if (m >= M) continue;
#pragma unroll
    for (int j = 0; j < 8; ++j) {
      int n = n0 + tn * 8 + j;
      if (n < N) C[(size_t)m * N + n] = (OutT)(acc[i][j] + bias[n]);
    }
  }
}

// ---------------- W_in -> transposed, padded bf16 [NPAD][DM] --------------------
__global__ void prep_wt(const float* __restrict__ W_in, __hip_bfloat16* __restrict__ Wt) {
  const int idx = blockIdx.x * 256 + threadIdx.x;
  if (idx >= NPAD * DM) return;
  const int n = idx % NPAD;
  const int k = idx / NPAD;
  const float v = (n < DPROJ) ? W_in[(size_t)k * DPROJ + n] : 0.f;
  Wt[(size_t)n * DM + k] = (__hip_bfloat16)v;
}

// ---------------- bf16 MFMA GEMM: C[M,N] = A[M,K] * Bt[N,K]^T + bias -----------
// A: bf16 [M][K] row-major; Bt: bf16 [>=N][K] row-major (B transposed, padded).
// 128x128 tile, 4 waves in 2x2, each wave 64x64 via 4x4 frags of 16x16x32.
// LDS layout [ks][row][8] (ks = k-octet 0..3): linear in lane order for
// global_load_lds (t = chunk*64+lane -> ks=t>>7, row=t&127) AND ~conflict-free
// for ds_read_b128 fragment reads (16 consecutive rows x 16B = 256B contiguous).
__global__ __launch_bounds__(256) void gemm_mfma_bt(
    const __hip_bfloat16* __restrict__ A, const __hip_bfloat16* __restrict__ Bt,
    const float* __restrict__ bias, float* __restrict__ C,
    int M, int N, int K) {
  __shared__ short As[4 * 128 * 8];
  __shared__ short Bs[4 * 128 * 8];
  const int tid = threadIdx.x;
  const int l = tid & 63;
  const int wv = tid >> 6;
  const int wr = wv >> 1, wc = wv & 1;
  const int m0 = blockIdx.x * 128;
  const int n0 = blockIdx.y * 128;
  const int ks = l >> 4, lr = l & 15;
  f32x4 acc[4][4] = {};
  for (int k0 = 0; k0 < K; k0 += 32) {
#pragma unroll
    for (int i = 0; i < 2; ++i) {
      const int t = (wv * 2 + i) * 64 + l;
      const int tks = t >> 7, trow = t & 127;
      __builtin_amdgcn_global_load_lds(
          (const __attribute__((address_space(1))) unsigned int*)(A + (size_t)(m0 + trow) * K + k0 + tks * 8),
          (__attribute__((address_space(3))) unsigned int*)(As + (size_t)(wv * 2 + i) * 512),
          16, 0, 0);
      __builtin_amdgcn_global_load_lds(
          (const __attribute__((address_space(1))) unsigned int*)(Bt + (size_t)(n0 + trow) * K + k0 + tks * 8),
          (__attribute__((address_space(3))) unsigned int*)(Bs + (size_t)(wv * 2 + i) * 512),
          16, 0, 0);
    }
    __syncthreads();
    bf16x8 af[4], bfr[4];
#pragma unroll
    for (int mi = 0; mi < 4; ++mi)
      af[mi] = *(const bf16x8*)&As[(size_t)(ks * 128 + wr * 64 + mi * 16 + lr) * 8];
#pragma unroll
    for (int ni = 0; ni < 4; ++ni)
      bfr[ni] = *(const bf16x8*)&Bs[(size_t)(ks * 128 + wc * 64 + ni * 16 + lr) * 8];
#pragma unroll
    for (int mi = 0; mi < 4; ++mi)
#pragma unroll
      for (int ni = 0; ni < 4; ++ni)
        acc[mi][ni] = __builtin_amdgcn_mfma_f32_16x16x32_bf16(af[mi], bfr[ni], acc[mi][ni], 0, 0, 0);
    __syncthreads();
  }
#pragma unroll
  for (int mi = 0; mi < 4; ++mi) {
    const int row = m0 + wr * 64 + mi * 16 + (l >> 4) * 4;
#pragma unroll
    for (int ni = 0; ni < 4; ++ni) {
      const int col = n0 + wc * 64 + ni * 16 + lr;
      if (col < N) {
        const float bv = bias[col];
#pragma unroll
        for (int r = 0; r < 4; ++r)
          C[(size_t)(row + r) * N + col] = acc[mi][ni][r] + bv;
      }
    }
  }
}

// ---------------- conv (both directions) + silu ----------------
// xconv[dir][b][s][c] in SCAN order for each direction.
__global__ void prep_conv(const float* __restrict__ zx, const float* __restrict__ cw,
                          const float* __restrict__ cb, float* __restrict__ xconv) {
  const int idx = blockIdx.x * 256 + threadIdx.x;
  if (idx >= 2 * BL * CONVC) return;
  const int c = idx % CONVC;
  int rest = idx / CONVC;
  const int s = rest % L;
  rest /= L;
  const int bb = rest % B;
  const int d = rest / B;
  float acc = cb[c];
  if (d == 0) {
#pragma unroll
    for (int k = 0; k < KC; ++k) {
      const int t = s - (KC - 1) + k;
      if (t >= 0) acc = fmaf(cw[c * KC + k], zx[((size_t)(bb * L + t)) * DPROJ + DI + c], acc);
    }
  } else {
    const int torig = L - 1 - s;
#pragma unroll
    for (int j = 0; j < KC; ++j) {
      const int t = torig + j;
      if (t < L) acc = fmaf(cw[c * KC + (KC - 1 - j)], zx[((size_t)(bb * L + t)) * DPROJ + DI + c], acc);
    }
  }
  xconv[idx] = acc / (1.f + expf(-acc));  // silu
}

// ---------------- dt / dA (scan order per direction) ----------------
__global__ void prep_dt(const float* __restrict__ zx, const float* __restrict__ dt_bias,
                        const float* __restrict__ A_log, float* __restrict__ dtb,
                        float* __restrict__ dab) {
  const int idx = blockIdx.x * 256 + threadIdx.x;
  if (idx >= 2 * BL * NH) return;
  const int h = idx % NH;
  int rest = idx / NH;
  const int s = rest % L;
  rest /= L;
  const int bb = rest % B;
  const int d = rest / B;
  const int torig = d ? (L - 1 - s) : s;
  const float raw = zx[((size_t)(bb * L + torig)) * DPROJ + DI + CONVC + h] + dt_bias[h];
  const float dt = (raw > 20.f) ? raw : log1pf(expf(raw));
  dtb[idx] = dt;
  dab[idx] = expf(-expf(A_log[h]) * dt);
}

// ---------------- scan phase A: per-chunk local final state + decay product ----
__global__ __launch_bounds__(64) void scan_phaseA(
    const float* __restrict__ xconv, const float* __restrict__ dtb,
    const float* __restrict__ dab, float* __restrict__ Sbuf,
    float* __restrict__ Pbuf) {
  const int g = blockIdx.x;   // (d*B+b)*NH + h
  const int c = blockIdx.y;   // chunk
  const int lane = threadIdx.x; // p
  const int hh = g % NH;
  const int db = g / NH;      // d*B+b
  float S[DS];
#pragma unroll
  for (int n = 0; n < DS; ++n) S[n] = 0.f;
  float P = 1.f;
  const float* xbase = xconv + (size_t)db * L * CONVC;
  for (int i = 0; i < CHUNK; ++i) {
    const int s = c * CHUNK + i;
    const float* row = xbase + (size_t)s * CONVC;
    const float xv = row[hh * HD + lane];
    const int di = (db * L + s) * NH + hh;
    const float dtv = dtb[di];
    const float dav = dab[di];
    P *= dav;
    const float a = dtv * xv;
    const float* Bt = row + DI;
#pragma unroll
    for (int n = 0; n < DS; ++n) S[n] = dav * S[n] + a * Bt[n];
  }
  float* o = Sbuf + (((size_t)g * NC + c) * HD + lane) * DS;
#pragma unroll
  for (int n = 0; n < DS; ++n) o[n] = S[n];
  if (lane == 0) Pbuf[g * NC + c] = P;
}

// ---------------- chain: turn local states into incoming states (in-place) ----
__global__ void scan_chain(float* __restrict__ Sbuf, const float* __restrict__ Pbuf) {
  const int idx = blockIdx.x * 256 + threadIdx.x;  // g*4096 + e
  const int g = idx >> 12;
  const int e = idx & 4095;
  float run = 0.f;
  float* base = Sbuf + (size_t)g * NC * 4096 + e;
  for (int c = 0; c < NC; ++c) {
    const float sc = base[(size_t)c * 4096];
    const float pc = Pbuf[g * NC + c];
    base[(size_t)c * 4096] = run;
    run = pc * run + sc;
  }
}

// ---------------- scan phase C: replay chunk with incoming state, emit y -------
__global__ __launch_bounds__(64) void scan_phaseC(
    const float* __restrict__ xconv, const float* __restrict__ dtb,
    const float* __restrict__ dab, const float* __restrict__ Dpar,
    const float* __restrict__ Sbuf, float* __restrict__ yraw) {
  const int g = blockIdx.x;
  const int c = blockIdx.y;
  const int lane = threadIdx.x;
  const int hh = g % NH;
  const int db = g / NH;
  float S[DS];
  const float* in = Sbuf + (((size_t)g * NC + c) * HD + lane) * DS;
#pragma unroll
  for (int n = 0; n < DS; ++n) S[n] = in[n];
  const float dp = Dpar[hh];
  const float* xbase = xconv + (size_t)db * L * CONVC;
  for (int i = 0; i < CHUNK; ++i) {
    const int s = c * CHUNK + i;
    const float* row = xbase + (size_t)s * CONVC;
    const float xv = row[hh * HD + lane];
    const int di = (db * L + s) * NH + hh;
    const float dtv = dtb[di];
    const float dav = dab[di];
    const float a = dtv * xv;
    const float* Bt = row + DI;
    const float* Ct = row + DI + DS;
    float acc = 0.f;
#pragma unroll
    for (int n = 0; n < DS; ++n) {
      S[n] = dav * S[n] + a * Bt[n];
      acc = fmaf(S[n], Ct[n], acc);
    }
    yraw[((size_t)db * L + s) * DI + hh * HD + lane] = acc + dp * xv;
  }
}

// ---------------- gate (silu(z)) + per-dir RMSNorm + sum dirs -------------------
__global__ __launch_bounds__(256) void gate_norm(
    const float* __restrict__ zx, const float* __restrict__ yraw,
    const float* __restrict__ nw, float* __restrict__ ycomb) {
  const int bt = blockIdx.x;   // b*L + t (original time order)
  const int b = bt / L, t = bt % L;
  const int tid = threadIdx.x;
  const float* z = zx + (size_t)bt * DPROJ;
  const float* y0 = yraw + ((size_t)b * L + t) * DI;                  // fwd dir, s=t
  const float* y1 = yraw + ((size_t)(B + b) * L + (L - 1 - t)) * DI;  // bwd dir, s=L-1-t
  float a0[4], a1[4];
  float s0 = 0.f, s1 = 0.f;
#pragma unroll
  for (int r = 0; r < 4; ++r) {
    const int cc = r * 256 + tid;
    const float zv = z[cc];
    const float gz = zv / (1.f + expf(-zv));
    a0[r] = y0[cc] * gz;
    a1[r] = y1[cc] * gz;
    s0 += a0[r] * a0[r];
    s1 += a1[r] * a1[r];
  }
#pragma unroll
  for (int off = 32; off > 0; off >>= 1) {
    s0 += __shfl_down(s0, off);
    s1 += __shfl_down(s1, off);
  }
  __shared__ float rs0[4], rs1[4];
  const int w = tid >> 6;
  if ((tid & 63) == 0) { rs0[w] = s0; rs1[w] = s1; }
  __syncthreads();
  s0 = rs0[0] + rs0[1] + rs0[2] + rs0[3];
  s1 = rs1[0] + rs1[1] + rs1[2] + rs1[3];
  const float r0 = rsqrtf(s0 * (1.f / DI) + 1e-5f);
  const float r1 = rsqrtf(s1 * (1.f / DI) + 1e-5f);
  float* oc = ycomb + (size_t)bt * DI;
#pragma unroll
  for (int r = 0; r < 4; ++r) {
    const int cc = r * 256 + tid;
    oc[cc] = nw[cc] * (a0[r] * r0 + a1[r] * r1);
  }
}

// ---------------- fold W_out @ Wp_out -> Wc (1024x80) --------------------------
__global__ void fuse_out(const float* __restrict__ Wo, const float* __restrict__ Wpo,
                         float* __restrict__ Wc) {
  const int idx = blockIdx.x * 256 + threadIdx.x;
  if (idx >= DI * DIN) return;
  const int c = idx / DIN, d = idx % DIN;
  float acc = 0.f;
  for (int m = 0; m < DM; ++m)
    acc = fmaf(Wo[(size_t)c * DM + m], Wpo[(size_t)m * DIN + d], acc);
  Wc[idx] = acc;
}

extern "C" void kernel_launch(void* const* d_in, const int* in_sizes, int n_in,
                              void* d_out, int out_size, void* d_ws, size_t ws_size,
                              hipStream_t stream) {
  const float* x       = (const float*)d_in[0];
  const float* Wp_in   = (const float*)d_in[1];
  const float* bp_in   = (const float*)d_in[2];
  const float* W_in    = (const float*)d_in[3];
  const float* b_in    = (const float*)d_in[4];
  const float* conv_w  = (const float*)d_in[5];
  const float* conv_b  = (const float*)d_in[6];
  const float* dt_bias = (const float*)d_in[7];
  const float* A_log   = (const float*)d_in[8];
  const float* Dpar    = (const float*)d_in[9];
  const float* norm_w  = (const float*)d_in[10];
  const float* W_out   = (const float*)d_in[11];
  const float* Wp_out  = (const float*)d_in[12];
  const float* bp_out  = (const float*)d_in[13];
  float* out = (float*)d_out;

  char* p = (char*)d_ws;
  __hip_bfloat16* hbf = (__hip_bfloat16*)p; p += (size_t)BL * DM * 2;   // 4 MB
  __hip_bfloat16* Wt  = (__hip_bfloat16*)p; p += (size_t)NPAD * DM * 2; // 2.36 MB
  float* zx    = (float*)p; p += (size_t)BL * DPROJ * 4;
  float* xconv = (float*)p; p += (size_t)2 * BL * CONVC * 4;
  float* dtb   = (float*)p; p += (size_t)2 * BL * NH * 4;
  float* dab   = (float*)p; p += (size_t)2 * BL * NH * 4;
  float* Sbuf  = (float*)p; p += (size_t)NG * NC * HD * DS * 4;
  float* Pbuf  = (float*)p; p += (size_t)NG * NC * 4;
  float* yraw  = (float*)p; p += (size_t)2 * BL * DI * 4;
  float* ycomb = (float*)p; p += (size_t)BL * DI * 4;
  float* Wc    = (float*)p; p += (size_t)DI * DIN * 4;
  (void)ws_size; (void)in_sizes; (void)n_in; (void)out_size;

  // 1. h = bf16(x @ Wp_in + bp_in)
  gemm_bias<__hip_bfloat16><<<dim3(BL / GBM, (DM + GBN - 1) / GBN), 256, 0, stream>>>(
      x, Wp_in, bp_in, hbf, BL, DM, DIN);
  // 1b. Wt = bf16(W_in^T), padded to NPAD rows
  prep_wt<<<(NPAD * DM + 255) / 256, 256, 0, stream>>>(W_in, Wt);
  // 2. zxbcdt = h @ W_in + b_in  (bf16 MFMA, shared by both directions)
  gemm_mfma_bt<<<dim3(BL / 128, NPAD / 128), 256, 0, stream>>>(
      hbf, Wt, b_in, zx, BL, DPROJ, DM);
  // 3. conv + silu for both directions; dt/dA
  prep_conv<<<(2 * BL * CONVC + 255) / 256, 256, 0, stream>>>(zx, conv_w, conv_b, xconv);
  prep_dt<<<(2 * BL * NH + 255) / 256, 256, 0, stream>>>(zx, dt_bias, A_log, dtb, dab);
  // 4. chunked scan
  scan_phaseA<<<dim3(NG, NC), 64, 0, stream>>>(xconv, dtb, dab, Sbuf, Pbuf);
  scan_chain<<<(NG * HD * DS) / 256, 256, 0, stream>>>(Sbuf, Pbuf);
  scan_phaseC<<<dim3(NG, NC), 64, 0, stream>>>(xconv, dtb, dab, Dpar, Sbuf, yraw);
  // 5. gate + RMSNorm + combine directions
  gate_norm<<<BL, 256, 0, stream>>>(zx, yraw, norm_w, ycomb);
  // 6. Wc = W_out @ Wp_out
  fuse_out<<<(DI * DIN + 255) / 256, 256, 0, stream>>>(W_out, Wp_out, Wc);
  // 7. out = ycomb @ Wc + bp_out
  gemm_bias<float><<<dim3(BL / GBM, (DIN + GBN - 1) / GBN), 256, 0, stream>>>(
      ycomb, Wc, bp_out, out, BL, DIN, DI);
}

// Round 5
// 506.567 us; speedup vs baseline: 1.5808x; 1.2775x over previous
//
#include <hip/hip_runtime.h>
#include <hip/hip_bf16.h>

constexpr int B = 2;
constexpr int L = 2048;
constexpr int DIN = 80;
constexpr int DM = 512;
constexpr int DI = 1024;
constexpr int DS = 64;
constexpr int KC = 7;
constexpr int HD = 64;
constexpr int NH = 16;                    // DI/HD
constexpr int CONVC = DI + 2 * DS;        // 1152
constexpr int DPROJ = 2 * DI + 2 * DS + NH; // 2192
constexpr int NPAD = 2304;                // DPROJ padded to 18*128
constexpr int BL = B * L;                 // 4096
constexpr int CHUNK = 64;
constexpr int NC = L / CHUNK;             // 32
constexpr int NG = 2 * B * NH;            // 64 scan groups (dir,b,head)
constexpr int KSPLIT = 16;                // final GEMM K-split

typedef __attribute__((ext_vector_type(8))) short bf16x8;
typedef __attribute__((ext_vector_type(4))) float f32x4;

// ---------------- fp32 tiled GEMM with bias: C[M,N] = A[M,K]*Bm[K,N] + bias[N]
constexpr int GBM = 128, GBN = 128, GBK = 16;

template <typename OutT>
__global__ __launch_bounds__(256) void gemm_bias(
    const float* __restrict__ A, const float* __restrict__ Bm,
    const float* __restrict__ bias, OutT* __restrict__ C,
    int M, int N, int K) {
  __shared__ float As[GBK][GBM + 4];
  __shared__ float Bs[GBK][GBN + 4];
  const int m0 = blockIdx.x * GBM;
  const int n0 = blockIdx.y * GBN;
  const int tid = threadIdx.x;
  const int tm = tid >> 4, tn = tid & 15;
  float acc[8][8] = {};
  const int arow = tid >> 2, acol = (tid & 3) << 2;   // A: 64 rows x 16 cols per pass
  const int brow = tid >> 5, bcol = (tid & 31) << 2;  // B: 8 rows x 128 cols per pass
  for (int k0 = 0; k0 < K; k0 += GBK) {
#pragma unroll
    for (int r = 0; r < 2; ++r) {
      int m = m0 + arow + r * 64;
      float4 v = make_float4(0.f, 0.f, 0.f, 0.f);
      if (m < M) v = *(const float4*)(A + (size_t)m * K + k0 + acol);
      As[acol + 0][arow + r * 64] = v.x;
      As[acol + 1][arow + r * 64] = v.y;
      As[acol + 2][arow + r * 64] = v.z;
      As[acol + 3][arow + r * 64] = v.w;
    }
#pragma unroll
    for (int r = 0; r < 2; ++r) {
      int kk = brow + r * 8;
      int n = n0 + bcol;
      float4 v = make_float4(0.f, 0.f, 0.f, 0.f);
      if (n < N) v = *(const float4*)(Bm + (size_t)(k0 + kk) * N + n);
      *(float4*)&Bs[kk][bcol] = v;
    }
    __syncthreads();
#pragma unroll
    for (int k = 0; k < GBK; ++k) {
      float a[8], bb[8];
#pragma unroll
      for (int i = 0; i < 8; ++i) a[i] = As[k][tm * 8 + i];
#pragma unroll
      for (int j = 0; j < 8; ++j) bb[j] = Bs[k][tn * 8 + j];
#pragma unroll
      for (int i = 0; i < 8; ++i)
#pragma unroll
        for (int j = 0; j < 8; ++j)
          acc[i][j] = fmaf(a[i], bb[j], acc[i][j]);
    }
    __syncthreads();
  }
#pragma unroll
  for (int i = 0; i < 8; ++i) {
    int m = m0 + tm * 8 + i;
    if (m >= M) continue;
#pragma unroll
    for (int j = 0; j < 8; ++j) {
      int n = n0 + tn * 8 + j;
      if (n < N) C[(size_t)m * N + n] = (OutT)(acc[i][j] + bias[n]);
    }
  }
}

// ---------------- W_in -> transposed, padded bf16 [NPAD][DM] --------------------
__global__ void prep_wt(const float* __restrict__ W_in, __hip_bfloat16* __restrict__ Wt) {
  const int idx = blockIdx.x * 256 + threadIdx.x;
  if (idx >= NPAD * DM) return;
  const int n = idx % NPAD;
  const int k = idx / NPAD;
  const float v = (n < DPROJ) ? W_in[(size_t)k * DPROJ + n] : 0.f;
  Wt[(size_t)n * DM + k] = (__hip_bfloat16)v;
}

// ---------------- bf16 MFMA GEMM: C[M,N] = A[M,K] * Bt[N,K]^T + bias -----------
__global__ __launch_bounds__(256) void gemm_mfma_bt(
    const __hip_bfloat16* __restrict__ A, const __hip_bfloat16* __restrict__ Bt,
    const float* __restrict__ bias, float* __restrict__ C,
    int M, int N, int K) {
  __shared__ short As[4 * 128 * 8];
  __shared__ short Bs[4 * 128 * 8];
  const int tid = threadIdx.x;
  const int l = tid & 63;
  const int wv = tid >> 6;
  const int wr = wv >> 1, wc = wv & 1;
  const int m0 = blockIdx.x * 128;
  const int n0 = blockIdx.y * 128;
  const int ks = l >> 4, lr = l & 15;
  f32x4 acc[4][4] = {};
  for (int k0 = 0; k0 < K; k0 += 32) {
#pragma unroll
    for (int i = 0; i < 2; ++i) {
      const int t = (wv * 2 + i) * 64 + l;
      const int tks = t >> 7, trow = t & 127;
      __builtin_amdgcn_global_load_lds(
          (const __attribute__((address_space(1))) unsigned int*)(A + (size_t)(m0 + trow) * K + k0 + tks * 8),
          (__attribute__((address_space(3))) unsigned int*)(As + (size_t)(wv * 2 + i) * 512),
          16, 0, 0);
      __builtin_amdgcn_global_load_lds(
          (const __attribute__((address_space(1))) unsigned int*)(Bt + (size_t)(n0 + trow) * K + k0 + tks * 8),
          (__attribute__((address_space(3))) unsigned int*)(Bs + (size_t)(wv * 2 + i) * 512),
          16, 0, 0);
    }
    __syncthreads();
    bf16x8 af[4], bfr[4];
#pragma unroll
    for (int mi = 0; mi < 4; ++mi)
      af[mi] = *(const bf16x8*)&As[(size_t)(ks * 128 + wr * 64 + mi * 16 + lr) * 8];
#pragma unroll
    for (int ni = 0; ni < 4; ++ni)
      bfr[ni] = *(const bf16x8*)&Bs[(size_t)(ks * 128 + wc * 64 + ni * 16 + lr) * 8];
#pragma unroll
    for (int mi = 0; mi < 4; ++mi)
#pragma unroll
      for (int ni = 0; ni < 4; ++ni)
        acc[mi][ni] = __builtin_amdgcn_mfma_f32_16x16x32_bf16(af[mi], bfr[ni], acc[mi][ni], 0, 0, 0);
    __syncthreads();
  }
#pragma unroll
  for (int mi = 0; mi < 4; ++mi) {
    const int row = m0 + wr * 64 + mi * 16 + (l >> 4) * 4;
#pragma unroll
    for (int ni = 0; ni < 4; ++ni) {
      const int col = n0 + wc * 64 + ni * 16 + lr;
      if (col < N) {
        const float bv = bias[col];
#pragma unroll
        for (int r = 0; r < 4; ++r)
          C[(size_t)(row + r) * N + col] = acc[mi][ni][r] + bv;
      }
    }
  }
}

// ---------------- final GEMM split-K: part[ks][M][80] = A64 * Wc64 ------------
// grid (M/64, KSPLIT); A = ycomb [M][1024], Wc [1024][80].
__global__ __launch_bounds__(256) void gemm_final_splitk(
    const float* __restrict__ Acf, const float* __restrict__ Wc,
    float* __restrict__ part) {
  __shared__ float As[64][65];
  __shared__ float Bs[64][80];
  const int tid = threadIdx.x;
  const int m0 = blockIdx.x * 64;
  const int k0 = blockIdx.y * 64;
  {
    const int r = tid >> 2, q = tid & 3;
#pragma unroll
    for (int j = 0; j < 4; ++j) {
      const int col = q * 16 + j * 4;
      float4 v = *(const float4*)(Acf + (size_t)(m0 + r) * DI + k0 + col);
      As[r][col + 0] = v.x; As[r][col + 1] = v.y;
      As[r][col + 2] = v.z; As[r][col + 3] = v.w;
    }
#pragma unroll
    for (int j = 0; j < 5; ++j) {
      const int col = (q * 5 + j) * 4;
      float4 v = *(const float4*)(Wc + (size_t)(k0 + r) * DIN + col);
      *(float4*)&Bs[r][col] = v;
    }
  }
  __syncthreads();
  const int r0 = (tid >> 4) * 4;     // 4 rows
  const int n0 = (tid & 15) * 5;     // 5 cols
  float acc[4][5] = {};
  for (int k = 0; k < 64; ++k) {
    float a[4];
#pragma unroll
    for (int i = 0; i < 4; ++i) a[i] = As[r0 + i][k];
#pragma unroll
    for (int j = 0; j < 5; ++j) {
      const float bv = Bs[k][n0 + j];
#pragma unroll
      for (int i = 0; i < 4; ++i) acc[i][j] = fmaf(a[i], bv, acc[i][j]);
    }
  }
#pragma unroll
  for (int i = 0; i < 4; ++i) {
    float* o = part + ((size_t)blockIdx.y * BL + m0 + r0 + i) * DIN + n0;
#pragma unroll
    for (int j = 0; j < 5; ++j) o[j] = acc[i][j];
  }
}

__global__ __launch_bounds__(256) void reduce_final(
    const float* __restrict__ part, const float* __restrict__ bias,
    float* __restrict__ out) {
  const int idx = blockIdx.x * 256 + threadIdx.x;
  if (idx >= BL * DIN) return;
  const int n = idx % DIN;
  float acc = bias[n];
#pragma unroll
  for (int s = 0; s < KSPLIT; ++s) acc += part[(size_t)s * BL * DIN + idx];
  out[idx] = acc;
}

// ---------------- conv (both directions) + silu ----------------
__global__ void prep_conv(const float* __restrict__ zx, const float* __restrict__ cw,
                          const float* __restrict__ cb, float* __restrict__ xconv) {
  const int idx = blockIdx.x * 256 + threadIdx.x;
  if (idx >= 2 * BL * CONVC) return;
  const int c = idx % CONVC;
  int rest = idx / CONVC;
  const int s = rest % L;
  rest /= L;
  const int bb = rest % B;
  const int d = rest / B;
  float acc = cb[c];
  if (d == 0) {
#pragma unroll
    for (int k = 0; k < KC; ++k) {
      const int t = s - (KC - 1) + k;
      if (t >= 0) acc = fmaf(cw[c * KC + k], zx[((size_t)(bb * L + t)) * DPROJ + DI + c], acc);
    }
  } else {
    const int torig = L - 1 - s;
#pragma unroll
    for (int j = 0; j < KC; ++j) {
      const int t = torig + j;
      if (t < L) acc = fmaf(cw[c * KC + (KC - 1 - j)], zx[((size_t)(bb * L + t)) * DPROJ + DI + c], acc);
    }
  }
  xconv[idx] = acc / (1.f + expf(-acc));  // silu
}

// ---------------- dt / dA (scan order per direction) ----------------
__global__ void prep_dt(const float* __restrict__ zx, const float* __restrict__ dt_bias,
                        const float* __restrict__ A_log, float* __restrict__ dtb,
                        float* __restrict__ dab) {
  const int idx = blockIdx.x * 256 + threadIdx.x;
  if (idx >= 2 * BL * NH) return;
  const int h = idx % NH;
  int rest = idx / NH;
  const int s = rest % L;
  rest /= L;
  const int bb = rest % B;
  const int d = rest / B;
  const int torig = d ? (L - 1 - s) : s;
  const float raw = zx[((size_t)(bb * L + torig)) * DPROJ + DI + CONVC + h] + dt_bias[h];
  const float dt = (raw > 20.f) ? raw : log1pf(expf(raw));
  dtb[idx] = dt;
  dab[idx] = expf(-expf(A_log[h]) * dt);
}

// ---------------- scan phase A ----------------
__global__ __launch_bounds__(64) void scan_phaseA(
    const float* __restrict__ xconv, const float* __restrict__ dtb,
    const float* __restrict__ dab, float* __restrict__ Sbuf,
    float* __restrict__ Pbuf) {
  const int g = blockIdx.x;   // (d*B+b)*NH + h
  const int c = blockIdx.y;   // chunk
  const int lane = threadIdx.x; // p
  const int hh = g % NH;
  const int db = g / NH;      // d*B+b
  float S[DS];
#pragma unroll
  for (int n = 0; n < DS; ++n) S[n] = 0.f;
  float P = 1.f;
  const float* xbase = xconv + (size_t)db * L * CONVC;
  for (int i = 0; i < CHUNK; ++i) {
    const int s = c * CHUNK + i;
    const float* row = xbase + (size_t)s * CONVC;
    const float xv = row[hh * HD + lane];
    const int di = (db * L + s) * NH + hh;
    const float dtv = dtb[di];
    const float dav = dab[di];
    P *= dav;
    const float a = dtv * xv;
    const float* Bt = row + DI;
#pragma unroll
    for (int n = 0; n < DS; ++n) S[n] = dav * S[n] + a * Bt[n];
  }
  float* o = Sbuf + (((size_t)g * NC + c) * HD + lane) * DS;
#pragma unroll
  for (int n = 0; n < DS; ++n) o[n] = S[n];
  if (lane == 0) Pbuf[g * NC + c] = P;
}

// ---------------- chain ----------------
__global__ void scan_chain(float* __restrict__ Sbuf, const float* __restrict__ Pbuf) {
  const int idx = blockIdx.x * 256 + threadIdx.x;  // g*4096 + e
  const int g = idx >> 12;
  const int e = idx & 4095;
  float run = 0.f;
  float* base = Sbuf + (size_t)g * NC * 4096 + e;
  for (int c = 0; c < NC; ++c) {
    const float sc = base[(size_t)c * 4096];
    const float pc = Pbuf[g * NC + c];
    base[(size_t)c * 4096] = run;
    run = pc * run + sc;
  }
}

// ---------------- scan phase C ----------------
__global__ __launch_bounds__(64) void scan_phaseC(
    const float* __restrict__ xconv, const float* __restrict__ dtb,
    const float* __restrict__ dab, const float* __restrict__ Dpar,
    const float* __restrict__ Sbuf, float* __restrict__ yraw) {
  const int g = blockIdx.x;
  const int c = blockIdx.y;
  const int lane = threadIdx.x;
  const int hh = g % NH;
  const int db = g / NH;
  float S[DS];
  const float* in = Sbuf + (((size_t)g * NC + c) * HD + lane) * DS;
#pragma unroll
  for (int n = 0; n < DS; ++n) S[n] = in[n];
  const float dp = Dpar[hh];
  const float* xbase = xconv + (size_t)db * L * CONVC;
  for (int i = 0; i < CHUNK; ++i) {
    const int s = c * CHUNK + i;
    const float* row = xbase + (size_t)s * CONVC;
    const float xv = row[hh * HD + lane];
    const int di = (db * L + s) * NH + hh;
    const float dtv = dtb[di];
    const float dav = dab[di];
    const float a = dtv * xv;
    const float* Bt = row + DI;
    const float* Ct = row + DI + DS;
    float acc = 0.f;
#pragma unroll
    for (int n = 0; n < DS; ++n) {
      S[n] = dav * S[n] + a * Bt[n];
      acc = fmaf(S[n], Ct[n], acc);
    }
    yraw[((size_t)db * L + s) * DI + hh * HD + lane] = acc + dp * xv;
  }
}

// ---------------- gate + RMSNorm + combine ----------------
__global__ __launch_bounds__(256) void gate_norm(
    const float* __restrict__ zx, const float* __restrict__ yraw,
    const float* __restrict__ nw, float* __restrict__ ycomb) {
  const int bt = blockIdx.x;   // b*L + t (original time order)
  const int b = bt / L, t = bt % L;
  const int tid = threadIdx.x;
  const float* z = zx + (size_t)bt * DPROJ;
  const float* y0 = yraw + ((size_t)b * L + t) * DI;                  // fwd dir, s=t
  const float* y1 = yraw + ((size_t)(B + b) * L + (L - 1 - t)) * DI;  // bwd dir, s=L-1-t
  float a0[4], a1[4];
  float s0 = 0.f, s1 = 0.f;
#pragma unroll
  for (int r = 0; r < 4; ++r) {
    const int cc = r * 256 + tid;
    const float zv = z[cc];
    const float gz = zv / (1.f + expf(-zv));
    a0[r] = y0[cc] * gz;
    a1[r] = y1[cc] * gz;
    s0 += a0[r] * a0[r];
    s1 += a1[r] * a1[r];
  }
#pragma unroll
  for (int off = 32; off > 0; off >>= 1) {
    s0 += __shfl_down(s0, off);
    s1 += __shfl_down(s1, off);
  }
  __shared__ float rs0[4], rs1[4];
  const int w = tid >> 6;
  if ((tid & 63) == 0) { rs0[w] = s0; rs1[w] = s1; }
  __syncthreads();
  s0 = rs0[0] + rs0[1] + rs0[2] + rs0[3];
  s1 = rs1[0] + rs1[1] + rs1[2] + rs1[3];
  const float r0 = rsqrtf(s0 * (1.f / DI) + 1e-5f);
  const float r1 = rsqrtf(s1 * (1.f / DI) + 1e-5f);
  float* oc = ycomb + (size_t)bt * DI;
#pragma unroll
  for (int r = 0; r < 4; ++r) {
    const int cc = r * 256 + tid;
    oc[cc] = nw[cc] * (a0[r] * r0 + a1[r] * r1);
  }
}

// ---------------- fold W_out @ Wp_out -> Wc (1024x80) --------------------------
__global__ void fuse_out(const float* __restrict__ Wo, const float* __restrict__ Wpo,
                         float* __restrict__ Wc) {
  const int idx = blockIdx.x * 256 + threadIdx.x;
  if (idx >= DI * DIN) return;
  const int c = idx / DIN, d = idx % DIN;
  float acc = 0.f;
  for (int m = 0; m < DM; ++m)
    acc = fmaf(Wo[(size_t)c * DM + m], Wpo[(size_t)m * DIN + d], acc);
  Wc[idx] = acc;
}

extern "C" void kernel_launch(void* const* d_in, const int* in_sizes, int n_in,
                              void* d_out, int out_size, void* d_ws, size_t ws_size,
                              hipStream_t stream) {
  const float* x       = (const float*)d_in[0];
  const float* Wp_in   = (const float*)d_in[1];
  const float* bp_in   = (const float*)d_in[2];
  const float* W_in    = (const float*)d_in[3];
  const float* b_in    = (const float*)d_in[4];
  const float* conv_w  = (const float*)d_in[5];
  const float* conv_b  = (const float*)d_in[6];
  const float* dt_bias = (const float*)d_in[7];
  const float* A_log   = (const float*)d_in[8];
  const float* Dpar    = (const float*)d_in[9];
  const float* norm_w  = (const float*)d_in[10];
  const float* W_out   = (const float*)d_in[11];
  const float* Wp_out  = (const float*)d_in[12];
  const float* bp_out  = (const float*)d_in[13];
  float* out = (float*)d_out;

  char* p = (char*)d_ws;
  __hip_bfloat16* hbf = (__hip_bfloat16*)p; p += (size_t)BL * DM * 2;   // 4 MB
  __hip_bfloat16* Wt  = (__hip_bfloat16*)p; p += (size_t)NPAD * DM * 2; // 2.36 MB
  float* zx    = (float*)p; p += (size_t)BL * DPROJ * 4;
  float* xconv = (float*)p; p += (size_t)2 * BL * CONVC * 4;
  float* dtb   = (float*)p; p += (size_t)2 * BL * NH * 4;
  float* dab   = (float*)p; p += (size_t)2 * BL * NH * 4;
  float* Sbuf  = (float*)p; p += (size_t)NG * NC * HD * DS * 4;
  float* Pbuf  = (float*)p; p += (size_t)NG * NC * 4;
  float* yraw  = (float*)p; p += (size_t)2 * BL * DI * 4;
  float* ycomb = (float*)p; p += (size_t)BL * DI * 4;
  float* Wc    = (float*)p; p += (size_t)DI * DIN * 4;
  float* part  = zx;   // alias: zx is dead after gate_norm; 21 MB < 35.9 MB
  (void)ws_size; (void)in_sizes; (void)n_in; (void)out_size;

  // 1. h = bf16(x @ Wp_in + bp_in)
  gemm_bias<__hip_bfloat16><<<dim3(BL / GBM, (DM + GBN - 1) / GBN), 256, 0, stream>>>(
      x, Wp_in, bp_in, hbf, BL, DM, DIN);
  // 1b. Wt = bf16(W_in^T), padded to NPAD rows
  prep_wt<<<(NPAD * DM + 255) / 256, 256, 0, stream>>>(W_in, Wt);
  // 2. zxbcdt = h @ W_in + b_in  (bf16 MFMA, shared by both directions)
  gemm_mfma_bt<<<dim3(BL / 128, NPAD / 128), 256, 0, stream>>>(
      hbf, Wt, b_in, zx, BL, DPROJ, DM);
  // 3. conv + silu for both directions; dt/dA
  prep_conv<<<(2 * BL * CONVC + 255) / 256, 256, 0, stream>>>(zx, conv_w, conv_b, xconv);
  prep_dt<<<(2 * BL * NH + 255) / 256, 256, 0, stream>>>(zx, dt_bias, A_log, dtb, dab);
  // 4. chunked scan
  scan_phaseA<<<dim3(NG, NC), 64, 0, stream>>>(xconv, dtb, dab, Sbuf, Pbuf);
  scan_chain<<<(NG * HD * DS) / 256, 256, 0, stream>>>(Sbuf, Pbuf);
  scan_phaseC<<<dim3(NG, NC), 64, 0, stream>>>(xconv, dtb, dab, Dpar, Sbuf, yraw);
  // 5. gate + RMSNorm + combine directions
  gate_norm<<<BL, 256, 0, stream>>>(zx, yraw, norm_w, ycomb);
  // 6. Wc = W_out @ Wp_out
  fuse_out<<<(DI * DIN + 255) / 256, 256, 0, stream>>>(W_out, Wp_out, Wc);
  // 7. out = ycomb @ Wc + bp_out  (split-K + reduce; part aliases dead zx)
  gemm_final_splitk<<<dim3(BL / 64, KSPLIT), 256, 0, stream>>>(ycomb, Wc, part);
  reduce_final<<<(BL * DIN + 255) / 256, 256, 0, stream>>>(part, bp_out, out);
}

// Round 6
// 361.313 us; speedup vs baseline: 2.2163x; 1.4020x over previous
//
#include <hip/hip_runtime.h>
#include <hip/hip_bf16.h>

constexpr int B = 2;
constexpr int L = 2048;
constexpr int DIN = 80;
constexpr int DM = 512;
constexpr int DI = 1024;
constexpr int DS = 64;
constexpr int KC = 7;
constexpr int HD = 64;
constexpr int NH = 16;                    // DI/HD
constexpr int CONVC = DI + 2 * DS;        // 1152
constexpr int DPROJ = 2 * DI + 2 * DS + NH; // 2192
constexpr int NPAD = 2304;                // DPROJ padded to 18*128
constexpr int BL = B * L;                 // 4096
constexpr int CHUNK = 64;
constexpr int NC = L / CHUNK;             // 32
constexpr int NG = 2 * B * NH;            // 64 scan groups (dir,b,head)
constexpr int KSPLIT = 16;                // final GEMM K-split
constexpr int XTS = 72;                   // LDS transposed-tile row stride (bf16)

typedef __attribute__((ext_vector_type(8))) short bf16x8;
typedef __attribute__((ext_vector_type(4))) float f32x4;

__device__ inline short f2bf(float f) {
  union { float f; unsigned u; } v; v.f = f;
  unsigned r = (v.u + 0x7FFF + ((v.u >> 16) & 1)) >> 16;  // RNE
  return (short)r;
}
__device__ inline float bf2f(short s) {
  union { unsigned u; float f; } v; v.u = ((unsigned)(unsigned short)s) << 16;
  return v.f;
}
// load 8 contiguous fp32, scale, convert to bf16x8 fragment
__device__ inline bf16x8 cvt8(const float* p, float s) {
  const float4 a = *(const float4*)p;
  const float4 b = *(const float4*)(p + 4);
  bf16x8 r;
  r[0] = f2bf(a.x * s); r[1] = f2bf(a.y * s); r[2] = f2bf(a.z * s); r[3] = f2bf(a.w * s);
  r[4] = f2bf(b.x * s); r[5] = f2bf(b.y * s); r[6] = f2bf(b.z * s); r[7] = f2bf(b.w * s);
  return r;
}

// ---------------- fp32 tiled GEMM with bias: C[M,N] = A[M,K]*Bm[K,N] + bias[N]
constexpr int GBM = 128, GBN = 128, GBK = 16;

template <typename OutT>
__global__ __launch_bounds__(256) void gemm_bias(
    const float* __restrict__ A, const float* __restrict__ Bm,
    const float* __restrict__ bias, OutT* __restrict__ C,
    int M, int N, int K) {
  __shared__ float As[GBK][GBM + 4];
  __shared__ float Bs[GBK][GBN + 4];
  const int m0 = blockIdx.x * GBM;
  const int n0 = blockIdx.y * GBN;
  const int tid = threadIdx.x;
  const int tm = tid >> 4, tn = tid & 15;
  float acc[8][8] = {};
  const int arow = tid >> 2, acol = (tid & 3) << 2;
  const int brow = tid >> 5, bcol = (tid & 31) << 2;
  for (int k0 = 0; k0 < K; k0 += GBK) {
#pragma unroll
    for (int r = 0; r < 2; ++r) {
      int m = m0 + arow + r * 64;
      float4 v = make_float4(0.f, 0.f, 0.f, 0.f);
      if (m < M) v = *(const float4*)(A + (size_t)m * K + k0 + acol);
      As[acol + 0][arow + r * 64] = v.x;
      As[acol + 1][arow + r * 64] = v.y;
      As[acol + 2][arow + r * 64] = v.z;
      As[acol + 3][arow + r * 64] = v.w;
    }
#pragma unroll
    for (int r = 0; r < 2; ++r) {
      int kk = brow + r * 8;
      int n = n0 + bcol;
      float4 v = make_float4(0.f, 0.f, 0.f, 0.f);
      if (n < N) v = *(const float4*)(Bm + (size_t)(k0 + kk) * N + n);
      *(float4*)&Bs[kk][bcol] = v;
    }
    __syncthreads();
#pragma unroll
    for (int k = 0; k < GBK; ++k) {
      float a[8], bb[8];
#pragma unroll
      for (int i = 0; i < 8; ++i) a[i] = As[k][tm * 8 + i];
#pragma unroll
      for (int j = 0; j < 8; ++j) bb[j] = Bs[k][tn * 8 + j];
#pragma unroll
      for (int i = 0; i < 8; ++i)
#pragma unroll
        for (int j = 0; j < 8; ++j)
          acc[i][j] = fmaf(a[i], bb[j], acc[i][j]);
    }
    __syncthreads();
  }
#pragma unroll
  for (int i = 0; i < 8; ++i) {
    int m = m0 + tm * 8 + i;
    if (m >= M) continue;
#pragma unroll
    for (int j = 0; j < 8; ++j) {
      int n = n0 + tn * 8 + j;
      if (n < N) C[(size_t)m * N + n] = (OutT)(acc[i][j] + bias[n]);
    }
  }
}

// ---------------- W_in -> transposed, padded bf16 [NPAD][DM] --------------------
__global__ void prep_wt(const float* __restrict__ W_in, __hip_bfloat16* __restrict__ Wt) {
  const int idx = blockIdx.x * 256 + threadIdx.x;
  if (idx >= NPAD * DM) return;
  const int n = idx % NPAD;
  const int k = idx / NPAD;
  const float v = (n < DPROJ) ? W_in[(size_t)k * DPROJ + n] : 0.f;
  Wt[(size_t)n * DM + k] = (__hip_bfloat16)v;
}

// ---------------- bf16 MFMA GEMM: C[M,N] = A[M,K] * Bt[N,K]^T + bias -----------
__global__ __launch_bounds__(256) void gemm_mfma_bt(
    const __hip_bfloat16* __restrict__ A, const __hip_bfloat16* __restrict__ Bt,
    const float* __restrict__ bias, float* __restrict__ C,
    int M, int N, int K) {
  __shared__ short As[4 * 128 * 8];
  __shared__ short Bs[4 * 128 * 8];
  const int tid = threadIdx.x;
  const int l = tid & 63;
  const int wv = tid >> 6;
  const int wr = wv >> 1, wc = wv & 1;
  const int m0 = blockIdx.x * 128;
  const int n0 = blockIdx.y * 128;
  const int ks = l >> 4, lr = l & 15;
  f32x4 acc[4][4] = {};
  for (int k0 = 0; k0 < K; k0 += 32) {
#pragma unroll
    for (int i = 0; i < 2; ++i) {
      const int t = (wv * 2 + i) * 64 + l;
      const int tks = t >> 7, trow = t & 127;
      __builtin_amdgcn_global_load_lds(
          (const __attribute__((address_space(1))) unsigned int*)(A + (size_t)(m0 + trow) * K + k0 + tks * 8),
          (__attribute__((address_space(3))) unsigned int*)(As + (size_t)(wv * 2 + i) * 512),
          16, 0, 0);
      __builtin_amdgcn_global_load_lds(
          (const __attribute__((address_space(1))) unsigned int*)(Bt + (size_t)(n0 + trow) * K + k0 + tks * 8),
          (__attribute__((address_space(3))) unsigned int*)(Bs + (size_t)(wv * 2 + i) * 512),
          16, 0, 0);
    }
    __syncthreads();
    bf16x8 af[4], bfr[4];
#pragma unroll
    for (int mi = 0; mi < 4; ++mi)
      af[mi] = *(const bf16x8*)&As[(size_t)(ks * 128 + wr * 64 + mi * 16 + lr) * 8];
#pragma unroll
    for (int ni = 0; ni < 4; ++ni)
      bfr[ni] = *(const bf16x8*)&Bs[(size_t)(ks * 128 + wc * 64 + ni * 16 + lr) * 8];
#pragma unroll
    for (int mi = 0; mi < 4; ++mi)
#pragma unroll
      for (int ni = 0; ni < 4; ++ni)
        acc[mi][ni] = __builtin_amdgcn_mfma_f32_16x16x32_bf16(af[mi], bfr[ni], acc[mi][ni], 0, 0, 0);
    __syncthreads();
  }
#pragma unroll
  for (int mi = 0; mi < 4; ++mi) {
    const int row = m0 + wr * 64 + mi * 16 + (l >> 4) * 4;
#pragma unroll
    for (int ni = 0; ni < 4; ++ni) {
      const int col = n0 + wc * 64 + ni * 16 + lr;
      if (col < N) {
        const float bv = bias[col];
#pragma unroll
        for (int r = 0; r < 4; ++r)
          C[(size_t)(row + r) * N + col] = acc[mi][ni][r] + bv;
      }
    }
  }
}

// ---------------- final GEMM split-K ------------------------------------------
__global__ __launch_bounds__(256) void gemm_final_splitk(
    const float* __restrict__ Acf, const float* __restrict__ Wc,
    float* __restrict__ part) {
  __shared__ float As[64][65];
  __shared__ float Bs[64][80];
  const int tid = threadIdx.x;
  const int m0 = blockIdx.x * 64;
  const int k0 = blockIdx.y * 64;
  {
    const int r = tid >> 2, q = tid & 3;
#pragma unroll
    for (int j = 0; j < 4; ++j) {
      const int col = q * 16 + j * 4;
      float4 v = *(const float4*)(Acf + (size_t)(m0 + r) * DI + k0 + col);
      As[r][col + 0] = v.x; As[r][col + 1] = v.y;
      As[r][col + 2] = v.z; As[r][col + 3] = v.w;
    }
#pragma unroll
    for (int j = 0; j < 5; ++j) {
      const int col = (q * 5 + j) * 4;
      float4 v = *(const float4*)(Wc + (size_t)(k0 + r) * DIN + col);
      *(float4*)&Bs[r][col] = v;
    }
  }
  __syncthreads();
  const int r0 = (tid >> 4) * 4;
  const int n0 = (tid & 15) * 5;
  float acc[4][5] = {};
  for (int k = 0; k < 64; ++k) {
    float a[4];
#pragma unroll
    for (int i = 0; i < 4; ++i) a[i] = As[r0 + i][k];
#pragma unroll
    for (int j = 0; j < 5; ++j) {
      const float bv = Bs[k][n0 + j];
#pragma unroll
      for (int i = 0; i < 4; ++i) acc[i][j] = fmaf(a[i], bv, acc[i][j]);
    }
  }
#pragma unroll
  for (int i = 0; i < 4; ++i) {
    float* o = part + ((size_t)blockIdx.y * BL + m0 + r0 + i) * DIN + n0;
#pragma unroll
    for (int j = 0; j < 5; ++j) o[j] = acc[i][j];
  }
}

__global__ __launch_bounds__(256) void reduce_final(
    const float* __restrict__ part, const float* __restrict__ bias,
    float* __restrict__ out) {
  const int idx = blockIdx.x * 256 + threadIdx.x;
  if (idx >= BL * DIN) return;
  const int n = idx % DIN;
  float acc = bias[n];
#pragma unroll
  for (int s = 0; s < KSPLIT; ++s) acc += part[(size_t)s * BL * DIN + idx];
  out[idx] = acc;
}

// ---------------- conv (both directions) + silu ----------------
__global__ void prep_conv(const float* __restrict__ zx, const float* __restrict__ cw,
                          const float* __restrict__ cb, float* __restrict__ xconv) {
  const int idx = blockIdx.x * 256 + threadIdx.x;
  if (idx >= 2 * BL * CONVC) return;
  const int c = idx % CONVC;
  int rest = idx / CONVC;
  const int s = rest % L;
  rest /= L;
  const int bb = rest % B;
  const int d = rest / B;
  float acc = cb[c];
  if (d == 0) {
#pragma unroll
    for (int k = 0; k < KC; ++k) {
      const int t = s - (KC - 1) + k;
      if (t >= 0) acc = fmaf(cw[c * KC + k], zx[((size_t)(bb * L + t)) * DPROJ + DI + c], acc);
    }
  } else {
    const int torig = L - 1 - s;
#pragma unroll
    for (int j = 0; j < KC; ++j) {
      const int t = torig + j;
      if (t < L) acc = fmaf(cw[c * KC + (KC - 1 - j)], zx[((size_t)(bb * L + t)) * DPROJ + DI + c], acc);
    }
  }
  xconv[idx] = acc / (1.f + expf(-acc));  // silu
}

// ---------------- dt / log(dA) (scan order per direction) ----------------
__global__ void prep_dt(const float* __restrict__ zx, const float* __restrict__ dt_bias,
                        const float* __restrict__ A_log, float* __restrict__ dtb,
                        float* __restrict__ ldab) {
  const int idx = blockIdx.x * 256 + threadIdx.x;
  if (idx >= 2 * BL * NH) return;
  const int h = idx % NH;
  int rest = idx / NH;
  const int s = rest % L;
  rest /= L;
  const int bb = rest % B;
  const int d = rest / B;
  const int torig = d ? (L - 1 - s) : s;
  const float raw = zx[((size_t)(bb * L + torig)) * DPROJ + DI + CONVC + h] + dt_bias[h];
  const float dt = (raw > 20.f) ? raw : log1pf(expf(raw));
  dtb[idx] = dt;
  ldab[idx] = -expf(A_log[h]) * dt;   // log(dA), always <= 0
}

// ---------------- G-prep: G[i][j] = C_i . B_j per (db, chunk), bf16 ------------
__global__ __launch_bounds__(64) void gprep(
    const float* __restrict__ xconv, short* __restrict__ G) {
  const int db = blockIdx.x, c = blockIdx.y;
  const int l = threadIdx.x, lr = l & 15, lq = l >> 4;
  const size_t base_row = (size_t)db * L + c * 64;
  f32x4 acc[4][4] = {};
#pragma unroll
  for (int ks2 = 0; ks2 < 2; ++ks2) {
    const int n0 = ks2 * 32 + lq * 8;
    bf16x8 pf[4], qf[4];
#pragma unroll
    for (int mi = 0; mi < 4; ++mi)
      pf[mi] = cvt8(xconv + (base_row + mi * 16 + lr) * CONVC + DI + DS + n0, 1.f);
#pragma unroll
    for (int ni = 0; ni < 4; ++ni)
      qf[ni] = cvt8(xconv + (base_row + ni * 16 + lr) * CONVC + DI + n0, 1.f);
#pragma unroll
    for (int mi = 0; mi < 4; ++mi)
#pragma unroll
      for (int ni = 0; ni < 4; ++ni)
        acc[mi][ni] = __builtin_amdgcn_mfma_f32_16x16x32_bf16(pf[mi], qf[ni], acc[mi][ni], 0, 0, 0);
  }
  short* g = G + ((size_t)(db * NC + c) << 12);
#pragma unroll
  for (int mi = 0; mi < 4; ++mi)
#pragma unroll
    for (int ni = 0; ni < 4; ++ni)
#pragma unroll
      for (int r = 0; r < 4; ++r)
        g[(mi * 16 + lq * 4 + r) * 64 + ni * 16 + lr] = f2bf(acc[mi][ni][r]);
}

// ---------------- scanA: chunk-local state S_local + decay product P -----------
// S_local[p][n] = sum_j (dt_j x_j[p] e^{cumE-cum_j}) B[j][n]
__global__ __launch_bounds__(64) void scanA_mfma(
    const float* __restrict__ xconv, const float* __restrict__ dtb,
    const float* __restrict__ ldab, float* __restrict__ Sbuf,
    float* __restrict__ Pbuf) {
  __shared__ short XT[64 * XTS];
  __shared__ short BT[64 * XTS];
  __shared__ float cumL[64];
  const int g = blockIdx.x, c = blockIdx.y;
  const int l = threadIdx.x, lr = l & 15, lq = l >> 4;
  const int hh = g & 15, db = g >> 4;
  const size_t base_row = (size_t)db * L + c * 64;
  const float dt_l = dtb[(base_row + l) * NH + hh];
  float cum = ldab[(base_row + l) * NH + hh];
#pragma unroll
  for (int off = 1; off < 64; off <<= 1) {
    float t = __shfl_up(cum, off);
    if (l >= off) cum += t;
  }
  cumL[l] = cum;
  const float cumE = __shfl(cum, 63);
  for (int j0 = 0; j0 < 64; j0 += 8) {
    bf16x8 xw, bw;
#pragma unroll
    for (int jj = 0; jj < 8; ++jj) {
      const float* row = xconv + (base_row + j0 + jj) * CONVC;
      const float dtj = __shfl(dt_l, j0 + jj);
      xw[jj] = f2bf(row[hh * 64 + l] * dtj);
      bw[jj] = f2bf(row[DI + l]);
    }
    *(bf16x8*)&XT[l * XTS + j0] = xw;
    *(bf16x8*)&BT[l * XTS + j0] = bw;
  }
  __syncthreads();
  f32x4 acc[4][4] = {};
#pragma unroll
  for (int ks2 = 0; ks2 < 2; ++ks2) {
    const int j0 = ks2 * 32 + lq * 8;
    const float4 c0 = *(const float4*)&cumL[j0];
    const float4 c1 = *(const float4*)&cumL[j0 + 4];
    float w[8] = {__expf(cumE - c0.x), __expf(cumE - c0.y), __expf(cumE - c0.z), __expf(cumE - c0.w),
                  __expf(cumE - c1.x), __expf(cumE - c1.y), __expf(cumE - c1.z), __expf(cumE - c1.w)};
    bf16x8 pf[4], qf[4];
#pragma unroll
    for (int mi = 0; mi < 4; ++mi) {
      const bf16x8 raw = *(const bf16x8*)&XT[(mi * 16 + lr) * XTS + j0];
#pragma unroll
      for (int jj = 0; jj < 8; ++jj) pf[mi][jj] = f2bf(bf2f(raw[jj]) * w[jj]);
    }
#pragma unroll
    for (int ni = 0; ni < 4; ++ni)
      qf[ni] = *(const bf16x8*)&BT[(ni * 16 + lr) * XTS + j0];
#pragma unroll
    for (int mi = 0; mi < 4; ++mi)
#pragma unroll
      for (int ni = 0; ni < 4; ++ni)
        acc[mi][ni] = __builtin_amdgcn_mfma_f32_16x16x32_bf16(pf[mi], qf[ni], acc[mi][ni], 0, 0, 0);
  }
  float* so = Sbuf + ((size_t)g * NC + c) * 4096;
#pragma unroll
  for (int mi = 0; mi < 4; ++mi)
#pragma unroll
    for (int ni = 0; ni < 4; ++ni)
#pragma unroll
      for (int r = 0; r < 4; ++r)
        so[(mi * 16 + lq * 4 + r) * 64 + ni * 16 + lr] = acc[mi][ni][r];
  if (l == 0) Pbuf[g * NC + c] = __expf(cumE);
}

// ---------------- chain (unchanged) ----------------
__global__ void scan_chain(float* __restrict__ Sbuf, const float* __restrict__ Pbuf) {
  const int idx = blockIdx.x * 256 + threadIdx.x;
  const int g = idx >> 12;
  const int e = idx & 4095;
  float run = 0.f;
  float* base = Sbuf + (size_t)g * NC * 4096 + e;
  for (int c = 0; c < NC; ++c) {
    const float sc = base[(size_t)c * 4096];
    const float pc = Pbuf[g * NC + c];
    base[(size_t)c * 4096] = run;
    run = pc * run + sc;
  }
}

// ---------------- scanC: Y[i][p] = e^{cum_i} C_i.S_in[p] + sum_{j<=i} mask*G*Xdt
__global__ __launch_bounds__(64) void scanC_mfma(
    const float* __restrict__ xconv, const float* __restrict__ dtb,
    const float* __restrict__ ldab, const short* __restrict__ G,
    const float* __restrict__ Sbuf, float* __restrict__ yraw) {
  __shared__ short XT[64 * XTS];
  __shared__ float cumL[64];
  const int g = blockIdx.x, c = blockIdx.y;
  const int l = threadIdx.x, lr = l & 15, lq = l >> 4;
  const int hh = g & 15, db = g >> 4;
  const size_t base_row = (size_t)db * L + c * 64;
  const float dt_l = dtb[(base_row + l) * NH + hh];
  float cum = ldab[(base_row + l) * NH + hh];
#pragma unroll
  for (int off = 1; off < 64; off <<= 1) {
    float t = __shfl_up(cum, off);
    if (l >= off) cum += t;
  }
  cumL[l] = cum;
  for (int j0 = 0; j0 < 64; j0 += 8) {
    bf16x8 xw;
#pragma unroll
    for (int jj = 0; jj < 8; ++jj) {
      const float* row = xconv + (base_row + j0 + jj) * CONVC;
      const float dtj = __shfl(dt_l, j0 + jj);
      xw[jj] = f2bf(row[hh * 64 + l] * dtj);
    }
    *(bf16x8*)&XT[l * XTS + j0] = xw;
  }
  __syncthreads();
  const float* Sin = Sbuf + ((size_t)g * NC + c) * 4096;
  const short* Gp = G + ((size_t)(db * NC + c) << 12);
  float sc[4], ci[4];
#pragma unroll
  for (int mi = 0; mi < 4; ++mi) {
    ci[mi] = cumL[mi * 16 + lr];
    sc[mi] = __expf(ci[mi]);
  }
  f32x4 acc[4][4] = {};
#pragma unroll
  for (int ks2 = 0; ks2 < 2; ++ks2) {
    const int n0 = ks2 * 32 + lq * 8;
    // ---- Yoff: P = e^{cum_i} * C_i[n], Q = S_in[p][n]
    {
      bf16x8 pf[4], qf[4];
#pragma unroll
      for (int mi = 0; mi < 4; ++mi)
        pf[mi] = cvt8(xconv + (base_row + mi * 16 + lr) * CONVC + DI + DS + n0, sc[mi]);
#pragma unroll
      for (int ni = 0; ni < 4; ++ni)
        qf[ni] = cvt8(Sin + (ni * 16 + lr) * 64 + n0, 1.f);
#pragma unroll
      for (int mi = 0; mi < 4; ++mi)
#pragma unroll
        for (int ni = 0; ni < 4; ++ni)
          acc[mi][ni] = __builtin_amdgcn_mfma_f32_16x16x32_bf16(pf[mi], qf[ni], acc[mi][ni], 0, 0, 0);
    }
    // ---- Ylocal: P = G[i][j] * mask(i,j), Q = XT[p][j]
    {
      const float4 c0 = *(const float4*)&cumL[n0];
      const float4 c1 = *(const float4*)&cumL[n0 + 4];
      const float cj[8] = {c0.x, c0.y, c0.z, c0.w, c1.x, c1.y, c1.z, c1.w};
      bf16x8 pf[4], qf[4];
#pragma unroll
      for (int mi = 0; mi < 4; ++mi) {
        const int i = mi * 16 + lr;
        const bf16x8 gv = *(const bf16x8*)&Gp[i * 64 + n0];
#pragma unroll
        for (int jj = 0; jj < 8; ++jj) {
          const float m = (n0 + jj <= i) ? __expf(ci[mi] - cj[jj]) : 0.f;
          pf[mi][jj] = f2bf(bf2f(gv[jj]) * m);
        }
      }
#pragma unroll
      for (int ni = 0; ni < 4; ++ni)
        qf[ni] = *(const bf16x8*)&XT[(ni * 16 + lr) * XTS + n0];
#pragma unroll
      for (int mi = 0; mi < 4; ++mi)
#pragma unroll
        for (int ni = 0; ni < 4; ++ni)
          acc[mi][ni] = __builtin_amdgcn_mfma_f32_16x16x32_bf16(pf[mi], qf[ni], acc[mi][ni], 0, 0, 0);
    }
  }
#pragma unroll
  for (int mi = 0; mi < 4; ++mi)
#pragma unroll
    for (int ni = 0; ni < 4; ++ni)
#pragma unroll
      for (int r = 0; r < 4; ++r)
        yraw[(base_row + mi * 16 + lq * 4 + r) * DI + hh * 64 + ni * 16 + lr] = acc[mi][ni][r];
}

// ---------------- gate + D*x + RMSNorm + combine ----------------
__global__ __launch_bounds__(256) void gate_norm(
    const float* __restrict__ zx, const float* __restrict__ yraw,
    const float* __restrict__ xconv, const float* __restrict__ Dpar,
    const float* __restrict__ nw, float* __restrict__ ycomb) {
  const int bt = blockIdx.x;
  const int b = bt / L, t = bt % L;
  const int tid = threadIdx.x;
  const float* z = zx + (size_t)bt * DPROJ;
  const float* y0 = yraw + ((size_t)b * L + t) * DI;
  const float* y1 = yraw + ((size_t)(B + b) * L + (L - 1 - t)) * DI;
  const float* x0 = xconv + ((size_t)b * L + t) * CONVC;
  const float* x1 = xconv + ((size_t)(B + b) * L + (L - 1 - t)) * CONVC;
  float a0[4], a1[4];
  float s0 = 0.f, s1 = 0.f;
#pragma unroll
  for (int r = 0; r < 4; ++r) {
    const int cc = r * 256 + tid;
    const float zv = z[cc];
    const float gz = zv / (1.f + expf(-zv));
    const float dp = Dpar[cc >> 6];
    a0[r] = (y0[cc] + dp * x0[cc]) * gz;
    a1[r] = (y1[cc] + dp * x1[cc]) * gz;
    s0 += a0[r] * a0[r];
    s1 += a1[r] * a1[r];
  }
#pragma unroll
  for (int off = 32; off > 0; off >>= 1) {
    s0 += __shfl_down(s0, off);
    s1 += __shfl_down(s1, off);
  }
  __shared__ float rs0[4], rs1[4];
  const int w = tid >> 6;
  if ((tid & 63) == 0) { rs0[w] = s0; rs1[w] = s1; }
  __syncthreads();
  s0 = rs0[0] + rs0[1] + rs0[2] + rs0[3];
  s1 = rs1[0] + rs1[1] + rs1[2] + rs1[3];
  const float r0 = rsqrtf(s0 * (1.f / DI) + 1e-5f);
  const float r1 = rsqrtf(s1 * (1.f / DI) + 1e-5f);
  float* oc = ycomb + (size_t)bt * DI;
#pragma unroll
  for (int r = 0; r < 4; ++r) {
    const int cc = r * 256 + tid;
    oc[cc] = nw[cc] * (a0[r] * r0 + a1[r] * r1);
  }
}

// ---------------- fold W_out @ Wp_out -> Wc (1024x80) --------------------------
__global__ void fuse_out(const float* __restrict__ Wo, const float* __restrict__ Wpo,
                         float* __restrict__ Wc) {
  const int idx = blockIdx.x * 256 + threadIdx.x;
  if (idx >= DI * DIN) return;
  const int c = idx / DIN, d = idx % DIN;
  float acc = 0.f;
  for (int m = 0; m < DM; ++m)
    acc = fmaf(Wo[(size_t)c * DM + m], Wpo[(size_t)m * DIN + d], acc);
  Wc[idx] = acc;
}

extern "C" void kernel_launch(void* const* d_in, const int* in_sizes, int n_in,
                              void* d_out, int out_size, void* d_ws, size_t ws_size,
                              hipStream_t stream) {
  const float* x       = (const float*)d_in[0];
  const float* Wp_in   = (const float*)d_in[1];
  const float* bp_in   = (const float*)d_in[2];
  const float* W_in    = (const float*)d_in[3];
  const float* b_in    = (const float*)d_in[4];
  const float* conv_w  = (const float*)d_in[5];
  const float* conv_b  = (const float*)d_in[6];
  const float* dt_bias = (const float*)d_in[7];
  const float* A_log   = (const float*)d_in[8];
  const float* Dpar    = (const float*)d_in[9];
  const float* norm_w  = (const float*)d_in[10];
  const float* W_out   = (const float*)d_in[11];
  const float* Wp_out  = (const float*)d_in[12];
  const float* bp_out  = (const float*)d_in[13];
  float* out = (float*)d_out;

  char* p = (char*)d_ws;
  __hip_bfloat16* hbf = (__hip_bfloat16*)p; p += (size_t)BL * DM * 2;
  __hip_bfloat16* Wt  = (__hip_bfloat16*)p; p += (size_t)NPAD * DM * 2;
  float* zx    = (float*)p; p += (size_t)BL * DPROJ * 4;
  float* xconv = (float*)p; p += (size_t)2 * BL * CONVC * 4;
  float* dtb   = (float*)p; p += (size_t)2 * BL * NH * 4;
  float* ldab  = (float*)p; p += (size_t)2 * BL * NH * 4;
  float* Sbuf  = (float*)p; p += (size_t)NG * NC * HD * DS * 4;
  float* Pbuf  = (float*)p; p += (size_t)NG * NC * 4;
  float* yraw  = (float*)p; p += (size_t)2 * BL * DI * 4;
  float* ycomb = (float*)p; p += (size_t)BL * DI * 4;
  float* Wc    = (float*)p; p += (size_t)DI * DIN * 4;
  short* G     = (short*)p; p += (size_t)2 * B * NC * 64 * 64 * 2;
  float* part  = zx;   // alias: zx dead after gate_norm; 21 MB fits
  (void)ws_size; (void)in_sizes; (void)n_in; (void)out_size;

  // 1. h = bf16(x @ Wp_in + bp_in)
  gemm_bias<__hip_bfloat16><<<dim3(BL / GBM, (DM + GBN - 1) / GBN), 256, 0, stream>>>(
      x, Wp_in, bp_in, hbf, BL, DM, DIN);
  // 1b. Wt = bf16(W_in^T), padded
  prep_wt<<<(NPAD * DM + 255) / 256, 256, 0, stream>>>(W_in, Wt);
  // 2. zxbcdt = h @ W_in + b_in (bf16 MFMA)
  gemm_mfma_bt<<<dim3(BL / 128, NPAD / 128), 256, 0, stream>>>(
      hbf, Wt, b_in, zx, BL, DPROJ, DM);
  // 3. conv + silu; dt/log-dA
  prep_conv<<<(2 * BL * CONVC + 255) / 256, 256, 0, stream>>>(zx, conv_w, conv_b, xconv);
  prep_dt<<<(2 * BL * NH + 255) / 256, 256, 0, stream>>>(zx, dt_bias, A_log, dtb, ldab);
  // 4. chunked scan via MFMA
  gprep<<<dim3(2 * B, NC), 64, 0, stream>>>(xconv, G);
  scanA_mfma<<<dim3(NG, NC), 64, 0, stream>>>(xconv, dtb, ldab, Sbuf, Pbuf);
  scan_chain<<<(NG * HD * DS) / 256, 256, 0, stream>>>(Sbuf, Pbuf);
  scanC_mfma<<<dim3(NG, NC), 64, 0, stream>>>(xconv, dtb, ldab, G, Sbuf, yraw);
  // 5. gate + D*x + RMSNorm + combine
  gate_norm<<<BL, 256, 0, stream>>>(zx, yraw, xconv, Dpar, norm_w, ycomb);
  // 6. Wc = W_out @ Wp_out
  fuse_out<<<(DI * DIN + 255) / 256, 256, 0, stream>>>(W_out, Wp_out, Wc);
  // 7. out = ycomb @ Wc + bp_out (split-K)
  gemm_final_splitk<<<dim3(BL / 64, KSPLIT), 256, 0, stream>>>(ycomb, Wc, part);
  reduce_final<<<(BL * DIN + 255) / 256, 256, 0, stream>>>(part, bp_out, out);
}

// Round 7
// 331.085 us; speedup vs baseline: 2.4187x; 1.0913x over previous
//
#include <hip/hip_runtime.h>
#include <hip/hip_bf16.h>

constexpr int B = 2;
constexpr int L = 2048;
constexpr int DIN = 80;
constexpr int DM = 512;
constexpr int DI = 1024;
constexpr int DS = 64;
constexpr int KC = 7;
constexpr int HD = 64;
constexpr int NH = 16;                    // DI/HD
constexpr int CONVC = DI + 2 * DS;        // 1152
constexpr int DPROJ = 2 * DI + 2 * DS + NH; // 2192
constexpr int NPAD = 2304;                // DPROJ padded to 18*128
constexpr int BL = B * L;                 // 4096
constexpr int CHUNK = 64;
constexpr int NC = L / CHUNK;             // 32
constexpr int NG = 2 * B * NH;            // 64 scan groups (dir,b,head)
constexpr int KSPLIT = 16;                // final GEMM K-split
constexpr int XTS = 72;                   // LDS transposed-tile row stride (bf16)
constexpr int TSEG = 32;                  // conv time-segment per thread

typedef __attribute__((ext_vector_type(8))) short bf16x8;
typedef __attribute__((ext_vector_type(4))) float f32x4;

__device__ inline short f2bf(float f) {
  union { float f; unsigned u; } v; v.f = f;
  unsigned r = (v.u + 0x7FFF + ((v.u >> 16) & 1)) >> 16;  // RNE
  return (short)r;
}
__device__ inline float bf2f(short s) {
  union { unsigned u; float f; } v; v.u = ((unsigned)(unsigned short)s) << 16;
  return v.f;
}
// load 8 contiguous fp32, scale, convert to bf16x8 fragment
__device__ inline bf16x8 cvt8(const float* p, float s) {
  const float4 a = *(const float4*)p;
  const float4 b = *(const float4*)(p + 4);
  bf16x8 r;
  r[0] = f2bf(a.x * s); r[1] = f2bf(a.y * s); r[2] = f2bf(a.z * s); r[3] = f2bf(a.w * s);
  r[4] = f2bf(b.x * s); r[5] = f2bf(b.y * s); r[6] = f2bf(b.z * s); r[7] = f2bf(b.w * s);
  return r;
}

// ---------------- fp32 tiled GEMM with bias: C[M,N] = A[M,K]*Bm[K,N] + bias[N]
constexpr int GBM = 128, GBN = 128, GBK = 16;

template <typename OutT>
__global__ __launch_bounds__(256) void gemm_bias(
    const float* __restrict__ A, const float* __restrict__ Bm,
    const float* __restrict__ bias, OutT* __restrict__ C,
    int M, int N, int K) {
  __shared__ float As[GBK][GBM + 4];
  __shared__ float Bs[GBK][GBN + 4];
  const int m0 = blockIdx.x * GBM;
  const int n0 = blockIdx.y * GBN;
  const int tid = threadIdx.x;
  const int tm = tid >> 4, tn = tid & 15;
  float acc[8][8] = {};
  const int arow = tid >> 2, acol = (tid & 3) << 2;
  const int brow = tid >> 5, bcol = (tid & 31) << 2;
  for (int k0 = 0; k0 < K; k0 += GBK) {
#pragma unroll
    for (int r = 0; r < 2; ++r) {
      int m = m0 + arow + r * 64;
      float4 v = make_float4(0.f, 0.f, 0.f, 0.f);
      if (m < M) v = *(const float4*)(A + (size_t)m * K + k0 + acol);
      As[acol + 0][arow + r * 64] = v.x;
      As[acol + 1][arow + r * 64] = v.y;
      As[acol + 2][arow + r * 64] = v.z;
      As[acol + 3][arow + r * 64] = v.w;
    }
#pragma unroll
    for (int r = 0; r < 2; ++r) {
      int kk = brow + r * 8;
      int n = n0 + bcol;
      float4 v = make_float4(0.f, 0.f, 0.f, 0.f);
      if (n < N) v = *(const float4*)(Bm + (size_t)(k0 + kk) * N + n);
      *(float4*)&Bs[kk][bcol] = v;
    }
    __syncthreads();
#pragma unroll
    for (int k = 0; k < GBK; ++k) {
      float a[8], bb[8];
#pragma unroll
      for (int i = 0; i < 8; ++i) a[i] = As[k][tm * 8 + i];
#pragma unroll
      for (int j = 0; j < 8; ++j) bb[j] = Bs[k][tn * 8 + j];
#pragma unroll
      for (int i = 0; i < 8; ++i)
#pragma unroll
        for (int j = 0; j < 8; ++j)
          acc[i][j] = fmaf(a[i], bb[j], acc[i][j]);
    }
    __syncthreads();
  }
#pragma unroll
  for (int i = 0; i < 8; ++i) {
    int m = m0 + tm * 8 + i;
    if (m >= M) continue;
#pragma unroll
    for (int j = 0; j < 8; ++j) {
      int n = n0 + tn * 8 + j;
      if (n < N) C[(size_t)m * N + n] = (OutT)(acc[i][j] + bias[n]);
    }
  }
}

// ---------------- W_in -> transposed, padded bf16 [NPAD][DM] --------------------
__global__ void prep_wt(const float* __restrict__ W_in, __hip_bfloat16* __restrict__ Wt) {
  const int idx = blockIdx.x * 256 + threadIdx.x;
  if (idx >= NPAD * DM) return;
  const int n = idx % NPAD;
  const int k = idx / NPAD;
  const float v = (n < DPROJ) ? W_in[(size_t)k * DPROJ + n] : 0.f;
  Wt[(size_t)n * DM + k] = (__hip_bfloat16)v;
}

// ---------------- bf16 MFMA GEMM: C[M,N] = A[M,K] * Bt[N,K]^T + bias -----------
__global__ __launch_bounds__(256) void gemm_mfma_bt(
    const __hip_bfloat16* __restrict__ A, const __hip_bfloat16* __restrict__ Bt,
    const float* __restrict__ bias, float* __restrict__ C,
    int M, int N, int K) {
  __shared__ short As[4 * 128 * 8];
  __shared__ short Bs[4 * 128 * 8];
  const int tid = threadIdx.x;
  const int l = tid & 63;
  const int wv = tid >> 6;
  const int wr = wv >> 1, wc = wv & 1;
  const int m0 = blockIdx.x * 128;
  const int n0 = blockIdx.y * 128;
  const int ks = l >> 4, lr = l & 15;
  f32x4 acc[4][4] = {};
  for (int k0 = 0; k0 < K; k0 += 32) {
#pragma unroll
    for (int i = 0; i < 2; ++i) {
      const int t = (wv * 2 + i) * 64 + l;
      const int tks = t >> 7, trow = t & 127;
      __builtin_amdgcn_global_load_lds(
          (const __attribute__((address_space(1))) unsigned int*)(A + (size_t)(m0 + trow) * K + k0 + tks * 8),
          (__attribute__((address_space(3))) unsigned int*)(As + (size_t)(wv * 2 + i) * 512),
          16, 0, 0);
      __builtin_amdgcn_global_load_lds(
          (const __attribute__((address_space(1))) unsigned int*)(Bt + (size_t)(n0 + trow) * K + k0 + tks * 8),
          (__attribute__((address_space(3))) unsigned int*)(Bs + (size_t)(wv * 2 + i) * 512),
          16, 0, 0);
    }
    __syncthreads();
    bf16x8 af[4], bfr[4];
#pragma unroll
    for (int mi = 0; mi < 4; ++mi)
      af[mi] = *(const bf16x8*)&As[(size_t)(ks * 128 + wr * 64 + mi * 16 + lr) * 8];
#pragma unroll
    for (int ni = 0; ni < 4; ++ni)
      bfr[ni] = *(const bf16x8*)&Bs[(size_t)(ks * 128 + wc * 64 + ni * 16 + lr) * 8];
#pragma unroll
    for (int mi = 0; mi < 4; ++mi)
#pragma unroll
      for (int ni = 0; ni < 4; ++ni)
        acc[mi][ni] = __builtin_amdgcn_mfma_f32_16x16x32_bf16(af[mi], bfr[ni], acc[mi][ni], 0, 0, 0);
    __syncthreads();
  }
#pragma unroll
  for (int mi = 0; mi < 4; ++mi) {
    const int row = m0 + wr * 64 + mi * 16 + (l >> 4) * 4;
#pragma unroll
    for (int ni = 0; ni < 4; ++ni) {
      const int col = n0 + wc * 64 + ni * 16 + lr;
      if (col < N) {
        const float bv = bias[col];
#pragma unroll
        for (int r = 0; r < 4; ++r)
          C[(size_t)(row + r) * N + col] = acc[mi][ni][r] + bv;
      }
    }
  }
}

// ---------------- final GEMM split-K ------------------------------------------
__global__ __launch_bounds__(256) void gemm_final_splitk(
    const float* __restrict__ Acf, const float* __restrict__ Wc,
    float* __restrict__ part) {
  __shared__ float As[64][65];
  __shared__ float Bs[64][80];
  const int tid = threadIdx.x;
  const int m0 = blockIdx.x * 64;
  const int k0 = blockIdx.y * 64;
  {
    const int r = tid >> 2, q = tid & 3;
#pragma unroll
    for (int j = 0; j < 4; ++j) {
      const int col = q * 16 + j * 4;
      float4 v = *(const float4*)(Acf + (size_t)(m0 + r) * DI + k0 + col);
      As[r][col + 0] = v.x; As[r][col + 1] = v.y;
      As[r][col + 2] = v.z; As[r][col + 3] = v.w;
    }
#pragma unroll
    for (int j = 0; j < 5; ++j) {
      const int col = (q * 5 + j) * 4;
      float4 v = *(const float4*)(Wc + (size_t)(k0 + r) * DIN + col);
      *(float4*)&Bs[r][col] = v;
    }
  }
  __syncthreads();
  const int r0 = (tid >> 4) * 4;
  const int n0 = (tid & 15) * 5;
  float acc[4][5] = {};
  for (int k = 0; k < 64; ++k) {
    float a[4];
#pragma unroll
    for (int i = 0; i < 4; ++i) a[i] = As[r0 + i][k];
#pragma unroll
    for (int j = 0; j < 5; ++j) {
      const float bv = Bs[k][n0 + j];
#pragma unroll
      for (int i = 0; i < 4; ++i) acc[i][j] = fmaf(a[i], bv, acc[i][j]);
    }
  }
#pragma unroll
  for (int i = 0; i < 4; ++i) {
    float* o = part + ((size_t)blockIdx.y * BL + m0 + r0 + i) * DIN + n0;
#pragma unroll
    for (int j = 0; j < 5; ++j) o[j] = acc[i][j];
  }
}

__global__ __launch_bounds__(256) void reduce_final(
    const float* __restrict__ part, const float* __restrict__ bias,
    float* __restrict__ out) {
  const int idx = blockIdx.x * 256 + threadIdx.x;
  if (idx >= BL * DIN) return;
  const int n = idx % DIN;
  float acc = bias[n];
#pragma unroll
  for (int s = 0; s < KSPLIT; ++s) acc += part[(size_t)s * BL * DIN + idx];
  out[idx] = acc;
}

// ---------------- conv both directions in one pass (rolling window) ------------
// Thread = one channel column; walks orig-time [t0-6, t0+TSEG+6).
// Window w0..w6 holds zx[t-6..t]. Fwd out at t: sum wt[k]*w[k].
// Bwd out at torig=t-6 (scan pos s=L-1-torig): sum wt[6-j]*w[j].
__global__ __launch_bounds__(128) void prep_conv2(
    const float* __restrict__ zx, const float* __restrict__ cw,
    const float* __restrict__ cb, float* __restrict__ xconv) {
  const int c = blockIdx.x * 128 + threadIdx.x;   // 0..1151
  const int b = blockIdx.z;
  const int t0 = blockIdx.y * TSEG;
  const float wt0 = cw[c * KC + 0], wt1 = cw[c * KC + 1], wt2 = cw[c * KC + 2],
              wt3 = cw[c * KC + 3], wt4 = cw[c * KC + 4], wt5 = cw[c * KC + 5],
              wt6 = cw[c * KC + 6];
  const float bias = cb[c];
  const float* src = zx + (size_t)b * L * DPROJ + DI + c;
  float* dstF = xconv + (size_t)b * L * CONVC + c;
  float* dstB = xconv + (size_t)(B + b) * L * CONVC + c;
  float w0 = 0.f, w1 = 0.f, w2 = 0.f, w3 = 0.f, w4 = 0.f, w5 = 0.f, w6 = 0.f;
  for (int t = t0 - 6; t < t0 + TSEG + 6; ++t) {
    float v = 0.f;
    if (t >= 0 && t < L) v = src[(size_t)t * DPROJ];
    w0 = w1; w1 = w2; w2 = w3; w3 = w4; w4 = w5; w5 = w6; w6 = v;
    if (t >= t0 && t < t0 + TSEG) {
      float a = bias + wt0 * w0 + wt1 * w1 + wt2 * w2 + wt3 * w3 + wt4 * w4 +
                wt5 * w5 + wt6 * w6;
      dstF[(size_t)t * CONVC] = a / (1.f + expf(-a));
    }
    const int torig = t - 6;
    if (torig >= t0 && torig < t0 + TSEG) {
      float a = bias + wt6 * w0 + wt5 * w1 + wt4 * w2 + wt3 * w3 + wt2 * w4 +
                wt1 * w5 + wt0 * w6;
      dstB[(size_t)(L - 1 - torig) * CONVC] = a / (1.f + expf(-a));
    }
  }
}

// ---------------- dt / log(dA) (scan order per direction) ----------------
__global__ void prep_dt(const float* __restrict__ zx, const float* __restrict__ dt_bias,
                        const float* __restrict__ A_log, float* __restrict__ dtb,
                        float* __restrict__ ldab) {
  const int idx = blockIdx.x * 256 + threadIdx.x;
  if (idx >= 2 * BL * NH) return;
  const int h = idx % NH;
  int rest = idx / NH;
  const int s = rest % L;
  rest /= L;
  const int bb = rest % B;
  const int d = rest / B;
  const int torig = d ? (L - 1 - s) : s;
  const float raw = zx[((size_t)(bb * L + torig)) * DPROJ + DI + CONVC + h] + dt_bias[h];
  const float dt = (raw > 20.f) ? raw : log1pf(expf(raw));
  dtb[idx] = dt;
  ldab[idx] = -expf(A_log[h]) * dt;   // log(dA), always <= 0
}

// ---------------- G-prep: G[i][j] = C_i . B_j per (db, chunk), bf16 ------------
__global__ __launch_bounds__(64) void gprep(
    const float* __restrict__ xconv, short* __restrict__ G) {
  const int db = blockIdx.x, c = blockIdx.y;
  const int l = threadIdx.x, lr = l & 15, lq = l >> 4;
  const size_t base_row = (size_t)db * L + c * 64;
  f32x4 acc[4][4] = {};
#pragma unroll
  for (int ks2 = 0; ks2 < 2; ++ks2) {
    const int n0 = ks2 * 32 + lq * 8;
    bf16x8 pf[4], qf[4];
#pragma unroll
    for (int mi = 0; mi < 4; ++mi)
      pf[mi] = cvt8(xconv + (base_row + mi * 16 + lr) * CONVC + DI + DS + n0, 1.f);
#pragma unroll
    for (int ni = 0; ni < 4; ++ni)
      qf[ni] = cvt8(xconv + (base_row + ni * 16 + lr) * CONVC + DI + n0, 1.f);
#pragma unroll
    for (int mi = 0; mi < 4; ++mi)
#pragma unroll
      for (int ni = 0; ni < 4; ++ni)
        acc[mi][ni] = __builtin_amdgcn_mfma_f32_16x16x32_bf16(pf[mi], qf[ni], acc[mi][ni], 0, 0, 0);
  }
  short* g = G + ((size_t)(db * NC + c) << 12);
#pragma unroll
  for (int mi = 0; mi < 4; ++mi)
#pragma unroll
    for (int ni = 0; ni < 4; ++ni)
#pragma unroll
      for (int r = 0; r < 4; ++r)
        g[(mi * 16 + lq * 4 + r) * 64 + ni * 16 + lr] = f2bf(acc[mi][ni][r]);
}

// ---------------- scanA: chunk-local state S_local + decay product P -----------
__global__ __launch_bounds__(64) void scanA_mfma(
    const float* __restrict__ xconv, const float* __restrict__ dtb,
    const float* __restrict__ ldab, float* __restrict__ Sbuf,
    float* __restrict__ Pbuf) {
  __shared__ short XT[64 * XTS];
  __shared__ short BT[64 * XTS];
  __shared__ float cumL[64];
  const int g = blockIdx.x, c = blockIdx.y;
  const int l = threadIdx.x, lr = l & 15, lq = l >> 4;
  const int hh = g & 15, db = g >> 4;
  const size_t base_row = (size_t)db * L + c * 64;
  const float dt_l = dtb[(base_row + l) * NH + hh];
  float cum = ldab[(base_row + l) * NH + hh];
#pragma unroll
  for (int off = 1; off < 64; off <<= 1) {
    float t = __shfl_up(cum, off);
    if (l >= off) cum += t;
  }
  cumL[l] = cum;
  const float cumE = __shfl(cum, 63);
  for (int j0 = 0; j0 < 64; j0 += 8) {
    bf16x8 xw, bw;
#pragma unroll
    for (int jj = 0; jj < 8; ++jj) {
      const float* row = xconv + (base_row + j0 + jj) * CONVC;
      const float dtj = __shfl(dt_l, j0 + jj);
      xw[jj] = f2bf(row[hh * 64 + l] * dtj);
      bw[jj] = f2bf(row[DI + l]);
    }
    *(bf16x8*)&XT[l * XTS + j0] = xw;
    *(bf16x8*)&BT[l * XTS + j0] = bw;
  }
  __syncthreads();
  f32x4 acc[4][4] = {};
#pragma unroll
  for (int ks2 = 0; ks2 < 2; ++ks2) {
    const int j0 = ks2 * 32 + lq * 8;
    const float4 c0 = *(const float4*)&cumL[j0];
    const float4 c1 = *(const float4*)&cumL[j0 + 4];
    float w[8] = {__expf(cumE - c0.x), __expf(cumE - c0.y), __expf(cumE - c0.z), __expf(cumE - c0.w),
                  __expf(cumE - c1.x), __expf(cumE - c1.y), __expf(cumE - c1.z), __expf(cumE - c1.w)};
    bf16x8 pf[4], qf[4];
#pragma unroll
    for (int mi = 0; mi < 4; ++mi) {
      const bf16x8 raw = *(const bf16x8*)&XT[(mi * 16 + lr) * XTS + j0];
#pragma unroll
      for (int jj = 0; jj < 8; ++jj) pf[mi][jj] = f2bf(bf2f(raw[jj]) * w[jj]);
    }
#pragma unroll
    for (int ni = 0; ni < 4; ++ni)
      qf[ni] = *(const bf16x8*)&BT[(ni * 16 + lr) * XTS + j0];
#pragma unroll
    for (int mi = 0; mi < 4; ++mi)
#pragma unroll
      for (int ni = 0; ni < 4; ++ni)
        acc[mi][ni] = __builtin_amdgcn_mfma_f32_16x16x32_bf16(pf[mi], qf[ni], acc[mi][ni], 0, 0, 0);
  }
  float* so = Sbuf + ((size_t)g * NC + c) * 4096;
#pragma unroll
  for (int mi = 0; mi < 4; ++mi)
#pragma unroll
    for (int ni = 0; ni < 4; ++ni)
#pragma unroll
      for (int r = 0; r < 4; ++r)
        so[(mi * 16 + lq * 4 + r) * 64 + ni * 16 + lr] = acc[mi][ni][r];
  if (l == 0) Pbuf[g * NC + c] = __expf(cumE);
}

// ---------------- chain ----------------
__global__ void scan_chain(float* __restrict__ Sbuf, const float* __restrict__ Pbuf) {
  const int idx = blockIdx.x * 256 + threadIdx.x;
  const int g = idx >> 12;
  const int e = idx & 4095;
  float run = 0.f;
  float* base = Sbuf + (size_t)g * NC * 4096 + e;
  for (int c = 0; c < NC; ++c) {
    const float sc = base[(size_t)c * 4096];
    const float pc = Pbuf[g * NC + c];
    base[(size_t)c * 4096] = run;
    run = pc * run + sc;
  }
}

// ---------------- scanC: Y[i][p] = e^{cum_i} C_i.S_in[p] + sum_{j<=i} mask*G*Xdt
__global__ __launch_bounds__(64) void scanC_mfma(
    const float* __restrict__ xconv, const float* __restrict__ dtb,
    const float* __restrict__ ldab, const short* __restrict__ G,
    const float* __restrict__ Sbuf, float* __restrict__ yraw) {
  __shared__ short XT[64 * XTS];
  __shared__ float cumL[64];
  const int g = blockIdx.x, c = blockIdx.y;
  const int l = threadIdx.x, lr = l & 15, lq = l >> 4;
  const int hh = g & 15, db = g >> 4;
  const size_t base_row = (size_t)db * L + c * 64;
  const float dt_l = dtb[(base_row + l) * NH + hh];
  float cum = ldab[(base_row + l) * NH + hh];
#pragma unroll
  for (int off = 1; off < 64; off <<= 1) {
    float t = __shfl_up(cum, off);
    if (l >= off) cum += t;
  }
  cumL[l] = cum;
  for (int j0 = 0; j0 < 64; j0 += 8) {
    bf16x8 xw;
#pragma unroll
    for (int jj = 0; jj < 8; ++jj) {
      const float* row = xconv + (base_row + j0 + jj) * CONVC;
      const float dtj = __shfl(dt_l, j0 + jj);
      xw[jj] = f2bf(row[hh * 64 + l] * dtj);
    }
    *(bf16x8*)&XT[l * XTS + j0] = xw;
  }
  __syncthreads();
  const float* Sin = Sbuf + ((size_t)g * NC + c) * 4096;
  const short* Gp = G + ((size_t)(db * NC + c) << 12);
  float sc[4], ci[4];
#pragma unroll
  for (int mi = 0; mi < 4; ++mi) {
    ci[mi] = cumL[mi * 16 + lr];
    sc[mi] = __expf(ci[mi]);
  }
  f32x4 acc[4][4] = {};
#pragma unroll
  for (int ks2 = 0; ks2 < 2; ++ks2) {
    const int n0 = ks2 * 32 + lq * 8;
    {
      bf16x8 pf[4], qf[4];
#pragma unroll
      for (int mi = 0; mi < 4; ++mi)
        pf[mi] = cvt8(xconv + (base_row + mi * 16 + lr) * CONVC + DI + DS + n0, sc[mi]);
#pragma unroll
      for (int ni = 0; ni < 4; ++ni)
        qf[ni] = cvt8(Sin + (ni * 16 + lr) * 64 + n0, 1.f);
#pragma unroll
      for (int mi = 0; mi < 4; ++mi)
#pragma unroll
        for (int ni = 0; ni < 4; ++ni)
          acc[mi][ni] = __builtin_amdgcn_mfma_f32_16x16x32_bf16(pf[mi], qf[ni], acc[mi][ni], 0, 0, 0);
    }
    {
      const float4 c0 = *(const float4*)&cumL[n0];
      const float4 c1 = *(const float4*)&cumL[n0 + 4];
      const float cj[8] = {c0.x, c0.y, c0.z, c0.w, c1.x, c1.y, c1.z, c1.w};
      bf16x8 pf[4], qf[4];
#pragma unroll
      for (int mi = 0; mi < 4; ++mi) {
        const int i = mi * 16 + lr;
        const bf16x8 gv = *(const bf16x8*)&Gp[i * 64 + n0];
#pragma unroll
        for (int jj = 0; jj < 8; ++jj) {
          const float m = (n0 + jj <= i) ? __expf(ci[mi] - cj[jj]) : 0.f;
          pf[mi][jj] = f2bf(bf2f(gv[jj]) * m);
        }
      }
#pragma unroll
      for (int ni = 0; ni < 4; ++ni)
        qf[ni] = *(const bf16x8*)&XT[(ni * 16 + lr) * XTS + n0];
#pragma unroll
      for (int mi = 0; mi < 4; ++mi)
#pragma unroll
        for (int ni = 0; ni < 4; ++ni)
          acc[mi][ni] = __builtin_amdgcn_mfma_f32_16x16x32_bf16(pf[mi], qf[ni], acc[mi][ni], 0, 0, 0);
    }
  }
#pragma unroll
  for (int mi = 0; mi < 4; ++mi)
#pragma unroll
    for (int ni = 0; ni < 4; ++ni)
#pragma unroll
      for (int r = 0; r < 4; ++r)
        yraw[(base_row + mi * 16 + lq * 4 + r) * DI + hh * 64 + ni * 16 + lr] = acc[mi][ni][r];
}

// ---------------- gate + D*x + RMSNorm + combine ----------------
__global__ __launch_bounds__(256) void gate_norm(
    const float* __restrict__ zx, const float* __restrict__ yraw,
    const float* __restrict__ xconv, const float* __restrict__ Dpar,
    const float* __restrict__ nw, float* __restrict__ ycomb) {
  const int bt = blockIdx.x;
  const int b = bt / L, t = bt % L;
  const int tid = threadIdx.x;
  const float* z = zx + (size_t)bt * DPROJ;
  const float* y0 = yraw + ((size_t)b * L + t) * DI;
  const float* y1 = yraw + ((size_t)(B + b) * L + (L - 1 - t)) * DI;
  const float* x0 = xconv + ((size_t)b * L + t) * CONVC;
  const float* x1 = xconv + ((size_t)(B + b) * L + (L - 1 - t)) * CONVC;
  float a0[4], a1[4];
  float s0 = 0.f, s1 = 0.f;
#pragma unroll
  for (int r = 0; r < 4; ++r) {
    const int cc = r * 256 + tid;
    const float zv = z[cc];
    const float gz = zv / (1.f + expf(-zv));
    const float dp = Dpar[cc >> 6];
    a0[r] = (y0[cc] + dp * x0[cc]) * gz;
    a1[r] = (y1[cc] + dp * x1[cc]) * gz;
    s0 += a0[r] * a0[r];
    s1 += a1[r] * a1[r];
  }
#pragma unroll
  for (int off = 32; off > 0; off >>= 1) {
    s0 += __shfl_down(s0, off);
    s1 += __shfl_down(s1, off);
  }
  __shared__ float rs0[4], rs1[4];
  const int w = tid >> 6;
  if ((tid & 63) == 0) { rs0[w] = s0; rs1[w] = s1; }
  __syncthreads();
  s0 = rs0[0] + rs0[1] + rs0[2] + rs0[3];
  s1 = rs1[0] + rs1[1] + rs1[2] + rs1[3];
  const float r0 = rsqrtf(s0 * (1.f / DI) + 1e-5f);
  const float r1 = rsqrtf(s1 * (1.f / DI) + 1e-5f);
  float* oc = ycomb + (size_t)bt * DI;
#pragma unroll
  for (int r = 0; r < 4; ++r) {
    const int cc = r * 256 + tid;
    oc[cc] = nw[cc] * (a0[r] * r0 + a1[r] * r1);
  }
}

// ---------------- fold W_out @ Wp_out -> Wc (1024x80) --------------------------
__global__ void fuse_out(const float* __restrict__ Wo, const float* __restrict__ Wpo,
                         float* __restrict__ Wc) {
  const int idx = blockIdx.x * 256 + threadIdx.x;
  if (idx >= DI * DIN) return;
  const int c = idx / DIN, d = idx % DIN;
  float acc = 0.f;
  for (int m = 0; m < DM; ++m)
    acc = fmaf(Wo[(size_t)c * DM + m], Wpo[(size_t)m * DIN + d], acc);
  Wc[idx] = acc;
}

extern "C" void kernel_launch(void* const* d_in, const int* in_sizes, int n_in,
                              void* d_out, int out_size, void* d_ws, size_t ws_size,
                              hipStream_t stream) {
  const float* x       = (const float*)d_in[0];
  const float* Wp_in   = (const float*)d_in[1];
  const float* bp_in   = (const float*)d_in[2];
  const float* W_in    = (const float*)d_in[3];
  const float* b_in    = (const float*)d_in[4];
  const float* conv_w  = (const float*)d_in[5];
  const float* conv_b  = (const float*)d_in[6];
  const float* dt_bias = (const float*)d_in[7];
  const float* A_log   = (const float*)d_in[8];
  const float* Dpar    = (const float*)d_in[9];
  const float* norm_w  = (const float*)d_in[10];
  const float* W_out   = (const float*)d_in[11];
  const float* Wp_out  = (const float*)d_in[12];
  const float* bp_out  = (const float*)d_in[13];
  float* out = (float*)d_out;

  char* p = (char*)d_ws;
  __hip_bfloat16* hbf = (__hip_bfloat16*)p; p += (size_t)BL * DM * 2;
  __hip_bfloat16* Wt  = (__hip_bfloat16*)p; p += (size_t)NPAD * DM * 2;
  float* zx    = (float*)p; p += (size_t)BL * DPROJ * 4;
  float* xconv = (float*)p; p += (size_t)2 * BL * CONVC * 4;
  float* dtb   = (float*)p; p += (size_t)2 * BL * NH * 4;
  float* ldab  = (float*)p; p += (size_t)2 * BL * NH * 4;
  float* Sbuf  = (float*)p; p += (size_t)NG * NC * HD * DS * 4;
  float* Pbuf  = (float*)p; p += (size_t)NG * NC * 4;
  float* yraw  = (float*)p; p += (size_t)2 * BL * DI * 4;
  float* ycomb = (float*)p; p += (size_t)BL * DI * 4;
  float* Wc    = (float*)p; p += (size_t)DI * DIN * 4;
  short* G     = (short*)p; p += (size_t)2 * B * NC * 64 * 64 * 2;
  float* part  = zx;   // alias: zx dead after gate_norm; 21 MB fits
  (void)ws_size; (void)in_sizes; (void)n_in; (void)out_size;

  // 1. h = bf16(x @ Wp_in + bp_in)
  gemm_bias<__hip_bfloat16><<<dim3(BL / GBM, (DM + GBN - 1) / GBN), 256, 0, stream>>>(
      x, Wp_in, bp_in, hbf, BL, DM, DIN);
  // 1b. Wt = bf16(W_in^T), padded
  prep_wt<<<(NPAD * DM + 255) / 256, 256, 0, stream>>>(W_in, Wt);
  // 2. zxbcdt = h @ W_in + b_in (bf16 MFMA)
  gemm_mfma_bt<<<dim3(BL / 128, NPAD / 128), 256, 0, stream>>>(
      hbf, Wt, b_in, zx, BL, DPROJ, DM);
  // 3. conv + silu (both dirs, one pass); dt/log-dA
  prep_conv2<<<dim3(CONVC / 128, L / TSEG, B), 128, 0, stream>>>(zx, conv_w, conv_b, xconv);
  prep_dt<<<(2 * BL * NH + 255) / 256, 256, 0, stream>>>(zx, dt_bias, A_log, dtb, ldab);
  // 4. chunked scan via MFMA
  gprep<<<dim3(2 * B, NC), 64, 0, stream>>>(xconv, G);
  scanA_mfma<<<dim3(NG, NC), 64, 0, stream>>>(xconv, dtb, ldab, Sbuf, Pbuf);
  scan_chain<<<(NG * HD * DS) / 256, 256, 0, stream>>>(Sbuf, Pbuf);
  scanC_mfma<<<dim3(NG, NC), 64, 0, stream>>>(xconv, dtb, ldab, G, Sbuf, yraw);
  // 5. gate + D*x + RMSNorm + combine
  gate_norm<<<BL, 256, 0, stream>>>(zx, yraw, xconv, Dpar, norm_w, ycomb);
  // 6. Wc = W_out @ Wp_out
  fuse_out<<<(DI * DIN + 255) / 256, 256, 0, stream>>>(W_out, Wp_out, Wc);
  // 7. out = ycomb @ Wc + bp_out (split-K)
  gemm_final_splitk<<<dim3(BL / 64, KSPLIT), 256, 0, stream>>>(ycomb, Wc, part);
  reduce_final<<<(BL * DIN + 255) / 256, 256, 0, stream>>>(part, bp_out, out);
}

// Round 9
// 294.475 us; speedup vs baseline: 2.7194x; 1.1243x over previous
//
#include <hip/hip_runtime.h>
#include <hip/hip_bf16.h>

constexpr int B = 2;
constexpr int L = 2048;
constexpr int DIN = 80;
constexpr int DM = 512;
constexpr int DI = 1024;
constexpr int DS = 64;
constexpr int KC = 7;
constexpr int HD = 64;
constexpr int NH = 16;                    // DI/HD
constexpr int CONVC = DI + 2 * DS;        // 1152
constexpr int DPROJ = 2 * DI + 2 * DS + NH; // 2192
constexpr int NPAD = 2304;                // DPROJ padded to 18*128
constexpr int BL = B * L;                 // 4096
constexpr int CHUNK = 64;
constexpr int NC = L / CHUNK;             // 32
constexpr int NG = 2 * B * NH;            // 64 scan groups (dir,b,head)
constexpr int KSPLIT = 16;                // final GEMM K-split
constexpr int KSPLIT2 = 8;                // Wc GEMM K-split
constexpr int XTS = 72;                   // LDS transposed-tile row stride (bf16)
constexpr int TSEG = 32;                  // conv time-segment per thread

typedef __attribute__((ext_vector_type(8))) short bf16x8;
typedef __attribute__((ext_vector_type(4))) float f32x4;

__device__ inline short f2bf(float f) {
  union { float f; unsigned u; } v; v.f = f;
  unsigned r = (v.u + 0x7FFF + ((v.u >> 16) & 1)) >> 16;  // RNE
  return (short)r;
}
__device__ inline float bf2f(short s) {
  union { unsigned u; float f; } v; v.u = ((unsigned)(unsigned short)s) << 16;
  return v.f;
}
// load 8 contiguous fp32, scale, convert to bf16x8 fragment
__device__ inline bf16x8 cvt8(const float* p, float s) {
  const float4 a = *(const float4*)p;
  const float4 b = *(const float4*)(p + 4);
  bf16x8 r;
  r[0] = f2bf(a.x * s); r[1] = f2bf(a.y * s); r[2] = f2bf(a.z * s); r[3] = f2bf(a.w * s);
  r[4] = f2bf(b.x * s); r[5] = f2bf(b.y * s); r[6] = f2bf(b.z * s); r[7] = f2bf(b.w * s);
  return r;
}

// ---------------- fp32 tiled GEMM with bias: C[M,N] = A[M,K]*Bm[K,N] + bias[N]
constexpr int GBM = 128, GBN = 128, GBK = 16;

template <typename OutT>
__global__ __launch_bounds__(256) void gemm_bias(
    const float* __restrict__ A, const float* __restrict__ Bm,
    const float* __restrict__ bias, OutT* __restrict__ C,
    int M, int N, int K) {
  __shared__ float As[GBK][GBM + 4];
  __shared__ float Bs[GBK][GBN + 4];
  const int m0 = blockIdx.x * GBM;
  const int n0 = blockIdx.y * GBN;
  const int tid = threadIdx.x;
  const int tm = tid >> 4, tn = tid & 15;
  float acc[8][8] = {};
  const int arow = tid >> 2, acol = (tid & 3) << 2;
  const int brow = tid >> 5, bcol = (tid & 31) << 2;
  for (int k0 = 0; k0 < K; k0 += GBK) {
#pragma unroll
    for (int r = 0; r < 2; ++r) {
      int m = m0 + arow + r * 64;
      float4 v = make_float4(0.f, 0.f, 0.f, 0.f);
      if (m < M) v = *(const float4*)(A + (size_t)m * K + k0 + acol);
      As[acol + 0][arow + r * 64] = v.x;
      As[acol + 1][arow + r * 64] = v.y;
      As[acol + 2][arow + r * 64] = v.z;
      As[acol + 3][arow + r * 64] = v.w;
    }
#pragma unroll
    for (int r = 0; r < 2; ++r) {
      int kk = brow + r * 8;
      int n = n0 + bcol;
      float4 v = make_float4(0.f, 0.f, 0.f, 0.f);
      if (n < N) v = *(const float4*)(Bm + (size_t)(k0 + kk) * N + n);
      *(float4*)&Bs[kk][bcol] = v;
    }
    __syncthreads();
#pragma unroll
    for (int k = 0; k < GBK; ++k) {
      float a[8], bb[8];
#pragma unroll
      for (int i = 0; i < 8; ++i) a[i] = As[k][tm * 8 + i];
#pragma unroll
      for (int j = 0; j < 8; ++j) bb[j] = Bs[k][tn * 8 + j];
#pragma unroll
      for (int i = 0; i < 8; ++i)
#pragma unroll
        for (int j = 0; j < 8; ++j)
          acc[i][j] = fmaf(a[i], bb[j], acc[i][j]);
    }
    __syncthreads();
  }
#pragma unroll
  for (int i = 0; i < 8; ++i) {
    int m = m0 + tm * 8 + i;
    if (m >= M) continue;
#pragma unroll
    for (int j = 0; j < 8; ++j) {
      int n = n0 + tn * 8 + j;
      if (n < N) C[(size_t)m * N + n] = (OutT)(acc[i][j] + bias[n]);
    }
  }
}

// ---------------- W_in -> transposed, padded bf16 [NPAD][DM] --------------------
__global__ void prep_wt(const float* __restrict__ W_in, __hip_bfloat16* __restrict__ Wt) {
  const int idx = blockIdx.x * 256 + threadIdx.x;
  if (idx >= NPAD * DM) return;
  const int n = idx % NPAD;
  const int k = idx / NPAD;
  const float v = (n < DPROJ) ? W_in[(size_t)k * DPROJ + n] : 0.f;
  Wt[(size_t)n * DM + k] = (__hip_bfloat16)v;
}

// ---------------- bf16 MFMA GEMM: C[M,N] = A[M,K] * Bt[N,K]^T + bias -----------
__global__ __launch_bounds__(256) void gemm_mfma_bt(
    const __hip_bfloat16* __restrict__ A, const __hip_bfloat16* __restrict__ Bt,
    const float* __restrict__ bias, float* __restrict__ C,
    int M, int N, int K) {
  __shared__ short As[4 * 128 * 8];
  __shared__ short Bs[4 * 128 * 8];
  const int tid = threadIdx.x;
  const int l = tid & 63;
  const int wv = tid >> 6;
  const int wr = wv >> 1, wc = wv & 1;
  const int m0 = blockIdx.x * 128;
  const int n0 = blockIdx.y * 128;
  const int ks = l >> 4, lr = l & 15;
  f32x4 acc[4][4] = {};
  for (int k0 = 0; k0 < K; k0 += 32) {
#pragma unroll
    for (int i = 0; i < 2; ++i) {
      const int t = (wv * 2 + i) * 64 + l;
      const int tks = t >> 7, trow = t & 127;
      __builtin_amdgcn_global_load_lds(
          (const __attribute__((address_space(1))) unsigned int*)(A + (size_t)(m0 + trow) * K + k0 + tks * 8),
          (__attribute__((address_space(3))) unsigned int*)(As + (size_t)(wv * 2 + i) * 512),
          16, 0, 0);
      __builtin_amdgcn_global_load_lds(
          (const __attribute__((address_space(1))) unsigned int*)(Bt + (size_t)(n0 + trow) * K + k0 + tks * 8),
          (__attribute__((address_space(3))) unsigned int*)(Bs + (size_t)(wv * 2 + i) * 512),
          16, 0, 0);
    }
    __syncthreads();
    bf16x8 af[4], bfr[4];
#pragma unroll
    for (int mi = 0; mi < 4; ++mi)
      af[mi] = *(const bf16x8*)&As[(size_t)(ks * 128 + wr * 64 + mi * 16 + lr) * 8];
#pragma unroll
    for (int ni = 0; ni < 4; ++ni)
      bfr[ni] = *(const bf16x8*)&Bs[(size_t)(ks * 128 + wc * 64 + ni * 16 + lr) * 8];
#pragma unroll
    for (int mi = 0; mi < 4; ++mi)
#pragma unroll
      for (int ni = 0; ni < 4; ++ni)
        acc[mi][ni] = __builtin_amdgcn_mfma_f32_16x16x32_bf16(af[mi], bfr[ni], acc[mi][ni], 0, 0, 0);
    __syncthreads();
  }
#pragma unroll
  for (int mi = 0; mi < 4; ++mi) {
    const int row = m0 + wr * 64 + mi * 16 + (l >> 4) * 4;
#pragma unroll
    for (int ni = 0; ni < 4; ++ni) {
      const int col = n0 + wc * 64 + ni * 16 + lr;
      if (col < N) {
        const float bv = bias[col];
#pragma unroll
        for (int r = 0; r < 4; ++r)
          C[(size_t)(row + r) * N + col] = acc[mi][ni][r] + bv;
      }
    }
  }
}

// ------- skinny GEMM split-K: part[sk][M][80] = A[:,k-slice] * Bm[k-slice,:80]
// grid (M/64, K/64); A row stride = Astride; Bm row stride = 80.
__global__ __launch_bounds__(256) void gemm_skinny_splitk(
    const float* __restrict__ A, const float* __restrict__ Bm,
    float* __restrict__ part, int Astride, int Mtotal) {
  __shared__ float As[64][65];
  __shared__ float Bs[64][80];
  const int tid = threadIdx.x;
  const int m0 = blockIdx.x * 64;
  const int k0 = blockIdx.y * 64;
  {
    const int r = tid >> 2, q = tid & 3;
#pragma unroll
    for (int j = 0; j < 4; ++j) {
      const int col = q * 16 + j * 4;
      float4 v = *(const float4*)(A + (size_t)(m0 + r) * Astride + k0 + col);
      As[r][col + 0] = v.x; As[r][col + 1] = v.y;
      As[r][col + 2] = v.z; As[r][col + 3] = v.w;
    }
#pragma unroll
    for (int j = 0; j < 5; ++j) {
      const int col = (q * 5 + j) * 4;
      float4 v = *(const float4*)(Bm + (size_t)(k0 + r) * DIN + col);
      *(float4*)&Bs[r][col] = v;
    }
  }
  __syncthreads();
  const int r0 = (tid >> 4) * 4;
  const int n0 = (tid & 15) * 5;
  float acc[4][5] = {};
  for (int k = 0; k < 64; ++k) {
    float a[4];
#pragma unroll
    for (int i = 0; i < 4; ++i) a[i] = As[r0 + i][k];
#pragma unroll
    for (int j = 0; j < 5; ++j) {
      const float bv = Bs[k][n0 + j];
#pragma unroll
      for (int i = 0; i < 4; ++i) acc[i][j] = fmaf(a[i], bv, acc[i][j]);
    }
  }
#pragma unroll
  for (int i = 0; i < 4; ++i) {
    float* o = part + ((size_t)blockIdx.y * Mtotal + m0 + r0 + i) * DIN + n0;
#pragma unroll
    for (int j = 0; j < 5; ++j) o[j] = acc[i][j];
  }
}

// ------- reduce split-K partials (+ optional bias over last dim 80) -----------
__global__ __launch_bounds__(256) void reduce_splitk(
    const float* __restrict__ part, const float* __restrict__ bias,
    float* __restrict__ out, int total, int nsl) {
  const int idx = blockIdx.x * 256 + threadIdx.x;
  if (idx >= total) return;
  float acc = bias ? bias[idx % DIN] : 0.f;
  for (int s = 0; s < nsl; ++s) acc += part[(size_t)s * total + idx];
  out[idx] = acc;
}

// ---------------- conv both directions in one pass (rolling window) ------------
__global__ __launch_bounds__(128) void prep_conv2(
    const float* __restrict__ zx, const float* __restrict__ cw,
    const float* __restrict__ cb, float* __restrict__ xconv) {
  const int c = blockIdx.x * 128 + threadIdx.x;   // 0..1151
  const int b = blockIdx.z;
  const int t0 = blockIdx.y * TSEG;
  const float wt0 = cw[c * KC + 0], wt1 = cw[c * KC + 1], wt2 = cw[c * KC + 2],
              wt3 = cw[c * KC + 3], wt4 = cw[c * KC + 4], wt5 = cw[c * KC + 5],
              wt6 = cw[c * KC + 6];
  const float bias = cb[c];
  const float* src = zx + (size_t)b * L * DPROJ + DI + c;
  float* dstF = xconv + (size_t)b * L * CONVC + c;
  float* dstB = xconv + (size_t)(B + b) * L * CONVC + c;
  float w0 = 0.f, w1 = 0.f, w2 = 0.f, w3 = 0.f, w4 = 0.f, w5 = 0.f, w6 = 0.f;
  for (int t = t0 - 6; t < t0 + TSEG + 6; ++t) {
    float v = 0.f;
    if (t >= 0 && t < L) v = src[(size_t)t * DPROJ];
    w0 = w1; w1 = w2; w2 = w3; w3 = w4; w4 = w5; w5 = w6; w6 = v;
    if (t >= t0 && t < t0 + TSEG) {
      float a = bias + wt0 * w0 + wt1 * w1 + wt2 * w2 + wt3 * w3 + wt4 * w4 +
                wt5 * w5 + wt6 * w6;
      dstF[(size_t)t * CONVC] = a / (1.f + expf(-a));
    }
    const int torig = t - 6;
    if (torig >= t0 && torig < t0 + TSEG) {
      float a = bias + wt6 * w0 + wt5 * w1 + wt4 * w2 + wt3 * w3 + wt2 * w4 +
                wt1 * w5 + wt0 * w6;
      dstB[(size_t)(L - 1 - torig) * CONVC] = a / (1.f + expf(-a));
    }
  }
}

// ---------------- dt / log(dA) (scan order per direction) ----------------
__global__ void prep_dt(const float* __restrict__ zx, const float* __restrict__ dt_bias,
                        const float* __restrict__ A_log, float* __restrict__ dtb,
                        float* __restrict__ ldab) {
  const int idx = blockIdx.x * 256 + threadIdx.x;
  if (idx >= 2 * BL * NH) return;
  const int h = idx % NH;
  int rest = idx / NH;
  const int s = rest % L;
  rest /= L;
  const int bb = rest % B;
  const int d = rest / B;
  const int torig = d ? (L - 1 - s) : s;
  const float raw = zx[((size_t)(bb * L + torig)) * DPROJ + DI + CONVC + h] + dt_bias[h];
  const float dt = (raw > 20.f) ? raw : log1pf(expf(raw));
  dtb[idx] = dt;
  ldab[idx] = -expf(A_log[h]) * dt;   // log(dA), always <= 0
}

// ---------------- G-prep: G[i][j] = C_i . B_j per (db, chunk), bf16 ------------
__global__ __launch_bounds__(64) void gprep(
    const float* __restrict__ xconv, short* __restrict__ G) {
  const int db = blockIdx.x, c = blockIdx.y;
  const int l = threadIdx.x, lr = l & 15, lq = l >> 4;
  const size_t base_row = (size_t)db * L + c * 64;
  f32x4 acc[4][4] = {};
#pragma unroll
  for (int ks2 = 0; ks2 < 2; ++ks2) {
    const int n0 = ks2 * 32 + lq * 8;
    bf16x8 pf[4], qf[4];
#pragma unroll
    for (int mi = 0; mi < 4; ++mi)
      pf[mi] = cvt8(xconv + (base_row + mi * 16 + lr) * CONVC + DI + DS + n0, 1.f);
#pragma unroll
    for (int ni = 0; ni < 4; ++ni)
      qf[ni] = cvt8(xconv + (base_row + ni * 16 + lr) * CONVC + DI + n0, 1.f);
#pragma unroll
    for (int mi = 0; mi < 4; ++mi)
#pragma unroll
      for (int ni = 0; ni < 4; ++ni)
        acc[mi][ni] = __builtin_amdgcn_mfma_f32_16x16x32_bf16(pf[mi], qf[ni], acc[mi][ni], 0, 0, 0);
  }
  short* g = G + ((size_t)(db * NC + c) << 12);
#pragma unroll
  for (int mi = 0; mi < 4; ++mi)
#pragma unroll
    for (int ni = 0; ni < 4; ++ni)
#pragma unroll
      for (int r = 0; r < 4; ++r)
        g[(mi * 16 + lq * 4 + r) * 64 + ni * 16 + lr] = f2bf(acc[mi][ni][r]);
}

// ---------------- scanA: chunk-local state S_local + decay product P -----------
__global__ __launch_bounds__(64) void scanA_mfma(
    const float* __restrict__ xconv, const float* __restrict__ dtb,
    const float* __restrict__ ldab, float* __restrict__ Sbuf,
    float* __restrict__ Pbuf) {
  __shared__ short XT[64 * XTS];
  __shared__ short BT[64 * XTS];
  __shared__ float cumL[64];
  const int g = blockIdx.x, c = blockIdx.y;
  const int l = threadIdx.x, lr = l & 15, lq = l >> 4;
  const int hh = g & 15, db = g >> 4;
  const size_t base_row = (size_t)db * L + c * 64;
  const float dt_l = dtb[(base_row + l) * NH + hh];
  float cum = ldab[(base_row + l) * NH + hh];
#pragma unroll
  for (int off = 1; off < 64; off <<= 1) {
    float t = __shfl_up(cum, off);
    if (l >= off) cum += t;
  }
  cumL[l] = cum;
  const float cumE = __shfl(cum, 63);
  for (int j0 = 0; j0 < 64; j0 += 8) {
    bf16x8 xw, bw;
#pragma unroll
    for (int jj = 0; jj < 8; ++jj) {
      const float* row = xconv + (base_row + j0 + jj) * CONVC;
      const float dtj = __shfl(dt_l, j0 + jj);
      xw[jj] = f2bf(row[hh * 64 + l] * dtj);
      bw[jj] = f2bf(row[DI + l]);
    }
    *(bf16x8*)&XT[l * XTS + j0] = xw;
    *(bf16x8*)&BT[l * XTS + j0] = bw;
  }
  __syncthreads();
  f32x4 acc[4][4] = {};
#pragma unroll
  for (int ks2 = 0; ks2 < 2; ++ks2) {
    const int j0 = ks2 * 32 + lq * 8;
    const float4 c0 = *(const float4*)&cumL[j0];
    const float4 c1 = *(const float4*)&cumL[j0 + 4];
    float w[8] = {__expf(cumE - c0.x), __expf(cumE - c0.y), __expf(cumE - c0.z), __expf(cumE - c0.w),
                  __expf(cumE - c1.x), __expf(cumE - c1.y), __expf(cumE - c1.z), __expf(cumE - c1.w)};
    bf16x8 pf[4], qf[4];
#pragma unroll
    for (int mi = 0; mi < 4; ++mi) {
      const bf16x8 raw = *(const bf16x8*)&XT[(mi * 16 + lr) * XTS + j0];
#pragma unroll
      for (int jj = 0; jj < 8; ++jj) pf[mi][jj] = f2bf(bf2f(raw[jj]) * w[jj]);
    }
#pragma unroll
    for (int ni = 0; ni < 4; ++ni)
      qf[ni] = *(const bf16x8*)&BT[(ni * 16 + lr) * XTS + j0];
#pragma unroll
    for (int mi = 0; mi < 4; ++mi)
#pragma unroll
      for (int ni = 0; ni < 4; ++ni)
        acc[mi][ni] = __builtin_amdgcn_mfma_f32_16x16x32_bf16(pf[mi], qf[ni], acc[mi][ni], 0, 0, 0);
  }
  float* so = Sbuf + ((size_t)g * NC + c) * 4096;
#pragma unroll
  for (int mi = 0; mi < 4; ++mi)
#pragma unroll
    for (int ni = 0; ni < 4; ++ni)
#pragma unroll
      for (int r = 0; r < 4; ++r)
        so[(mi * 16 + lq * 4 + r) * 64 + ni * 16 + lr] = acc[mi][ni][r];
  if (l == 0) Pbuf[g * NC + c] = __expf(cumE);
}

// ---------------- chain ----------------
__global__ void scan_chain(float* __restrict__ Sbuf, const float* __restrict__ Pbuf) {
  const int idx = blockIdx.x * 256 + threadIdx.x;
  const int g = idx >> 12;
  const int e = idx & 4095;
  float run = 0.f;
  float* base = Sbuf + (size_t)g * NC * 4096 + e;
  for (int c = 0; c < NC; ++c) {
    const float sc = base[(size_t)c * 4096];
    const float pc = Pbuf[g * NC + c];
    base[(size_t)c * 4096] = run;
    run = pc * run + sc;
  }
}

// ---------------- scanC: Y[i][p] = e^{cum_i} C_i.S_in[p] + sum_{j<=i} mask*G*Xdt
__global__ __launch_bounds__(64) void scanC_mfma(
    const float* __restrict__ xconv, const float* __restrict__ dtb,
    const float* __restrict__ ldab, const short* __restrict__ G,
    const float* __restrict__ Sbuf, float* __restrict__ yraw) {
  __shared__ short XT[64 * XTS];
  __shared__ float cumL[64];
  const int g = blockIdx.x, c = blockIdx.y;
  const int l = threadIdx.x, lr = l & 15, lq = l >> 4;
  const int hh = g & 15, db = g >> 4;
  const size_t base_row = (size_t)db * L + c * 64;
  const float dt_l = dtb[(base_row + l) * NH + hh];
  float cum = ldab[(base_row + l) * NH + hh];
#pragma unroll
  for (int off = 1; off < 64; off <<= 1) {
    float t = __shfl_up(cum, off);
    if (l >= off) cum += t;
  }
  cumL[l] = cum;
  for (int j0 = 0; j0 < 64; j0 += 8) {
    bf16x8 xw;
#pragma unroll
    for (int jj = 0; jj < 8; ++jj) {
      const float* row = xconv + (base_row + j0 + jj) * CONVC;
      const float dtj = __shfl(dt_l, j0 + jj);
      xw[jj] = f2bf(row[hh * 64 + l] * dtj);
    }
    *(bf16x8*)&XT[l * XTS + j0] = xw;
  }
  __syncthreads();
  const float* Sin = Sbuf + ((size_t)g * NC + c) * 4096;
  const short* Gp = G + ((size_t)(db * NC + c) << 12);
  float sc[4], ci[4];
#pragma unroll
  for (int mi = 0; mi < 4; ++mi) {
    ci[mi] = cumL[mi * 16 + lr];
    sc[mi] = __expf(ci[mi]);
  }
  f32x4 acc[4][4] = {};
#pragma unroll
  for (int ks2 = 0; ks2 < 2; ++ks2) {
    const int n0 = ks2 * 32 + lq * 8;
    {
      bf16x8 pf[4], qf[4];
#pragma unroll
      for (int mi = 0; mi < 4; ++mi)
        pf[mi] = cvt8(xconv + (base_row + mi * 16 + lr) * CONVC + DI + DS + n0, sc[mi]);
#pragma unroll
      for (int ni = 0; ni < 4; ++ni)
        qf[ni] = cvt8(Sin + (ni * 16 + lr) * 64 + n0, 1.f);
#pragma unroll
      for (int mi = 0; mi < 4; ++mi)
#pragma unroll
        for (int ni = 0; ni < 4; ++ni)
          acc[mi][ni] = __builtin_amdgcn_mfma_f32_16x16x32_bf16(pf[mi], qf[ni], acc[mi][ni], 0, 0, 0);
    }
    {
      const float4 c0 = *(const float4*)&cumL[n0];
      const float4 c1 = *(const float4*)&cumL[n0 + 4];
      const float cj[8] = {c0.x, c0.y, c0.z, c0.w, c1.x, c1.y, c1.z, c1.w};
      bf16x8 pf[4], qf[4];
#pragma unroll
      for (int mi = 0; mi < 4; ++mi) {
        const int i = mi * 16 + lr;
        const bf16x8 gv = *(const bf16x8*)&Gp[i * 64 + n0];
#pragma unroll
        for (int jj = 0; jj < 8; ++jj) {
          const float m = (n0 + jj <= i) ? __expf(ci[mi] - cj[jj]) : 0.f;
          pf[mi][jj] = f2bf(bf2f(gv[jj]) * m);
        }
      }
#pragma unroll
      for (int ni = 0; ni < 4; ++ni)
        qf[ni] = *(const bf16x8*)&XT[(ni * 16 + lr) * XTS + n0];
#pragma unroll
      for (int mi = 0; mi < 4; ++mi)
#pragma unroll
        for (int ni = 0; ni < 4; ++ni)
          acc[mi][ni] = __builtin_amdgcn_mfma_f32_16x16x32_bf16(pf[mi], qf[ni], acc[mi][ni], 0, 0, 0);
    }
  }
#pragma unroll
  for (int mi = 0; mi < 4; ++mi)
#pragma unroll
    for (int ni = 0; ni < 4; ++ni)
#pragma unroll
      for (int r = 0; r < 4; ++r)
        yraw[(base_row + mi * 16 + lq * 4 + r) * DI + hh * 64 + ni * 16 + lr] = acc[mi][ni][r];
}

// ---------------- gate + D*x + RMSNorm + combine ----------------
__global__ __launch_bounds__(256) void gate_norm(
    const float* __restrict__ zx, const float* __restrict__ yraw,
    const float* __restrict__ xconv, const float* __restrict__ Dpar,
    const float* __restrict__ nw, float* __restrict__ ycomb) {
  const int bt = blockIdx.x;
  const int b = bt / L, t = bt % L;
  const int tid = threadIdx.x;
  const float* z = zx + (size_t)bt * DPROJ;
  const float* y0 = yraw + ((size_t)b * L + t) * DI;
  const float* y1 = yraw + ((size_t)(B + b) * L + (L - 1 - t)) * DI;
  const float* x0 = xconv + ((size_t)b * L + t) * CONVC;
  const float* x1 = xconv + ((size_t)(B + b) * L + (L - 1 - t)) * CONVC;
  float a0[4], a1[4];
  float s0 = 0.f, s1 = 0.f;
#pragma unroll
  for (int r = 0; r < 4; ++r) {
    const int cc = r * 256 + tid;
    const float zv = z[cc];
    const float gz = zv / (1.f + expf(-zv));
    const float dp = Dpar[cc >> 6];
    a0[r] = (y0[cc] + dp * x0[cc]) * gz;
    a1[r] = (y1[cc] + dp * x1[cc]) * gz;
    s0 += a0[r] * a0[r];
    s1 += a1[r] * a1[r];
  }
#pragma unroll
  for (int off = 32; off > 0; off >>= 1) {
    s0 += __shfl_down(s0, off);
    s1 += __shfl_down(s1, off);
  }
  __shared__ float rs0[4], rs1[4];
  const int w = tid >> 6;
  if ((tid & 63) == 0) { rs0[w] = s0; rs1[w] = s1; }
  __syncthreads();
  s0 = rs0[0] + rs0[1] + rs0[2] + rs0[3];
  s1 = rs1[0] + rs1[1] + rs1[2] + rs1[3];
  const float r0 = rsqrtf(s0 * (1.f / DI) + 1e-5f);
  const float r1 = rsqrtf(s1 * (1.f / DI) + 1e-5f);
  float* oc = ycomb + (size_t)bt * DI;
#pragma unroll
  for (int r = 0; r < 4; ++r) {
    const int cc = r * 256 + tid;
    oc[cc] = nw[cc] * (a0[r] * r0 + a1[r] * r1);
  }
}

extern "C" void kernel_launch(void* const* d_in, const int* in_sizes, int n_in,
                              void* d_out, int out_size, void* d_ws, size_t ws_size,
                              hipStream_t stream) {
  const float* x       = (const float*)d_in[0];
  const float* Wp_in   = (const float*)d_in[1];
  const float* bp_in   = (const float*)d_in[2];
  const float* W_in    = (const float*)d_in[3];
  const float* b_in    = (const float*)d_in[4];
  const float* conv_w  = (const float*)d_in[5];
  const float* conv_b  = (const float*)d_in[6];
  const float* dt_bias = (const float*)d_in[7];
  const float* A_log   = (const float*)d_in[8];
  const float* Dpar    = (const float*)d_in[9];
  const float* norm_w  = (const float*)d_in[10];
  const float* W_out   = (const float*)d_in[11];
  const float* Wp_out  = (const float*)d_in[12];
  const float* bp_out  = (const float*)d_in[13];
  float* out = (float*)d_out;

  char* p = (char*)d_ws;
  __hip_bfloat16* hbf = (__hip_bfloat16*)p; p += (size_t)BL * DM * 2;
  __hip_bfloat16* Wt  = (__hip_bfloat16*)p; p += (size_t)NPAD * DM * 2;
  float* zx    = (float*)p; p += (size_t)BL * DPROJ * 4;
  float* xconv = (float*)p; p += (size_t)2 * BL * CONVC * 4;
  float* dtb   = (float*)p; p += (size_t)2 * BL * NH * 4;
  float* ldab  = (float*)p; p += (size_t)2 * BL * NH * 4;
  float* Sbuf  = (float*)p; p += (size_t)NG * NC * HD * DS * 4;
  float* Pbuf  = (float*)p; p += (size_t)NG * NC * 4;
  float* yraw  = (float*)p; p += (size_t)2 * BL * DI * 4;
  float* ycomb = (float*)p; p += (size_t)BL * DI * 4;
  float* Wc    = (float*)p; p += (size_t)DI * DIN * 4;
  short* G     = (short*)p; p += (size_t)2 * B * NC * 64 * 64 * 2;
  float* part2 = (float*)p; p += (size_t)KSPLIT2 * DI * DIN * 4;  // 2.6 MB
  float* part  = zx;   // alias: zx dead after gate_norm; 21 MB fits
  (void)ws_size; (void)in_sizes; (void)n_in; (void)out_size;

  // 1. h = bf16(x @ Wp_in + bp_in)
  gemm_bias<__hip_bfloat16><<<dim3(BL / GBM, (DM + GBN - 1) / GBN), 256, 0, stream>>>(
      x, Wp_in, bp_in, hbf, BL, DM, DIN);
  // 1b. Wt = bf16(W_in^T), padded
  prep_wt<<<(NPAD * DM + 255) / 256, 256, 0, stream>>>(W_in, Wt);
  // 2. zxbcdt = h @ W_in + b_in (bf16 MFMA)
  gemm_mfma_bt<<<dim3(BL / 128, NPAD / 128), 256, 0, stream>>>(
      hbf, Wt, b_in, zx, BL, DPROJ, DM);
  // 3. conv + silu (both dirs, one pass); dt/log-dA
  prep_conv2<<<dim3(CONVC / 128, L / TSEG, B), 128, 0, stream>>>(zx, conv_w, conv_b, xconv);
  prep_dt<<<(2 * BL * NH + 255) / 256, 256, 0, stream>>>(zx, dt_bias, A_log, dtb, ldab);
  // 4. chunked scan via MFMA
  gprep<<<dim3(2 * B, NC), 64, 0, stream>>>(xconv, G);
  scanA_mfma<<<dim3(NG, NC), 64, 0, stream>>>(xconv, dtb, ldab, Sbuf, Pbuf);
  scan_chain<<<(NG * HD * DS) / 256, 256, 0, stream>>>(Sbuf, Pbuf);
  scanC_mfma<<<dim3(NG, NC), 64, 0, stream>>>(xconv, dtb, ldab, G, Sbuf, yraw);
  // 5. gate + D*x + RMSNorm + combine
  gate_norm<<<BL, 256, 0, stream>>>(zx, yraw, xconv, Dpar, norm_w, ycomb);
  // 6. Wc = W_out @ Wp_out (split-K: 16x8 blocks + reduce)
  gemm_skinny_splitk<<<dim3(DI / 64, KSPLIT2), 256, 0, stream>>>(W_out, Wp_out, part2, DM, DI);
  reduce_splitk<<<(DI * DIN + 255) / 256, 256, 0, stream>>>(part2, nullptr, Wc, DI * DIN, KSPLIT2);
  // 7. out = ycomb @ Wc + bp_out (split-K: 64x16 blocks + reduce)
  gemm_skinny_splitk<<<dim3(BL / 64, KSPLIT), 256, 0, stream>>>(ycomb, Wc, part, DI, BL);
  reduce_splitk<<<(BL * DIN + 255) / 256, 256, 0, stream>>>(part, bp_out, out, BL * DIN, KSPLIT);
}

// Round 10
// 293.093 us; speedup vs baseline: 2.7322x; 1.0047x over previous
//
#include <hip/hip_runtime.h>
#include <hip/hip_bf16.h>

constexpr int B = 2;
constexpr int L = 2048;
constexpr int DIN = 80;
constexpr int DM = 512;
constexpr int DI = 1024;
constexpr int DS = 64;
constexpr int KC = 7;
constexpr int HD = 64;
constexpr int NH = 16;                    // DI/HD
constexpr int CONVC = DI + 2 * DS;        // 1152
constexpr int DPROJ = 2 * DI + 2 * DS + NH; // 2192
constexpr int NPAD = 2304;                // DPROJ padded to 18*128
constexpr int BL = B * L;                 // 4096
constexpr int CHUNK = 64;
constexpr int NC = L / CHUNK;             // 32
constexpr int NG = 2 * B * NH;            // 64 scan groups (dir,b,head)
constexpr int KSPLIT = 16;                // final GEMM K-split
constexpr int KSPLIT2 = 8;                // Wc GEMM K-split
constexpr int XTS = 72;                   // LDS transposed-tile row stride (bf16)
constexpr int TSEG = 32;                  // conv time-segment per thread

typedef __attribute__((ext_vector_type(8))) short bf16x8;
typedef __attribute__((ext_vector_type(4))) short s16x4;
typedef __attribute__((ext_vector_type(4))) float f32x4;

__device__ inline short f2bf(float f) {
  union { float f; unsigned u; } v; v.f = f;
  unsigned r = (v.u + 0x7FFF + ((v.u >> 16) & 1)) >> 16;  // RNE
  return (short)r;
}
__device__ inline float bf2f(short s) {
  union { unsigned u; float f; } v; v.u = ((unsigned)(unsigned short)s) << 16;
  return v.f;
}
// load 8 contiguous fp32, scale, convert to bf16x8 fragment
__device__ inline bf16x8 cvt8(const float* p, float s) {
  const float4 a = *(const float4*)p;
  const float4 b = *(const float4*)(p + 4);
  bf16x8 r;
  r[0] = f2bf(a.x * s); r[1] = f2bf(a.y * s); r[2] = f2bf(a.z * s); r[3] = f2bf(a.w * s);
  r[4] = f2bf(b.x * s); r[5] = f2bf(b.y * s); r[6] = f2bf(b.z * s); r[7] = f2bf(b.w * s);
  return r;
}

// ---------------- fp32 tiled GEMM with bias ----------------
constexpr int GBM = 128, GBN = 128, GBK = 16;

template <typename OutT>
__global__ __launch_bounds__(256) void gemm_bias(
    const float* __restrict__ A, const float* __restrict__ Bm,
    const float* __restrict__ bias, OutT* __restrict__ C,
    int M, int N, int K) {
  __shared__ float As[GBK][GBM + 4];
  __shared__ float Bs[GBK][GBN + 4];
  const int m0 = blockIdx.x * GBM;
  const int n0 = blockIdx.y * GBN;
  const int tid = threadIdx.x;
  const int tm = tid >> 4, tn = tid & 15;
  float acc[8][8] = {};
  const int arow = tid >> 2, acol = (tid & 3) << 2;
  const int brow = tid >> 5, bcol = (tid & 31) << 2;
  for (int k0 = 0; k0 < K; k0 += GBK) {
#pragma unroll
    for (int r = 0; r < 2; ++r) {
      int m = m0 + arow + r * 64;
      float4 v = make_float4(0.f, 0.f, 0.f, 0.f);
      if (m < M) v = *(const float4*)(A + (size_t)m * K + k0 + acol);
      As[acol + 0][arow + r * 64] = v.x;
      As[acol + 1][arow + r * 64] = v.y;
      As[acol + 2][arow + r * 64] = v.z;
      As[acol + 3][arow + r * 64] = v.w;
    }
#pragma unroll
    for (int r = 0; r < 2; ++r) {
      int kk = brow + r * 8;
      int n = n0 + bcol;
      float4 v = make_float4(0.f, 0.f, 0.f, 0.f);
      if (n < N) v = *(const float4*)(Bm + (size_t)(k0 + kk) * N + n);
      *(float4*)&Bs[kk][bcol] = v;
    }
    __syncthreads();
#pragma unroll
    for (int k = 0; k < GBK; ++k) {
      float a[8], bb[8];
#pragma unroll
      for (int i = 0; i < 8; ++i) a[i] = As[k][tm * 8 + i];
#pragma unroll
      for (int j = 0; j < 8; ++j) bb[j] = Bs[k][tn * 8 + j];
#pragma unroll
      for (int i = 0; i < 8; ++i)
#pragma unroll
        for (int j = 0; j < 8; ++j)
          acc[i][j] = fmaf(a[i], bb[j], acc[i][j]);
    }
    __syncthreads();
  }
#pragma unroll
  for (int i = 0; i < 8; ++i) {
    int m = m0 + tm * 8 + i;
    if (m >= M) continue;
#pragma unroll
    for (int j = 0; j < 8; ++j) {
      int n = n0 + tn * 8 + j;
      if (n < N) C[(size_t)m * N + n] = (OutT)(acc[i][j] + bias[n]);
    }
  }
}

// ---------------- W_in -> transposed, padded bf16 [NPAD][DM] -------------------
__global__ void prep_wt(const float* __restrict__ W_in, __hip_bfloat16* __restrict__ Wt) {
  const int idx = blockIdx.x * 256 + threadIdx.x;
  if (idx >= NPAD * DM) return;
  const int n = idx % NPAD;
  const int k = idx / NPAD;
  const float v = (n < DPROJ) ? W_in[(size_t)k * DPROJ + n] : 0.f;
  Wt[(size_t)n * DM + k] = (__hip_bfloat16)v;
}

// ---------------- bf16 MFMA GEMM -> bf16 C: C[M,N] = A*Bt^T + bias -------------
__global__ __launch_bounds__(256) void gemm_mfma_bt(
    const __hip_bfloat16* __restrict__ A, const __hip_bfloat16* __restrict__ Bt,
    const float* __restrict__ bias, short* __restrict__ C,
    int M, int N, int K) {
  __shared__ short As[4 * 128 * 8];
  __shared__ short Bs[4 * 128 * 8];
  const int tid = threadIdx.x;
  const int l = tid & 63;
  const int wv = tid >> 6;
  const int wr = wv >> 1, wc = wv & 1;
  const int m0 = blockIdx.x * 128;
  const int n0 = blockIdx.y * 128;
  const int ks = l >> 4, lr = l & 15;
  f32x4 acc[4][4] = {};
  for (int k0 = 0; k0 < K; k0 += 32) {
#pragma unroll
    for (int i = 0; i < 2; ++i) {
      const int t = (wv * 2 + i) * 64 + l;
      const int tks = t >> 7, trow = t & 127;
      __builtin_amdgcn_global_load_lds(
          (const __attribute__((address_space(1))) unsigned int*)(A + (size_t)(m0 + trow) * K + k0 + tks * 8),
          (__attribute__((address_space(3))) unsigned int*)(As + (size_t)(wv * 2 + i) * 512),
          16, 0, 0);
      __builtin_amdgcn_global_load_lds(
          (const __attribute__((address_space(1))) unsigned int*)(Bt + (size_t)(n0 + trow) * K + k0 + tks * 8),
          (__attribute__((address_space(3))) unsigned int*)(Bs + (size_t)(wv * 2 + i) * 512),
          16, 0, 0);
    }
    __syncthreads();
    bf16x8 af[4], bfr[4];
#pragma unroll
    for (int mi = 0; mi < 4; ++mi)
      af[mi] = *(const bf16x8*)&As[(size_t)(ks * 128 + wr * 64 + mi * 16 + lr) * 8];
#pragma unroll
    for (int ni = 0; ni < 4; ++ni)
      bfr[ni] = *(const bf16x8*)&Bs[(size_t)(ks * 128 + wc * 64 + ni * 16 + lr) * 8];
#pragma unroll
    for (int mi = 0; mi < 4; ++mi)
#pragma unroll
      for (int ni = 0; ni < 4; ++ni)
        acc[mi][ni] = __builtin_amdgcn_mfma_f32_16x16x32_bf16(af[mi], bfr[ni], acc[mi][ni], 0, 0, 0);
    __syncthreads();
  }
#pragma unroll
  for (int mi = 0; mi < 4; ++mi) {
    const int row = m0 + wr * 64 + mi * 16 + (l >> 4) * 4;
#pragma unroll
    for (int ni = 0; ni < 4; ++ni) {
      const int col = n0 + wc * 64 + ni * 16 + lr;
      if (col < N) {
        const float bv = bias[col];
#pragma unroll
        for (int r = 0; r < 4; ++r)
          C[(size_t)(row + r) * N + col] = f2bf(acc[mi][ni][r] + bv);
      }
    }
  }
}

// ------- skinny GEMM split-K: part[sk][M][80] = A[:,k-slice] * Bm[k-slice,:80]
__global__ __launch_bounds__(256) void gemm_skinny_splitk(
    const float* __restrict__ A, const float* __restrict__ Bm,
    float* __restrict__ part, int Astride, int Mtotal) {
  __shared__ float As[64][65];
  __shared__ float Bs[64][80];
  const int tid = threadIdx.x;
  const int m0 = blockIdx.x * 64;
  const int k0 = blockIdx.y * 64;
  {
    const int r = tid >> 2, q = tid & 3;
#pragma unroll
    for (int j = 0; j < 4; ++j) {
      const int col = q * 16 + j * 4;
      float4 v = *(const float4*)(A + (size_t)(m0 + r) * Astride + k0 + col);
      As[r][col + 0] = v.x; As[r][col + 1] = v.y;
      As[r][col + 2] = v.z; As[r][col + 3] = v.w;
    }
#pragma unroll
    for (int j = 0; j < 5; ++j) {
      const int col = (q * 5 + j) * 4;
      float4 v = *(const float4*)(Bm + (size_t)(k0 + r) * DIN + col);
      *(float4*)&Bs[r][col] = v;
    }
  }
  __syncthreads();
  const int r0 = (tid >> 4) * 4;
  const int n0 = (tid & 15) * 5;
  float acc[4][5] = {};
  for (int k = 0; k < 64; ++k) {
    float a[4];
#pragma unroll
    for (int i = 0; i < 4; ++i) a[i] = As[r0 + i][k];
#pragma unroll
    for (int j = 0; j < 5; ++j) {
      const float bv = Bs[k][n0 + j];
#pragma unroll
      for (int i = 0; i < 4; ++i) acc[i][j] = fmaf(a[i], bv, acc[i][j]);
    }
  }
#pragma unroll
  for (int i = 0; i < 4; ++i) {
    float* o = part + ((size_t)blockIdx.y * Mtotal + m0 + r0 + i) * DIN + n0;
#pragma unroll
    for (int j = 0; j < 5; ++j) o[j] = acc[i][j];
  }
}

__global__ __launch_bounds__(256) void reduce_splitk(
    const float* __restrict__ part, const float* __restrict__ bias,
    float* __restrict__ out, int total, int nsl) {
  const int idx = blockIdx.x * 256 + threadIdx.x;
  if (idx >= total) return;
  float acc = bias ? bias[idx % DIN] : 0.f;
  for (int s = 0; s < nsl; ++s) acc += part[(size_t)s * total + idx];
  out[idx] = acc;
}

// ---------------- dt / log(dA) (scan order per direction); zx bf16 -------------
__global__ void prep_dt(const short* __restrict__ zx, const float* __restrict__ dt_bias,
                        const float* __restrict__ A_log, float* __restrict__ dtb,
                        float* __restrict__ ldab) {
  const int idx = blockIdx.x * 256 + threadIdx.x;
  if (idx >= 2 * BL * NH) return;
  const int h = idx % NH;
  int rest = idx / NH;
  const int s = rest % L;
  rest /= L;
  const int bb = rest % B;
  const int d = rest / B;
  const int torig = d ? (L - 1 - s) : s;
  const float raw = bf2f(zx[((size_t)(bb * L + torig)) * DPROJ + DI + CONVC + h]) + dt_bias[h];
  const float dt = (raw > 20.f) ? raw : log1pf(expf(raw));
  dtb[idx] = dt;
  ldab[idx] = -expf(A_log[h]) * dt;   // log(dA), always <= 0
}

// ------- conv both dirs + silu -> bf16 xconv, and xdt = silu*dt (c<DI) --------
// dt is direction-symmetric at fixed orig-time -> read dir0 region of dtb.
__global__ __launch_bounds__(128) void prep_conv2(
    const short* __restrict__ zx, const float* __restrict__ cw,
    const float* __restrict__ cb, const float* __restrict__ dtb,
    short* __restrict__ xconv, short* __restrict__ xdt) {
  const int c = blockIdx.x * 128 + threadIdx.x;   // 0..1151
  const int b = blockIdx.z;
  const int t0 = blockIdx.y * TSEG;
  const float wt0 = cw[c * KC + 0], wt1 = cw[c * KC + 1], wt2 = cw[c * KC + 2],
              wt3 = cw[c * KC + 3], wt4 = cw[c * KC + 4], wt5 = cw[c * KC + 5],
              wt6 = cw[c * KC + 6];
  const float bias = cb[c];
  const short* src = zx + (size_t)b * L * DPROJ + DI + c;
  short* dstF = xconv + (size_t)b * L * CONVC + c;
  short* dstB = xconv + (size_t)(B + b) * L * CONVC + c;
  const bool isx = (c < DI);
  const int h = isx ? (c >> 6) : 0;
  short* dxF = xdt + (size_t)b * L * DI + c;
  short* dxB = xdt + (size_t)(B + b) * L * DI + c;
  const float* dto = dtb + (size_t)b * L * NH + h;   // dir0 = orig-time order
  float w0 = 0.f, w1 = 0.f, w2 = 0.f, w3 = 0.f, w4 = 0.f, w5 = 0.f, w6 = 0.f;
  for (int t = t0 - 6; t < t0 + TSEG + 6; ++t) {
    float v = 0.f;
    if (t >= 0 && t < L) v = bf2f(src[(size_t)t * DPROJ]);
    w0 = w1; w1 = w2; w2 = w3; w3 = w4; w4 = w5; w5 = w6; w6 = v;
    if (t >= t0 && t < t0 + TSEG) {
      float a = bias + wt0 * w0 + wt1 * w1 + wt2 * w2 + wt3 * w3 + wt4 * w4 +
                wt5 * w5 + wt6 * w6;
      const float sf = a / (1.f + expf(-a));
      dstF[(size_t)t * CONVC] = f2bf(sf);
      if (isx) dxF[(size_t)t * DI] = f2bf(sf * dto[(size_t)t * NH]);
    }
    const int torig = t - 6;
    if (torig >= t0 && torig < t0 + TSEG) {
      float a = bias + wt6 * w0 + wt5 * w1 + wt4 * w2 + wt3 * w3 + wt2 * w4 +
                wt1 * w5 + wt0 * w6;
      const float sb = a / (1.f + expf(-a));
      const size_t srow = (size_t)(L - 1 - torig);
      dstB[srow * CONVC] = f2bf(sb);
      if (isx) dxB[srow * DI] = f2bf(sb * dto[(size_t)torig * NH]);
    }
  }
}

// ---------------- G-prep: G[i][j] = C_i . B_j per (db, chunk), bf16 ------------
__global__ __launch_bounds__(64) void gprep(
    const short* __restrict__ xconv, short* __restrict__ G) {
  const int db = blockIdx.x, c = blockIdx.y;
  const int l = threadIdx.x, lr = l & 15, lq = l >> 4;
  const size_t base_row = (size_t)db * L + c * 64;
  f32x4 acc[4][4] = {};
#pragma unroll
  for (int ks2 = 0; ks2 < 2; ++ks2) {
    const int n0 = ks2 * 32 + lq * 8;
    bf16x8 pf[4], qf[4];
#pragma unroll
    for (int mi = 0; mi < 4; ++mi)
      pf[mi] = *(const bf16x8*)&xconv[(base_row + mi * 16 + lr) * CONVC + DI + DS + n0];
#pragma unroll
    for (int ni = 0; ni < 4; ++ni)
      qf[ni] = *(const bf16x8*)&xconv[(base_row + ni * 16 + lr) * CONVC + DI + n0];
#pragma unroll
    for (int mi = 0; mi < 4; ++mi)
#pragma unroll
      for (int ni = 0; ni < 4; ++ni)
        acc[mi][ni] = __builtin_amdgcn_mfma_f32_16x16x32_bf16(pf[mi], qf[ni], acc[mi][ni], 0, 0, 0);
  }
  short* g = G + ((size_t)(db * NC + c) << 12);
#pragma unroll
  for (int mi = 0; mi < 4; ++mi)
#pragma unroll
    for (int ni = 0; ni < 4; ++ni)
#pragma unroll
      for (int r = 0; r < 4; ++r)
        g[(mi * 16 + lq * 4 + r) * 64 + ni * 16 + lr] = f2bf(acc[mi][ni][r]);
}

// ---------------- scanA: chunk-local state S_local + decay product P -----------
__global__ __launch_bounds__(64) void scanA_mfma(
    const short* __restrict__ xdt, const short* __restrict__ xconv,
    const float* __restrict__ ldab, float* __restrict__ Sbuf,
    float* __restrict__ Pbuf) {
  __shared__ short XT[64 * XTS];
  __shared__ short BT[64 * XTS];
  __shared__ float cumL[64];
  const int g = blockIdx.x, c = blockIdx.y;
  const int l = threadIdx.x, lr = l & 15, lq = l >> 4;
  const int hh = g & 15, db = g >> 4;
  const size_t base_row = (size_t)db * L + c * 64;
  float cum = ldab[(base_row + l) * NH + hh];
#pragma unroll
  for (int off = 1; off < 64; off <<= 1) {
    float t = __shfl_up(cum, off);
    if (l >= off) cum += t;
  }
  cumL[l] = cum;
  const float cumE = __shfl(cum, 63);
  // row-wise staging: thread l = time-row l; vector loads, transposed LDS stores
  const short* xrow = xdt + (base_row + l) * DI + hh * 64;
  const short* brow = xconv + (base_row + l) * CONVC + DI;
#pragma unroll
  for (int q = 0; q < 8; ++q) {
    const bf16x8 xv = *(const bf16x8*)&xrow[q * 8];
    const bf16x8 bv = *(const bf16x8*)&brow[q * 8];
#pragma unroll
    for (int e = 0; e < 8; ++e) {
      XT[(q * 8 + e) * XTS + l] = xv[e];
      BT[(q * 8 + e) * XTS + l] = bv[e];
    }
  }
  __syncthreads();
  f32x4 acc[4][4] = {};
#pragma unroll
  for (int ks2 = 0; ks2 < 2; ++ks2) {
    const int j0 = ks2 * 32 + lq * 8;
    const float4 c0 = *(const float4*)&cumL[j0];
    const float4 c1 = *(const float4*)&cumL[j0 + 4];
    float w[8] = {__expf(cumE - c0.x), __expf(cumE - c0.y), __expf(cumE - c0.z), __expf(cumE - c0.w),
                  __expf(cumE - c1.x), __expf(cumE - c1.y), __expf(cumE - c1.z), __expf(cumE - c1.w)};
    bf16x8 pf[4], qf[4];
#pragma unroll
    for (int mi = 0; mi < 4; ++mi) {
      const bf16x8 raw = *(const bf16x8*)&XT[(mi * 16 + lr) * XTS + j0];
#pragma unroll
      for (int jj = 0; jj < 8; ++jj) pf[mi][jj] = f2bf(bf2f(raw[jj]) * w[jj]);
    }
#pragma unroll
    for (int ni = 0; ni < 4; ++ni)
      qf[ni] = *(const bf16x8*)&BT[(ni * 16 + lr) * XTS + j0];
#pragma unroll
    for (int mi = 0; mi < 4; ++mi)
#pragma unroll
      for (int ni = 0; ni < 4; ++ni)
        acc[mi][ni] = __builtin_amdgcn_mfma_f32_16x16x32_bf16(pf[mi], qf[ni], acc[mi][ni], 0, 0, 0);
  }
  float* so = Sbuf + ((size_t)g * NC + c) * 4096;
#pragma unroll
  for (int mi = 0; mi < 4; ++mi)
#pragma unroll
    for (int ni = 0; ni < 4; ++ni)
#pragma unroll
      for (int r = 0; r < 4; ++r)
        so[(mi * 16 + lq * 4 + r) * 64 + ni * 16 + lr] = acc[mi][ni][r];
  if (l == 0) Pbuf[g * NC + c] = __expf(cumE);
}

// ---------------- chain ----------------
__global__ void scan_chain(float* __restrict__ Sbuf, const float* __restrict__ Pbuf) {
  const int idx = blockIdx.x * 256 + threadIdx.x;
  const int g = idx >> 12;
  const int e = idx & 4095;
  float run = 0.f;
  float* base = Sbuf + (size_t)g * NC * 4096 + e;
  for (int c = 0; c < NC; ++c) {
    const float sc = base[(size_t)c * 4096];
    const float pc = Pbuf[g * NC + c];
    base[(size_t)c * 4096] = run;
    run = pc * run + sc;
  }
}

// ---------------- scanC -> bf16 yraw ----------------
__global__ __launch_bounds__(64) void scanC_mfma(
    const short* __restrict__ xdt, const short* __restrict__ xconv,
    const float* __restrict__ ldab, const short* __restrict__ G,
    const float* __restrict__ Sbuf, short* __restrict__ yraw) {
  __shared__ short XT[64 * XTS];
  __shared__ float cumL[64];
  const int g = blockIdx.x, c = blockIdx.y;
  const int l = threadIdx.x, lr = l & 15, lq = l >> 4;
  const int hh = g & 15, db = g >> 4;
  const size_t base_row = (size_t)db * L + c * 64;
  float cum = ldab[(base_row + l) * NH + hh];
#pragma unroll
  for (int off = 1; off < 64; off <<= 1) {
    float t = __shfl_up(cum, off);
    if (l >= off) cum += t;
  }
  cumL[l] = cum;
  const short* xrow = xdt + (base_row + l) * DI + hh * 64;
#pragma unroll
  for (int q = 0; q < 8; ++q) {
    const bf16x8 xv = *(const bf16x8*)&xrow[q * 8];
#pragma unroll
    for (int e = 0; e < 8; ++e) XT[(q * 8 + e) * XTS + l] = xv[e];
  }
  __syncthreads();
  const float* Sin = Sbuf + ((size_t)g * NC + c) * 4096;
  const short* Gp = G + ((size_t)(db * NC + c) << 12);
  float sc[4], ci[4];
#pragma unroll
  for (int mi = 0; mi < 4; ++mi) {
    ci[mi] = cumL[mi * 16 + lr];
    sc[mi] = __expf(ci[mi]);
  }
  f32x4 acc[4][4] = {};
#pragma unroll
  for (int ks2 = 0; ks2 < 2; ++ks2) {
    const int n0 = ks2 * 32 + lq * 8;
    // Yoff: P = e^{cum_i} * C_i[n], Q = S_in[p][n]
    {
      bf16x8 pf[4], qf[4];
#pragma unroll
      for (int mi = 0; mi < 4; ++mi) {
        const bf16x8 cv = *(const bf16x8*)&xconv[(base_row + mi * 16 + lr) * CONVC + DI + DS + n0];
#pragma unroll
        for (int e = 0; e < 8; ++e) pf[mi][e] = f2bf(bf2f(cv[e]) * sc[mi]);
      }
#pragma unroll
      for (int ni = 0; ni < 4; ++ni)
        qf[ni] = cvt8(Sin + (ni * 16 + lr) * 64 + n0, 1.f);
#pragma unroll
      for (int mi = 0; mi < 4; ++mi)
#pragma unroll
        for (int ni = 0; ni < 4; ++ni)
          acc[mi][ni] = __builtin_amdgcn_mfma_f32_16x16x32_bf16(pf[mi], qf[ni], acc[mi][ni], 0, 0, 0);
    }
    // Ylocal: P = G[i][j]*mask, Q = XT[p][j]
    {
      const float4 c0 = *(const float4*)&cumL[n0];
      const float4 c1 = *(const float4*)&cumL[n0 + 4];
      const float cj[8] = {c0.x, c0.y, c0.z, c0.w, c1.x, c1.y, c1.z, c1.w};
      bf16x8 pf[4], qf[4];
#pragma unroll
      for (int mi = 0; mi < 4; ++mi) {
        const int i = mi * 16 + lr;
        const bf16x8 gv = *(const bf16x8*)&Gp[i * 64 + n0];
#pragma unroll
        for (int jj = 0; jj < 8; ++jj) {
          const float m = (n0 + jj <= i) ? __expf(ci[mi] - cj[jj]) : 0.f;
          pf[mi][jj] = f2bf(bf2f(gv[jj]) * m);
        }
      }
#pragma unroll
      for (int ni = 0; ni < 4; ++ni)
        qf[ni] = *(const bf16x8*)&XT[(ni * 16 + lr) * XTS + n0];
#pragma unroll
      for (int mi = 0; mi < 4; ++mi)
#pragma unroll
        for (int ni = 0; ni < 4; ++ni)
          acc[mi][ni] = __builtin_amdgcn_mfma_f32_16x16x32_bf16(pf[mi], qf[ni], acc[mi][ni], 0, 0, 0);
    }
  }
#pragma unroll
  for (int mi = 0; mi < 4; ++mi)
#pragma unroll
    for (int ni = 0; ni < 4; ++ni)
#pragma unroll
      for (int r = 0; r < 4; ++r)
        yraw[(base_row + mi * 16 + lq * 4 + r) * DI + hh * 64 + ni * 16 + lr] = f2bf(acc[mi][ni][r]);
}

// ---------------- gate + D*x + RMSNorm + combine (bf16 in, f32 out) -----------
__global__ __launch_bounds__(256) void gate_norm(
    const short* __restrict__ zx, const short* __restrict__ yraw,
    const short* __restrict__ xconv, const float* __restrict__ Dpar,
    const float* __restrict__ nw, float* __restrict__ ycomb) {
  const int bt = blockIdx.x;
  const int b = bt / L, t = bt % L;
  const int tid = threadIdx.x;
  const int c0 = tid * 4;                 // 4 consecutive channels
  const float dp = Dpar[c0 >> 6];
  const s16x4 zv4 = *(const s16x4*)&zx[(size_t)bt * DPROJ + c0];
  const s16x4 y04 = *(const s16x4*)&yraw[((size_t)b * L + t) * DI + c0];
  const s16x4 y14 = *(const s16x4*)&yraw[((size_t)(B + b) * L + (L - 1 - t)) * DI + c0];
  const s16x4 x04 = *(const s16x4*)&xconv[((size_t)b * L + t) * CONVC + c0];
  const s16x4 x14 = *(const s16x4*)&xconv[((size_t)(B + b) * L + (L - 1 - t)) * CONVC + c0];
  float a0[4], a1[4];
  float s0 = 0.f, s1 = 0.f;
#pragma unroll
  for (int r = 0; r < 4; ++r) {
    const float zv = bf2f(zv4[r]);
    const float gz = zv / (1.f + expf(-zv));
    a0[r] = (bf2f(y04[r]) + dp * bf2f(x04[r])) * gz;
    a1[r] = (bf2f(y14[r]) + dp * bf2f(x14[r])) * gz;
    s0 += a0[r] * a0[r];
    s1 += a1[r] * a1[r];
  }
#pragma unroll
  for (int off = 32; off > 0; off >>= 1) {
    s0 += __shfl_down(s0, off);
    s1 += __shfl_down(s1, off);
  }
  __shared__ float rs0[4], rs1[4];
  const int w = tid >> 6;
  if ((tid & 63) == 0) { rs0[w] = s0; rs1[w] = s1; }
  __syncthreads();
  s0 = rs0[0] + rs0[1] + rs0[2] + rs0[3];
  s1 = rs1[0] + rs1[1] + rs1[2] + rs1[3];
  const float r0 = rsqrtf(s0 * (1.f / DI) + 1e-5f);
  const float r1 = rsqrtf(s1 * (1.f / DI) + 1e-5f);
  float4 o;
  o.x = nw[c0 + 0] * (a0[0] * r0 + a1[0] * r1);
  o.y = nw[c0 + 1] * (a0[1] * r0 + a1[1] * r1);
  o.z = nw[c0 + 2] * (a0[2] * r0 + a1[2] * r1);
  o.w = nw[c0 + 3] * (a0[3] * r0 + a1[3] * r1);
  *(float4*)&ycomb[(size_t)bt * DI + c0] = o;
}

extern "C" void kernel_launch(void* const* d_in, const int* in_sizes, int n_in,
                              void* d_out, int out_size, void* d_ws, size_t ws_size,
                              hipStream_t stream) {
  const float* x       = (const float*)d_in[0];
  const float* Wp_in   = (const float*)d_in[1];
  const float* bp_in   = (const float*)d_in[2];
  const float* W_in    = (const float*)d_in[3];
  const float* b_in    = (const float*)d_in[4];
  const float* conv_w  = (const float*)d_in[5];
  const float* conv_b  = (const float*)d_in[6];
  const float* dt_bias = (const float*)d_in[7];
  const float* A_log   = (const float*)d_in[8];
  const float* Dpar    = (const float*)d_in[9];
  const float* norm_w  = (const float*)d_in[10];
  const float* W_out   = (const float*)d_in[11];
  const float* Wp_out  = (const float*)d_in[12];
  const float* bp_out  = (const float*)d_in[13];
  float* out = (float*)d_out;

  char* p = (char*)d_ws;
  __hip_bfloat16* hbf = (__hip_bfloat16*)p; p += (size_t)BL * DM * 2;
  __hip_bfloat16* Wt  = (__hip_bfloat16*)p; p += (size_t)NPAD * DM * 2;
  short* zx    = (short*)p; p += (size_t)BL * DPROJ * 2;
  short* xconv = (short*)p; p += (size_t)2 * BL * CONVC * 2;
  short* xdt   = (short*)p; p += (size_t)2 * BL * DI * 2;
  float* dtb   = (float*)p; p += (size_t)2 * BL * NH * 4;
  float* ldab  = (float*)p; p += (size_t)2 * BL * NH * 4;
  float* Sbuf  = (float*)p; p += (size_t)NG * NC * HD * DS * 4;
  float* Pbuf  = (float*)p; p += (size_t)NG * NC * 4;
  short* yraw  = (short*)p; p += (size_t)2 * BL * DI * 2;
  float* ycomb = (float*)p; p += (size_t)BL * DI * 4;
  float* Wc    = (float*)p; p += (size_t)DI * DIN * 4;
  short* G     = (short*)p; p += (size_t)2 * B * NC * 64 * 64 * 2;
  float* part2 = (float*)p; p += (size_t)KSPLIT2 * DI * DIN * 4;
  float* part  = (float*)p; p += (size_t)KSPLIT * BL * DIN * 4;
  (void)ws_size; (void)in_sizes; (void)n_in; (void)out_size;

  // 1. h = bf16(x @ Wp_in + bp_in)
  gemm_bias<__hip_bfloat16><<<dim3(BL / GBM, (DM + GBN - 1) / GBN), 256, 0, stream>>>(
      x, Wp_in, bp_in, hbf, BL, DM, DIN);
  // 1b. Wt = bf16(W_in^T), padded
  prep_wt<<<(NPAD * DM + 255) / 256, 256, 0, stream>>>(W_in, Wt);
  // 2. zxbcdt = h @ W_in + b_in (bf16 MFMA, bf16 out)
  gemm_mfma_bt<<<dim3(BL / 128, NPAD / 128), 256, 0, stream>>>(
      hbf, Wt, b_in, zx, BL, DPROJ, DM);
  // 3. dt/log-dA first (conv consumes dtb), then conv + silu + xdt
  prep_dt<<<(2 * BL * NH + 255) / 256, 256, 0, stream>>>(zx, dt_bias, A_log, dtb, ldab);
  prep_conv2<<<dim3(CONVC / 128, L / TSEG, B), 128, 0, stream>>>(
      zx, conv_w, conv_b, dtb, xconv, xdt);
  // 4. chunked scan via MFMA
  gprep<<<dim3(2 * B, NC), 64, 0, stream>>>(xconv, G);
  scanA_mfma<<<dim3(NG, NC), 64, 0, stream>>>(xdt, xconv, ldab, Sbuf, Pbuf);
  scan_chain<<<(NG * HD * DS) / 256, 256, 0, stream>>>(Sbuf, Pbuf);
  scanC_mfma<<<dim3(NG, NC), 64, 0, stream>>>(xdt, xconv, ldab, G, Sbuf, yraw);
  // 5. gate + D*x + RMSNorm + combine
  gate_norm<<<BL, 256, 0, stream>>>(zx, yraw, xconv, Dpar, norm_w, ycomb);
  // 6. Wc = W_out @ Wp_out (split-K)
  gemm_skinny_splitk<<<dim3(DI / 64, KSPLIT2), 256, 0, stream>>>(W_out, Wp_out, part2, DM, DI);
  reduce_splitk<<<(DI * DIN + 255) / 256, 256, 0, stream>>>(part2, nullptr, Wc, DI * DIN, KSPLIT2);
  // 7. out = ycomb @ Wc + bp_out (split-K)
  gemm_skinny_splitk<<<dim3(BL / 64, KSPLIT), 256, 0, stream>>>(ycomb, Wc, part, DI, BL);
  reduce_splitk<<<(BL * DIN + 255) / 256, 256, 0, stream>>>(part, bp_out, out, BL * DIN, KSPLIT);
}

// Round 12
// 285.718 us; speedup vs baseline: 2.8027x; 1.0258x over previous
//
#include <hip/hip_runtime.h>
#include <hip/hip_bf16.h>

constexpr int B = 2;
constexpr int L = 2048;
constexpr int DIN = 80;
constexpr int DM = 512;
constexpr int DI = 1024;
constexpr int DS = 64;
constexpr int KC = 7;
constexpr int HD = 64;
constexpr int NH = 16;                    // DI/HD
constexpr int CONVC = DI + 2 * DS;        // 1152
constexpr int DPROJ = 2 * DI + 2 * DS + NH; // 2192
constexpr int NPAD = 2304;                // DPROJ padded to 18*128
constexpr int BL = B * L;                 // 4096
constexpr int CHUNK = 64;
constexpr int NC = L / CHUNK;             // 32
constexpr int NG = 2 * B * NH;            // 64 scan groups (dir,b,head)
constexpr int KSPLIT = 16;                // final GEMM K-split
constexpr int KSPLIT2 = 8;                // Wc GEMM K-split
constexpr int XTS = 72;                   // LDS transposed-tile row stride (bf16)
constexpr int TSEG = 32;                  // conv time-segment per block

typedef __attribute__((ext_vector_type(8))) short bf16x8;
typedef __attribute__((ext_vector_type(4))) short s16x4;
typedef __attribute__((ext_vector_type(4))) float f32x4;

__device__ inline short f2bf(float f) {
  union { float f; unsigned u; } v; v.f = f;
  unsigned r = (v.u + 0x7FFF + ((v.u >> 16) & 1)) >> 16;  // RNE
  return (short)r;
}
__device__ inline float bf2f(short s) {
  union { unsigned u; float f; } v; v.u = ((unsigned)(unsigned short)s) << 16;
  return v.f;
}
// load 8 contiguous fp32, scale, convert to bf16x8 fragment
__device__ inline bf16x8 cvt8(const float* p, float s) {
  const float4 a = *(const float4*)p;
  const float4 b = *(const float4*)(p + 4);
  bf16x8 r;
  r[0] = f2bf(a.x * s); r[1] = f2bf(a.y * s); r[2] = f2bf(a.z * s); r[3] = f2bf(a.w * s);
  r[4] = f2bf(b.x * s); r[5] = f2bf(b.y * s); r[6] = f2bf(b.z * s); r[7] = f2bf(b.w * s);
  return r;
}

// ---------------- fp32 tiled GEMM with bias ----------------
constexpr int GBM = 128, GBN = 128, GBK = 16;

template <typename OutT>
__global__ __launch_bounds__(256) void gemm_bias(
    const float* __restrict__ A, const float* __restrict__ Bm,
    const float* __restrict__ bias, OutT* __restrict__ C,
    int M, int N, int K) {
  __shared__ float As[GBK][GBM + 4];
  __shared__ float Bs[GBK][GBN + 4];
  const int m0 = blockIdx.x * GBM;
  const int n0 = blockIdx.y * GBN;
  const int tid = threadIdx.x;
  const int tm = tid >> 4, tn = tid & 15;
  float acc[8][8] = {};
  const int arow = tid >> 2, acol = (tid & 3) << 2;
  const int brow = tid >> 5, bcol = (tid & 31) << 2;
  for (int k0 = 0; k0 < K; k0 += GBK) {
#pragma unroll
    for (int r = 0; r < 2; ++r) {
      int m = m0 + arow + r * 64;
      float4 v = make_float4(0.f, 0.f, 0.f, 0.f);
      if (m < M) v = *(const float4*)(A + (size_t)m * K + k0 + acol);
      As[acol + 0][arow + r * 64] = v.x;
      As[acol + 1][arow + r * 64] = v.y;
      As[acol + 2][arow + r * 64] = v.z;
      As[acol + 3][arow + r * 64] = v.w;
    }
#pragma unroll
    for (int r = 0; r < 2; ++r) {
      int kk = brow + r * 8;
      int n = n0 + bcol;
      float4 v = make_float4(0.f, 0.f, 0.f, 0.f);
      if (n < N) v = *(const float4*)(Bm + (size_t)(k0 + kk) * N + n);
      *(float4*)&Bs[kk][bcol] = v;
    }
    __syncthreads();
#pragma unroll
    for (int k = 0; k < GBK; ++k) {
      float a[8], bb[8];
#pragma unroll
      for (int i = 0; i < 8; ++i) a[i] = As[k][tm * 8 + i];
#pragma unroll
      for (int j = 0; j < 8; ++j) bb[j] = Bs[k][tn * 8 + j];
#pragma unroll
      for (int i = 0; i < 8; ++i)
#pragma unroll
        for (int j = 0; j < 8; ++j)
          acc[i][j] = fmaf(a[i], bb[j], acc[i][j]);
    }
    __syncthreads();
  }
#pragma unroll
  for (int i = 0; i < 8; ++i) {
    int m = m0 + tm * 8 + i;
    if (m >= M) continue;
#pragma unroll
    for (int j = 0; j < 8; ++j) {
      int n = n0 + tn * 8 + j;
      if (n < N) C[(size_t)m * N + n] = (OutT)(acc[i][j] + bias[n]);
    }
  }
}

// ---------------- W_in -> transposed, padded bf16 [NPAD][DM] -------------------
__global__ void prep_wt(const float* __restrict__ W_in, __hip_bfloat16* __restrict__ Wt) {
  const int idx = blockIdx.x * 256 + threadIdx.x;
  if (idx >= NPAD * DM) return;
  const int n = idx % NPAD;
  const int k = idx / NPAD;
  const float v = (n < DPROJ) ? W_in[(size_t)k * DPROJ + n] : 0.f;
  Wt[(size_t)n * DM + k] = (__hip_bfloat16)v;
}

// ---------------- bf16 MFMA GEMM -> bf16 C ----------------
__global__ __launch_bounds__(256) void gemm_mfma_bt(
    const __hip_bfloat16* __restrict__ A, const __hip_bfloat16* __restrict__ Bt,
    const float* __restrict__ bias, short* __restrict__ C,
    int M, int N, int K) {
  __shared__ short As[4 * 128 * 8];
  __shared__ short Bs[4 * 128 * 8];
  const int tid = threadIdx.x;
  const int l = tid & 63;
  const int wv = tid >> 6;
  const int wr = wv >> 1, wc = wv & 1;
  const int m0 = blockIdx.x * 128;
  const int n0 = blockIdx.y * 128;
  const int ks = l >> 4, lr = l & 15;
  f32x4 acc[4][4] = {};
  for (int k0 = 0; k0 < K; k0 += 32) {
#pragma unroll
    for (int i = 0; i < 2; ++i) {
      const int t = (wv * 2 + i) * 64 + l;
      const int tks = t >> 7, trow = t & 127;
      __builtin_amdgcn_global_load_lds(
          (const __attribute__((address_space(1))) unsigned int*)(A + (size_t)(m0 + trow) * K + k0 + tks * 8),
          (__attribute__((address_space(3))) unsigned int*)(As + (size_t)(wv * 2 + i) * 512),
          16, 0, 0);
      __builtin_amdgcn_global_load_lds(
          (const __attribute__((address_space(1))) unsigned int*)(Bt + (size_t)(n0 + trow) * K + k0 + tks * 8),
          (__attribute__((address_space(3))) unsigned int*)(Bs + (size_t)(wv * 2 + i) * 512),
          16, 0, 0);
    }
    __syncthreads();
    bf16x8 af[4], bfr[4];
#pragma unroll
    for (int mi = 0; mi < 4; ++mi)
      af[mi] = *(const bf16x8*)&As[(size_t)(ks * 128 + wr * 64 + mi * 16 + lr) * 8];
#pragma unroll
    for (int ni = 0; ni < 4; ++ni)
      bfr[ni] = *(const bf16x8*)&Bs[(size_t)(ks * 128 + wc * 64 + ni * 16 + lr) * 8];
#pragma unroll
    for (int mi = 0; mi < 4; ++mi)
#pragma unroll
      for (int ni = 0; ni < 4; ++ni)
        acc[mi][ni] = __builtin_amdgcn_mfma_f32_16x16x32_bf16(af[mi], bfr[ni], acc[mi][ni], 0, 0, 0);
    __syncthreads();
  }
#pragma unroll
  for (int mi = 0; mi < 4; ++mi) {
    const int row = m0 + wr * 64 + mi * 16 + (l >> 4) * 4;
#pragma unroll
    for (int ni = 0; ni < 4; ++ni) {
      const int col = n0 + wc * 64 + ni * 16 + lr;
      if (col < N) {
        const float bv = bias[col];
#pragma unroll
        for (int r = 0; r < 4; ++r)
          C[(size_t)(row + r) * N + col] = f2bf(acc[mi][ni][r] + bv);
      }
    }
  }
}

// ------- skinny GEMM split-K ------------------------------------------------
__global__ __launch_bounds__(256) void gemm_skinny_splitk(
    const float* __restrict__ A, const float* __restrict__ Bm,
    float* __restrict__ part, int Astride, int Mtotal) {
  __shared__ float As[64][65];
  __shared__ float Bs[64][80];
  const int tid = threadIdx.x;
  const int m0 = blockIdx.x * 64;
  const int k0 = blockIdx.y * 64;
  {
    const int r = tid >> 2, q = tid & 3;
#pragma unroll
    for (int j = 0; j < 4; ++j) {
      const int col = q * 16 + j * 4;
      float4 v = *(const float4*)(A + (size_t)(m0 + r) * Astride + k0 + col);
      As[r][col + 0] = v.x; As[r][col + 1] = v.y;
      As[r][col + 2] = v.z; As[r][col + 3] = v.w;
    }
#pragma unroll
    for (int j = 0; j < 5; ++j) {
      const int col = (q * 5 + j) * 4;
      float4 v = *(const float4*)(Bm + (size_t)(k0 + r) * DIN + col);
      *(float4*)&Bs[r][col] = v;
    }
  }
  __syncthreads();
  const int r0 = (tid >> 4) * 4;
  const int n0 = (tid & 15) * 5;
  float acc[4][5] = {};
  for (int k = 0; k < 64; ++k) {
    float a[4];
#pragma unroll
    for (int i = 0; i < 4; ++i) a[i] = As[r0 + i][k];
#pragma unroll
    for (int j = 0; j < 5; ++j) {
      const float bv = Bs[k][n0 + j];
#pragma unroll
      for (int i = 0; i < 4; ++i) acc[i][j] = fmaf(a[i], bv, acc[i][j]);
    }
  }
#pragma unroll
  for (int i = 0; i < 4; ++i) {
    float* o = part + ((size_t)blockIdx.y * Mtotal + m0 + r0 + i) * DIN + n0;
#pragma unroll
    for (int j = 0; j < 5; ++j) o[j] = acc[i][j];
  }
}

__global__ __launch_bounds__(256) void reduce_splitk(
    const float* __restrict__ part, const float* __restrict__ bias,
    float* __restrict__ out, int total, int nsl) {
  const int idx = blockIdx.x * 256 + threadIdx.x;
  if (idx >= total) return;
  float acc = bias ? bias[idx % DIN] : 0.f;
  for (int s = 0; s < nsl; ++s) acc += part[(size_t)s * total + idx];
  out[idx] = acc;
}

// ---------------- dt / log(dA) ----------------
__global__ void prep_dt(const short* __restrict__ zx, const float* __restrict__ dt_bias,
                        const float* __restrict__ A_log, float* __restrict__ dtb,
                        float* __restrict__ ldab) {
  const int idx = blockIdx.x * 256 + threadIdx.x;
  if (idx >= 2 * BL * NH) return;
  const int h = idx % NH;
  int rest = idx / NH;
  const int s = rest % L;
  rest /= L;
  const int bb = rest % B;
  const int d = rest / B;
  const int torig = d ? (L - 1 - s) : s;
  const float raw = bf2f(zx[((size_t)(bb * L + torig)) * DPROJ + DI + CONVC + h]) + dt_bias[h];
  const float dt = (raw > 20.f) ? raw : log1pf(expf(raw));
  dtb[idx] = dt;
  ldab[idx] = -expf(A_log[h]) * dt;   // log(dA), always <= 0
}

// ------- conv both dirs + silu -> bf16 xconv + xdt; LDS-staged window ---------
// Block = 128 channels x TSEG times. Stage rows [t0-6, t0+TSEG+6) in LDS with
// 44 INDEPENDENT loads (one latency total), then compute from LDS.
__global__ __launch_bounds__(128) void prep_conv3(
    const short* __restrict__ zx, const float* __restrict__ cw,
    const float* __restrict__ cb, const float* __restrict__ dtb,
    short* __restrict__ xconv, short* __restrict__ xdt) {
  __shared__ float Z[TSEG + 12][128];
  const int tid = threadIdx.x;
  const int c = blockIdx.x * 128 + tid;   // 0..1151
  const int b = blockIdx.z;
  const int t0 = blockIdx.y * TSEG;
  const short* src = zx + (size_t)b * L * DPROJ + DI + c;
#pragma unroll
  for (int r = 0; r < TSEG + 12; ++r) {
    const int t = t0 - 6 + r;
    float v = 0.f;
    if (t >= 0 && t < L) v = bf2f(src[(size_t)t * DPROJ]);
    Z[r][tid] = v;
  }
  const float wt0 = cw[c * KC + 0], wt1 = cw[c * KC + 1], wt2 = cw[c * KC + 2],
              wt3 = cw[c * KC + 3], wt4 = cw[c * KC + 4], wt5 = cw[c * KC + 5],
              wt6 = cw[c * KC + 6];
  const float bias = cb[c];
  short* dstF = xconv + (size_t)b * L * CONVC + c;
  short* dstB = xconv + (size_t)(B + b) * L * CONVC + c;
  const bool isx = (c < DI);
  const int h = isx ? (c >> 6) : 0;
  short* dxF = xdt + (size_t)b * L * DI + c;
  short* dxB = xdt + (size_t)(B + b) * L * DI + c;
  const float* dto = dtb + (size_t)b * L * NH + h;   // dir0 = orig-time order
  __syncthreads();
#pragma unroll 4
  for (int i = 0; i < TSEG; ++i) {
    const int t = t0 + i;
    // fwd at t: rows t-6..t = Z[i..i+6]
    float af = bias + wt0 * Z[i + 0][tid] + wt1 * Z[i + 1][tid] + wt2 * Z[i + 2][tid] +
               wt3 * Z[i + 3][tid] + wt4 * Z[i + 4][tid] + wt5 * Z[i + 5][tid] +
               wt6 * Z[i + 6][tid];
    // bwd at torig=t: rows t..t+6 with reversed taps = Z[i+6..i+12]
    float ab = bias + wt6 * Z[i + 6][tid] + wt5 * Z[i + 7][tid] + wt4 * Z[i + 8][tid] +
               wt3 * Z[i + 9][tid] + wt2 * Z[i + 10][tid] + wt1 * Z[i + 11][tid] +
               wt0 * Z[i + 12][tid];
    const float sf = af / (1.f + expf(-af));
    const float sb = ab / (1.f + expf(-ab));
    dstF[(size_t)t * CONVC] = f2bf(sf);
    dstB[(size_t)(L - 1 - t) * CONVC] = f2bf(sb);
    if (isx) {
      const float dtv = dto[(size_t)t * NH];
      dxF[(size_t)t * DI] = f2bf(sf * dtv);
      dxB[(size_t)(L - 1 - t) * DI] = f2bf(sb * dtv);
    }
  }
}

// ---------------- G-prep ----------------
__global__ __launch_bounds__(64) void gprep(
    const short* __restrict__ xconv, short* __restrict__ G) {
  const int db = blockIdx.x, c = blockIdx.y;
  const int l = threadIdx.x, lr = l & 15, lq = l >> 4;
  const size_t base_row = (size_t)db * L + c * 64;
  f32x4 acc[4][4] = {};
#pragma unroll
  for (int ks2 = 0; ks2 < 2; ++ks2) {
    const int n0 = ks2 * 32 + lq * 8;
    bf16x8 pf[4], qf[4];
#pragma unroll
    for (int mi = 0; mi < 4; ++mi)
      pf[mi] = *(const bf16x8*)&xconv[(base_row + mi * 16 + lr) * CONVC + DI + DS + n0];
#pragma unroll
    for (int ni = 0; ni < 4; ++ni)
      qf[ni] = *(const bf16x8*)&xconv[(base_row + ni * 16 + lr) * CONVC + DI + n0];
#pragma unroll
    for (int mi = 0; mi < 4; ++mi)
#pragma unroll
      for (int ni = 0; ni < 4; ++ni)
        acc[mi][ni] = __builtin_amdgcn_mfma_f32_16x16x32_bf16(pf[mi], qf[ni], acc[mi][ni], 0, 0, 0);
  }
  short* g = G + ((size_t)(db * NC + c) << 12);
#pragma unroll
  for (int mi = 0; mi < 4; ++mi)
#pragma unroll
    for (int ni = 0; ni < 4; ++ni)
#pragma unroll
      for (int r = 0; r < 4; ++r)
        g[(mi * 16 + lq * 4 + r) * 64 + ni * 16 + lr] = f2bf(acc[mi][ni][r]);
}

// ---------------- scanA ----------------
__global__ __launch_bounds__(64) void scanA_mfma(
    const short* __restrict__ xdt, const short* __restrict__ xconv,
    const float* __restrict__ ldab, float* __restrict__ Sbuf,
    float* __restrict__ Pbuf) {
  __shared__ short XT[64 * XTS];
  __shared__ short BT[64 * XTS];
  __shared__ float cumL[64];
  const int g = blockIdx.x, c = blockIdx.y;
  const int l = threadIdx.x, lr = l & 15, lq = l >> 4;
  const int hh = g & 15, db = g >> 4;
  const size_t base_row = (size_t)db * L + c * 64;
  float cum = ldab[(base_row + l) * NH + hh];
#pragma unroll
  for (int off = 1; off < 64; off <<= 1) {
    float t = __shfl_up(cum, off);
    if (l >= off) cum += t;
  }
  cumL[l] = cum;
  const float cumE = __shfl(cum, 63);
  const short* xrow = xdt + (base_row + l) * DI + hh * 64;
  const short* brow = xconv + (base_row + l) * CONVC + DI;
#pragma unroll
  for (int q = 0; q < 8; ++q) {
    const bf16x8 xv = *(const bf16x8*)&xrow[q * 8];
    const bf16x8 bv = *(const bf16x8*)&brow[q * 8];
#pragma unroll
    for (int e = 0; e < 8; ++e) {
      XT[(q * 8 + e) * XTS + l] = xv[e];
      BT[(q * 8 + e) * XTS + l] = bv[e];
    }
  }
  __syncthreads();
  f32x4 acc[4][4] = {};
#pragma unroll
  for (int ks2 = 0; ks2 < 2; ++ks2) {
    const int j0 = ks2 * 32 + lq * 8;
    const float4 c0 = *(const float4*)&cumL[j0];
    const float4 c1 = *(const float4*)&cumL[j0 + 4];
    float w[8] = {__expf(cumE - c0.x), __expf(cumE - c0.y), __expf(cumE - c0.z), __expf(cumE - c0.w),
                  __expf(cumE - c1.x), __expf(cumE - c1.y), __expf(cumE - c1.z), __expf(cumE - c1.w)};
    bf16x8 pf[4], qf[4];
#pragma unroll
    for (int mi = 0; mi < 4; ++mi) {
      const bf16x8 raw = *(const bf16x8*)&XT[(mi * 16 + lr) * XTS + j0];
#pragma unroll
      for (int jj = 0; jj < 8; ++jj) pf[mi][jj] = f2bf(bf2f(raw[jj]) * w[jj]);
    }
#pragma unroll
    for (int ni = 0; ni < 4; ++ni)
      qf[ni] = *(const bf16x8*)&BT[(ni * 16 + lr) * XTS + j0];
#pragma unroll
    for (int mi = 0; mi < 4; ++mi)
#pragma unroll
      for (int ni = 0; ni < 4; ++ni)
        acc[mi][ni] = __builtin_amdgcn_mfma_f32_16x16x32_bf16(pf[mi], qf[ni], acc[mi][ni], 0, 0, 0);
  }
  float* so = Sbuf + ((size_t)g * NC + c) * 4096;
#pragma unroll
  for (int mi = 0; mi < 4; ++mi)
#pragma unroll
    for (int ni = 0; ni < 4; ++ni)
#pragma unroll
      for (int r = 0; r < 4; ++r)
        so[(mi * 16 + lq * 4 + r) * 64 + ni * 16 + lr] = acc[mi][ni][r];
  if (l == 0) Pbuf[g * NC + c] = __expf(cumE);
}

// ---------------- chain ----------------
__global__ void scan_chain(float* __restrict__ Sbuf, const float* __restrict__ Pbuf) {
  const int idx = blockIdx.x * 256 + threadIdx.x;
  const int g = idx >> 12;
  const int e = idx & 4095;
  float run = 0.f;
  float* base = Sbuf + (size_t)g * NC * 4096 + e;
  for (int c = 0; c < NC; ++c) {
    const float sc = base[(size_t)c * 4096];
    const float pc = Pbuf[g * NC + c];
    base[(size_t)c * 4096] = run;
    run = pc * run + sc;
  }
}

// ---------------- scanC -> bf16 yraw ----------------
__global__ __launch_bounds__(64) void scanC_mfma(
    const short* __restrict__ xdt, const short* __restrict__ xconv,
    const float* __restrict__ ldab, const short* __restrict__ G,
    const float* __restrict__ Sbuf, short* __restrict__ yraw) {
  __shared__ short XT[64 * XTS];
  __shared__ float cumL[64];
  const int g = blockIdx.x, c = blockIdx.y;
  const int l = threadIdx.x, lr = l & 15, lq = l >> 4;
  const int hh = g & 15, db = g >> 4;
  const size_t base_row = (size_t)db * L + c * 64;
  float cum = ldab[(base_row + l) * NH + hh];
#pragma unroll
  for (int off = 1; off < 64; off <<= 1) {
    float t = __shfl_up(cum, off);
    if (l >= off) cum += t;
  }
  cumL[l] = cum;
  const short* xrow = xdt + (base_row + l) * DI + hh * 64;
#pragma unroll
  for (int q = 0; q < 8; ++q) {
    const bf16x8 xv = *(const bf16x8*)&xrow[q * 8];
#pragma unroll
    for (int e = 0; e < 8; ++e) XT[(q * 8 + e) * XTS + l] = xv[e];
  }
  __syncthreads();
  const float* Sin = Sbuf + ((size_t)g * NC + c) * 4096;
  const short* Gp = G + ((size_t)(db * NC + c) << 12);
  float sc[4], ci[4];
#pragma unroll
  for (int mi = 0; mi < 4; ++mi) {
    ci[mi] = cumL[mi * 16 + lr];
    sc[mi] = __expf(ci[mi]);
  }
  f32x4 acc[4][4] = {};
#pragma unroll
  for (int ks2 = 0; ks2 < 2; ++ks2) {
    const int n0 = ks2 * 32 + lq * 8;
    {
      bf16x8 pf[4], qf[4];
#pragma unroll
      for (int mi = 0; mi < 4; ++mi) {
        const bf16x8 cv = *(const bf16x8*)&xconv[(base_row + mi * 16 + lr) * CONVC + DI + DS + n0];
#pragma unroll
        for (int e = 0; e < 8; ++e) pf[mi][e] = f2bf(bf2f(cv[e]) * sc[mi]);
      }
#pragma unroll
      for (int ni = 0; ni < 4; ++ni)
        qf[ni] = cvt8(Sin + (ni * 16 + lr) * 64 + n0, 1.f);
#pragma unroll
      for (int mi = 0; mi < 4; ++mi)
#pragma unroll
        for (int ni = 0; ni < 4; ++ni)
          acc[mi][ni] = __builtin_amdgcn_mfma_f32_16x16x32_bf16(pf[mi], qf[ni], acc[mi][ni], 0, 0, 0);
    }
    {
      const float4 c0 = *(const float4*)&cumL[n0];
      const float4 c1 = *(const float4*)&cumL[n0 + 4];
      const float cj[8] = {c0.x, c0.y, c0.z, c0.w, c1.x, c1.y, c1.z, c1.w};
      bf16x8 pf[4], qf[4];
#pragma unroll
      for (int mi = 0; mi < 4; ++mi) {
        const int i = mi * 16 + lr;
        const bf16x8 gv = *(const bf16x8*)&Gp[i * 64 + n0];
#pragma unroll
        for (int jj = 0; jj < 8; ++jj) {
          const float m = (n0 + jj <= i) ? __expf(ci[mi] - cj[jj]) : 0.f;
          pf[mi][jj] = f2bf(bf2f(gv[jj]) * m);
        }
      }
#pragma unroll
      for (int ni = 0; ni < 4; ++ni)
        qf[ni] = *(const bf16x8*)&XT[(ni * 16 + lr) * XTS + n0];
#pragma unroll
      for (int mi = 0; mi < 4; ++mi)
#pragma unroll
        for (int ni = 0; ni < 4; ++ni)
          acc[mi][ni] = __builtin_amdgcn_mfma_f32_16x16x32_bf16(pf[mi], qf[ni], acc[mi][ni], 0, 0, 0);
    }
  }
#pragma unroll
  for (int mi = 0; mi < 4; ++mi)
#pragma unroll
    for (int ni = 0; ni < 4; ++ni)
#pragma unroll
      for (int r = 0; r < 4; ++r)
        yraw[(base_row + mi * 16 + lq * 4 + r) * DI + hh * 64 + ni * 16 + lr] = f2bf(acc[mi][ni][r]);
}

// ---------------- gate + D*x + RMSNorm + combine ----------------
__global__ __launch_bounds__(256) void gate_norm(
    const short* __restrict__ zx, const short* __restrict__ yraw,
    const short* __restrict__ xconv, const float* __restrict__ Dpar,
    const float* __restrict__ nw, float* __restrict__ ycomb) {
  const int bt = blockIdx.x;
  const int b = bt / L, t = bt % L;
  const int tid = threadIdx.x;
  const int c0 = tid * 4;                 // 4 consecutive channels
  const float dp = Dpar[c0 >> 6];
  const s16x4 zv4 = *(const s16x4*)&zx[(size_t)bt * DPROJ + c0];
  const s16x4 y04 = *(const s16x4*)&yraw[((size_t)b * L + t) * DI + c0];
  const s16x4 y14 = *(const s16x4*)&yraw[((size_t)(B + b) * L + (L - 1 - t)) * DI + c0];
  const s16x4 x04 = *(const s16x4*)&xconv[((size_t)b * L + t) * CONVC + c0];
  const s16x4 x14 = *(const s16x4*)&xconv[((size_t)(B + b) * L + (L - 1 - t)) * CONVC + c0];
  float a0[4], a1[4];
  float s0 = 0.f, s1 = 0.f;
#pragma unroll
  for (int r = 0; r < 4; ++r) {
    const float zv = bf2f(zv4[r]);
    const float gz = zv / (1.f + expf(-zv));
    a0[r] = (bf2f(y04[r]) + dp * bf2f(x04[r])) * gz;
    a1[r] = (bf2f(y14[r]) + dp * bf2f(x14[r])) * gz;
    s0 += a0[r] * a0[r];
    s1 += a1[r] * a1[r];
  }
#pragma unroll
  for (int off = 32; off > 0; off >>= 1) {
    s0 += __shfl_down(s0, off);
    s1 += __shfl_down(s1, off);
  }
  __shared__ float rs0[4], rs1[4];
  const int w = tid >> 6;
  if ((tid & 63) == 0) { rs0[w] = s0; rs1[w] = s1; }
  __syncthreads();
  s0 = rs0[0] + rs0[1] + rs0[2] + rs0[3];
  s1 = rs1[0] + rs1[1] + rs1[2] + rs1[3];
  const float r0 = rsqrtf(s0 * (1.f / DI) + 1e-5f);
  const float r1 = rsqrtf(s1 * (1.f / DI) + 1e-5f);
  float4 o;
  o.x = nw[c0 + 0] * (a0[0] * r0 + a1[0] * r1);
  o.y = nw[c0 + 1] * (a0[1] * r0 + a1[1] * r1);
  o.z = nw[c0 + 2] * (a0[2] * r0 + a1[2] * r1);
  o.w = nw[c0 + 3] * (a0[3] * r0 + a1[3] * r1);
  *(float4*)&ycomb[(size_t)bt * DI + c0] = o;
}

extern "C" void kernel_launch(void* const* d_in, const int* in_sizes, int n_in,
                              void* d_out, int out_size, void* d_ws, size_t ws_size,
                              hipStream_t stream) {
  const float* x       = (const float*)d_in[0];
  const float* Wp_in   = (const float*)d_in[1];
  const float* bp_in   = (const float*)d_in[2];
  const float* W_in    = (const float*)d_in[3];
  const float* b_in    = (const float*)d_in[4];
  const float* conv_w  = (const float*)d_in[5];
  const float* conv_b  = (const float*)d_in[6];
  const float* dt_bias = (const float*)d_in[7];
  const float* A_log   = (const float*)d_in[8];
  const float* Dpar    = (const float*)d_in[9];
  const float* norm_w  = (const float*)d_in[10];
  const float* W_out   = (const float*)d_in[11];
  const float* Wp_out  = (const float*)d_in[12];
  const float* bp_out  = (const float*)d_in[13];
  float* out = (float*)d_out;

  char* p = (char*)d_ws;
  __hip_bfloat16* hbf = (__hip_bfloat16*)p; p += (size_t)BL * DM * 2;
  __hip_bfloat16* Wt  = (__hip_bfloat16*)p; p += (size_t)NPAD * DM * 2;
  short* zx    = (short*)p; p += (size_t)BL * DPROJ * 2;
  short* xconv = (short*)p; p += (size_t)2 * BL * CONVC * 2;
  short* xdt   = (short*)p; p += (size_t)2 * BL * DI * 2;
  float* dtb   = (float*)p; p += (size_t)2 * BL * NH * 4;
  float* ldab  = (float*)p; p += (size_t)2 * BL * NH * 4;
  float* Sbuf  = (float*)p; p += (size_t)NG * NC * HD * DS * 4;
  float* Pbuf  = (float*)p; p += (size_t)NG * NC * 4;
  short* yraw  = (short*)p; p += (size_t)2 * BL * DI * 2;
  float* ycomb = (float*)p; p += (size_t)BL * DI * 4;
  float* Wc    = (float*)p; p += (size_t)DI * DIN * 4;
  short* G     = (short*)p; p += (size_t)2 * B * NC * 64 * 64 * 2;
  float* part2 = (float*)p; p += (size_t)KSPLIT2 * DI * DIN * 4;
  float* part  = (float*)p; p += (size_t)KSPLIT * BL * DIN * 4;
  (void)ws_size; (void)in_sizes; (void)n_in; (void)out_size;

  // 1. h = bf16(x @ Wp_in + bp_in)
  gemm_bias<__hip_bfloat16><<<dim3(BL / GBM, (DM + GBN - 1) / GBN), 256, 0, stream>>>(
      x, Wp_in, bp_in, hbf, BL, DM, DIN);
  // 1b. Wt = bf16(W_in^T), padded
  prep_wt<<<(NPAD * DM + 255) / 256, 256, 0, stream>>>(W_in, Wt);
  // 2. zxbcdt = h @ W_in + b_in (bf16 MFMA, bf16 out)
  gemm_mfma_bt<<<dim3(BL / 128, NPAD / 128), 256, 0, stream>>>(
      hbf, Wt, b_in, zx, BL, DPROJ, DM);
  // 3. dt/log-dA first (conv consumes dtb), then LDS-staged conv + silu + xdt
  prep_dt<<<(2 * BL * NH + 255) / 256, 256, 0, stream>>>(zx, dt_bias, A_log, dtb, ldab);
  prep_conv3<<<dim3(CONVC / 128, L / TSEG, B), 128, 0, stream>>>(
      zx, conv_w, conv_b, dtb, xconv, xdt);
  // 4. chunked scan via MFMA
  gprep<<<dim3(2 * B, NC), 64, 0, stream>>>(xconv, G);
  scanA_mfma<<<dim3(NG, NC), 64, 0, stream>>>(xdt, xconv, ldab, Sbuf, Pbuf);
  scan_chain<<<(NG * HD * DS) / 256, 256, 0, stream>>>(Sbuf, Pbuf);
  scanC_mfma<<<dim3(NG, NC), 64, 0, stream>>>(xdt, xconv, ldab, G, Sbuf, yraw);
  // 5. gate + D*x + RMSNorm + combine
  gate_norm<<<BL, 256, 0, stream>>>(zx, yraw, xconv, Dpar, norm_w, ycomb);
  // 6. Wc = W_out @ Wp_out (split-K)
  gemm_skinny_splitk<<<dim3(DI / 64, KSPLIT2), 256, 0, stream>>>(W_out, Wp_out, part2, DM, DI);
  reduce_splitk<<<(DI * DIN + 255) / 256, 256, 0, stream>>>(part2, nullptr, Wc, DI * DIN, KSPLIT2);
  // 7. out = ycomb @ Wc + bp_out (split-K)
  gemm_skinny_splitk<<<dim3(BL / 64, KSPLIT), 256, 0, stream>>>(ycomb, Wc, part, DI, BL);
  reduce_splitk<<<(BL * DIN + 255) / 256, 256, 0, stream>>>(part, bp_out, out, BL * DIN, KSPLIT);
}

// Round 13
// 244.186 us; speedup vs baseline: 3.2794x; 1.1701x over previous
//
#include <hip/hip_runtime.h>
#include <hip/hip_bf16.h>

constexpr int B = 2;
constexpr int L = 2048;
constexpr int DIN = 80;
constexpr int DM = 512;
constexpr int DI = 1024;
constexpr int DS = 64;
constexpr int KC = 7;
constexpr int HD = 64;
constexpr int NH = 16;                    // DI/HD
constexpr int CONVC = DI + 2 * DS;        // 1152
constexpr int DPROJ = 2 * DI + 2 * DS + NH; // 2192
constexpr int NPAD = 2304;                // DPROJ padded to 18*128
constexpr int BL = B * L;                 // 4096
constexpr int CHUNK = 64;
constexpr int NC = L / CHUNK;             // 32
constexpr int NG = 2 * B * NH;            // 64 scan groups (dir,b,head)
constexpr int KF = 96;                    // folded K (80 feats + 1 bias + pad)
constexpr int KSPLIT = 16;                // final GEMM K-split (K=1024)
constexpr int KSPLIT2 = 8;                // Wc GEMM K-split (K=512)
constexpr int KSPLITW = 8;                // Wfold GEMM K-split (K=512)
constexpr int XTS = 72;                   // LDS transposed-tile row stride (bf16)
constexpr int TSEG = 32;                  // conv time-segment per block

typedef __attribute__((ext_vector_type(8))) short bf16x8;
typedef __attribute__((ext_vector_type(4))) short s16x4;
typedef __attribute__((ext_vector_type(4))) float f32x4;

__device__ inline short f2bf(float f) {
  union { float f; unsigned u; } v; v.f = f;
  unsigned r = (v.u + 0x7FFF + ((v.u >> 16) & 1)) >> 16;  // RNE
  return (short)r;
}
__device__ inline float bf2f(short s) {
  union { unsigned u; float f; } v; v.u = ((unsigned)(unsigned short)s) << 16;
  return v.f;
}

// ---------------- W_in -> transposed fp32 [NPAD][DM] (LDS tile transpose) ------
__global__ __launch_bounds__(256) void prep_wtT(const float* __restrict__ W_in,
                                                float* __restrict__ WtT) {
  __shared__ float tile[64][65];
  const int n0 = blockIdx.x * 64;
  const int k0 = blockIdx.y * 64;
  const int tx = threadIdx.x & 63, ty = threadIdx.x >> 6;
#pragma unroll
  for (int i = 0; i < 16; ++i) {
    const int r = ty * 16 + i;
    const int n = n0 + tx;
    tile[r][tx] = (n < DPROJ) ? W_in[(size_t)(k0 + r) * DPROJ + n] : 0.f;
  }
  __syncthreads();
#pragma unroll
  for (int i = 0; i < 16; ++i) {
    const int r = ty * 16 + i;
    WtT[(size_t)(n0 + r) * DM + k0 + tx] = tile[tx][r];
  }
}

// ---------------- Bmx [DM][KF]: cols 0-79 = Wp_in^T, col 80 = bp_in ------------
__global__ void prep_bmx(const float* __restrict__ Wp_in, const float* __restrict__ bp_in,
                         float* __restrict__ Bmx) {
  const int idx = blockIdx.x * 256 + threadIdx.x;
  if (idx >= DM * KF) return;
  const int m = idx / KF, k = idx % KF;
  float v = 0.f;
  if (k < DIN) v = Wp_in[(size_t)k * DM + m];
  else if (k == DIN) v = bp_in[m];
  Bmx[idx] = v;
}

// ---------------- xpad bf16 [BL][KF]: x cols + 1.0 bias col --------------------
__global__ void prep_xpad(const float* __restrict__ x, short* __restrict__ xpad) {
  const int idx = blockIdx.x * 256 + threadIdx.x;
  if (idx >= BL * KF) return;
  const int r = idx / KF, k = idx % KF;
  float v = 0.f;
  if (k < DIN) v = x[(size_t)r * DIN + k];
  else if (k == DIN) v = 1.f;
  xpad[idx] = f2bf(v);
}

// ------- skinny GEMM split-K: part[sk][M][NCOLS] = A[:,k-slice]*Bm[k-slice,:] --
// grid (M/64, K/64); A row stride = Astride; Bm row stride = NCOLS.
template <int NCOLS>
__global__ __launch_bounds__(256) void gemm_skinny_splitk(
    const float* __restrict__ A, const float* __restrict__ Bm,
    float* __restrict__ part, int Astride, int Mtotal) {
  __shared__ float As[64][65];
  __shared__ float Bs[64][NCOLS];
  constexpr int CPT = NCOLS / 16;  // cols per thread
  const int tid = threadIdx.x;
  const int m0 = blockIdx.x * 64;
  const int k0 = blockIdx.y * 64;
  {
    const int r = tid >> 2, q = tid & 3;
#pragma unroll
    for (int j = 0; j < 4; ++j) {
      const int col = q * 16 + j * 4;
      float4 v = *(const float4*)(A + (size_t)(m0 + r) * Astride + k0 + col);
      As[r][col + 0] = v.x; As[r][col + 1] = v.y;
      As[r][col + 2] = v.z; As[r][col + 3] = v.w;
    }
#pragma unroll
    for (int j = 0; j < CPT; ++j) {
      const int col = (q * CPT + j) * 4;
      float4 v = *(const float4*)(Bm + (size_t)(k0 + r) * NCOLS + col);
      *(float4*)&Bs[r][col] = v;
    }
  }
  __syncthreads();
  const int r0 = (tid >> 4) * 4;
  const int n0 = (tid & 15) * CPT;
  float acc[4][CPT] = {};
  for (int k = 0; k < 64; ++k) {
    float a[4];
#pragma unroll
    for (int i = 0; i < 4; ++i) a[i] = As[r0 + i][k];
#pragma unroll
    for (int j = 0; j < CPT; ++j) {
      const float bv = Bs[k][n0 + j];
#pragma unroll
      for (int i = 0; i < 4; ++i) acc[i][j] = fmaf(a[i], bv, acc[i][j]);
    }
  }
#pragma unroll
  for (int i = 0; i < 4; ++i) {
    float* o = part + ((size_t)blockIdx.y * Mtotal + m0 + r0 + i) * NCOLS + n0;
#pragma unroll
    for (int j = 0; j < CPT; ++j) o[j] = acc[i][j];
  }
}

__global__ __launch_bounds__(256) void reduce_splitk(
    const float* __restrict__ part, const float* __restrict__ bias,
    float* __restrict__ out, int total, int nsl, int ncols) {
  const int idx = blockIdx.x * 256 + threadIdx.x;
  if (idx >= total) return;
  float acc = bias ? bias[idx % ncols] : 0.f;
  for (int s = 0; s < nsl; ++s) acc += part[(size_t)s * total + idx];
  out[idx] = acc;
}

__global__ __launch_bounds__(256) void reduce_bf16(
    const float* __restrict__ part, short* __restrict__ out, int total, int nsl) {
  const int idx = blockIdx.x * 256 + threadIdx.x;
  if (idx >= total) return;
  float acc = 0.f;
  for (int s = 0; s < nsl; ++s) acc += part[(size_t)s * total + idx];
  out[idx] = f2bf(acc);
}

// ---------------- bf16 MFMA GEMM -> bf16 C: C = A * Bt^T + bias ----------------
__global__ __launch_bounds__(256) void gemm_mfma_bt(
    const short* __restrict__ A, const short* __restrict__ Bt,
    const float* __restrict__ bias, short* __restrict__ C,
    int M, int N, int K) {
  __shared__ short As[4 * 128 * 8];
  __shared__ short Bs[4 * 128 * 8];
  const int tid = threadIdx.x;
  const int l = tid & 63;
  const int wv = tid >> 6;
  const int wr = wv >> 1, wc = wv & 1;
  const int m0 = blockIdx.x * 128;
  const int n0 = blockIdx.y * 128;
  const int ks = l >> 4, lr = l & 15;
  f32x4 acc[4][4] = {};
  for (int k0 = 0; k0 < K; k0 += 32) {
#pragma unroll
    for (int i = 0; i < 2; ++i) {
      const int t = (wv * 2 + i) * 64 + l;
      const int tks = t >> 7, trow = t & 127;
      __builtin_amdgcn_global_load_lds(
          (const __attribute__((address_space(1))) unsigned int*)(A + (size_t)(m0 + trow) * K + k0 + tks * 8),
          (__attribute__((address_space(3))) unsigned int*)(As + (size_t)(wv * 2 + i) * 512),
          16, 0, 0);
      __builtin_amdgcn_global_load_lds(
          (const __attribute__((address_space(1))) unsigned int*)(Bt + (size_t)(n0 + trow) * K + k0 + tks * 8),
          (__attribute__((address_space(3))) unsigned int*)(Bs + (size_t)(wv * 2 + i) * 512),
          16, 0, 0);
    }
    __syncthreads();
    bf16x8 af[4], bfr[4];
#pragma unroll
    for (int mi = 0; mi < 4; ++mi)
      af[mi] = *(const bf16x8*)&As[(size_t)(ks * 128 + wr * 64 + mi * 16 + lr) * 8];
#pragma unroll
    for (int ni = 0; ni < 4; ++ni)
      bfr[ni] = *(const bf16x8*)&Bs[(size_t)(ks * 128 + wc * 64 + ni * 16 + lr) * 8];
#pragma unroll
    for (int mi = 0; mi < 4; ++mi)
#pragma unroll
      for (int ni = 0; ni < 4; ++ni)
        acc[mi][ni] = __builtin_amdgcn_mfma_f32_16x16x32_bf16(af[mi], bfr[ni], acc[mi][ni], 0, 0, 0);
    __syncthreads();
  }
#pragma unroll
  for (int mi = 0; mi < 4; ++mi) {
    const int row = m0 + wr * 64 + mi * 16 + (l >> 4) * 4;
#pragma unroll
    for (int ni = 0; ni < 4; ++ni) {
      const int col = n0 + wc * 64 + ni * 16 + lr;
      if (col < N) {
        const float bv = bias[col];
#pragma unroll
        for (int r = 0; r < 4; ++r)
          C[(size_t)(row + r) * N + col] = f2bf(acc[mi][ni][r] + bv);
      }
    }
  }
}

// ---------------- dt / log(dA) ----------------
__global__ void prep_dt(const short* __restrict__ zx, const float* __restrict__ dt_bias,
                        const float* __restrict__ A_log, float* __restrict__ dtb,
                        float* __restrict__ ldab) {
  const int idx = blockIdx.x * 256 + threadIdx.x;
  if (idx >= 2 * BL * NH) return;
  const int h = idx % NH;
  int rest = idx / NH;
  const int s = rest % L;
  rest /= L;
  const int bb = rest % B;
  const int d = rest / B;
  const int torig = d ? (L - 1 - s) : s;
  const float raw = bf2f(zx[((size_t)(bb * L + torig)) * DPROJ + DI + CONVC + h]) + dt_bias[h];
  const float dt = (raw > 20.f) ? raw : log1pf(expf(raw));
  dtb[idx] = dt;
  ldab[idx] = -expf(A_log[h]) * dt;   // log(dA), always <= 0
}

// ------- conv both dirs + silu -> bf16 xconv; LDS-staged window ----------------
__global__ __launch_bounds__(128) void prep_conv3(
    const short* __restrict__ zx, const float* __restrict__ cw,
    const float* __restrict__ cb, short* __restrict__ xconv) {
  __shared__ float Z[TSEG + 12][128];
  const int tid = threadIdx.x;
  const int c = blockIdx.x * 128 + tid;   // 0..1151
  const int b = blockIdx.z;
  const int t0 = blockIdx.y * TSEG;
  const short* src = zx + (size_t)b * L * DPROJ + DI + c;
#pragma unroll
  for (int r = 0; r < TSEG + 12; ++r) {
    const int t = t0 - 6 + r;
    float v = 0.f;
    if (t >= 0 && t < L) v = bf2f(src[(size_t)t * DPROJ]);
    Z[r][tid] = v;
  }
  const float wt0 = cw[c * KC + 0], wt1 = cw[c * KC + 1], wt2 = cw[c * KC + 2],
              wt3 = cw[c * KC + 3], wt4 = cw[c * KC + 4], wt5 = cw[c * KC + 5],
              wt6 = cw[c * KC + 6];
  const float bias = cb[c];
  short* dstF = xconv + (size_t)b * L * CONVC + c;
  short* dstB = xconv + (size_t)(B + b) * L * CONVC + c;
  __syncthreads();
#pragma unroll 4
  for (int i = 0; i < TSEG; ++i) {
    const int t = t0 + i;
    float af = bias + wt0 * Z[i + 0][tid] + wt1 * Z[i + 1][tid] + wt2 * Z[i + 2][tid] +
               wt3 * Z[i + 3][tid] + wt4 * Z[i + 4][tid] + wt5 * Z[i + 5][tid] +
               wt6 * Z[i + 6][tid];
    float ab = bias + wt6 * Z[i + 6][tid] + wt5 * Z[i + 7][tid] + wt4 * Z[i + 8][tid] +
               wt3 * Z[i + 9][tid] + wt2 * Z[i + 10][tid] + wt1 * Z[i + 11][tid] +
               wt0 * Z[i + 12][tid];
    dstF[(size_t)t * CONVC] = f2bf(af / (1.f + expf(-af)));
    dstB[(size_t)(L - 1 - t) * CONVC] = f2bf(ab / (1.f + expf(-ab)));
  }
}

// ---------------- G-prep ----------------
__global__ __launch_bounds__(64) void gprep(
    const short* __restrict__ xconv, short* __restrict__ G) {
  const int db = blockIdx.x, c = blockIdx.y;
  const int l = threadIdx.x, lr = l & 15, lq = l >> 4;
  const size_t base_row = (size_t)db * L + c * 64;
  f32x4 acc[4][4] = {};
#pragma unroll
  for (int ks2 = 0; ks2 < 2; ++ks2) {
    const int n0 = ks2 * 32 + lq * 8;
    bf16x8 pf[4], qf[4];
#pragma unroll
    for (int mi = 0; mi < 4; ++mi)
      pf[mi] = *(const bf16x8*)&xconv[(base_row + mi * 16 + lr) * CONVC + DI + DS + n0];
#pragma unroll
    for (int ni = 0; ni < 4; ++ni)
      qf[ni] = *(const bf16x8*)&xconv[(base_row + ni * 16 + lr) * CONVC + DI + n0];
#pragma unroll
    for (int mi = 0; mi < 4; ++mi)
#pragma unroll
      for (int ni = 0; ni < 4; ++ni)
        acc[mi][ni] = __builtin_amdgcn_mfma_f32_16x16x32_bf16(pf[mi], qf[ni], acc[mi][ni], 0, 0, 0);
  }
  short* g = G + ((size_t)(db * NC + c) << 12);
#pragma unroll
  for (int mi = 0; mi < 4; ++mi)
#pragma unroll
    for (int ni = 0; ni < 4; ++ni)
#pragma unroll
      for (int r = 0; r < 4; ++r)
        g[(mi * 16 + lq * 4 + r) * 64 + ni * 16 + lr] = f2bf(acc[mi][ni][r]);
}

// ---------------- scanA: dt applied in staging; Sbuf bf16 out ------------------
__global__ __launch_bounds__(64) void scanA_mfma(
    const short* __restrict__ xconv, const float* __restrict__ dtb,
    const float* __restrict__ ldab, short* __restrict__ Sbuf,
    float* __restrict__ Pbuf) {
  __shared__ short XT[64 * XTS];
  __shared__ short BT[64 * XTS];
  __shared__ float cumL[64];
  const int g = blockIdx.x, c = blockIdx.y;
  const int l = threadIdx.x, lr = l & 15, lq = l >> 4;
  const int hh = g & 15, db = g >> 4;
  const size_t base_row = (size_t)db * L + c * 64;
  const float dt_l = dtb[(base_row + l) * NH + hh];
  float cum = ldab[(base_row + l) * NH + hh];
#pragma unroll
  for (int off = 1; off < 64; off <<= 1) {
    float t = __shfl_up(cum, off);
    if (l >= off) cum += t;
  }
  cumL[l] = cum;
  const float cumE = __shfl(cum, 63);
  const short* xrow = xconv + (base_row + l) * CONVC + hh * 64;
  const short* brow = xconv + (base_row + l) * CONVC + DI;
#pragma unroll
  for (int q = 0; q < 8; ++q) {
    const bf16x8 xv = *(const bf16x8*)&xrow[q * 8];
    const bf16x8 bv = *(const bf16x8*)&brow[q * 8];
#pragma unroll
    for (int e = 0; e < 8; ++e) {
      XT[(q * 8 + e) * XTS + l] = f2bf(bf2f(xv[e]) * dt_l);
      BT[(q * 8 + e) * XTS + l] = bv[e];
    }
  }
  __syncthreads();
  f32x4 acc[4][4] = {};
#pragma unroll
  for (int ks2 = 0; ks2 < 2; ++ks2) {
    const int j0 = ks2 * 32 + lq * 8;
    const float4 c0 = *(const float4*)&cumL[j0];
    const float4 c1 = *(const float4*)&cumL[j0 + 4];
    float w[8] = {__expf(cumE - c0.x), __expf(cumE - c0.y), __expf(cumE - c0.z), __expf(cumE - c0.w),
                  __expf(cumE - c1.x), __expf(cumE - c1.y), __expf(cumE - c1.z), __expf(cumE - c1.w)};
    bf16x8 pf[4], qf[4];
#pragma unroll
    for (int mi = 0; mi < 4; ++mi) {
      const bf16x8 raw = *(const bf16x8*)&XT[(mi * 16 + lr) * XTS + j0];
#pragma unroll
      for (int jj = 0; jj < 8; ++jj) pf[mi][jj] = f2bf(bf2f(raw[jj]) * w[jj]);
    }
#pragma unroll
    for (int ni = 0; ni < 4; ++ni)
      qf[ni] = *(const bf16x8*)&BT[(ni * 16 + lr) * XTS + j0];
#pragma unroll
    for (int mi = 0; mi < 4; ++mi)
#pragma unroll
      for (int ni = 0; ni < 4; ++ni)
        acc[mi][ni] = __builtin_amdgcn_mfma_f32_16x16x32_bf16(pf[mi], qf[ni], acc[mi][ni], 0, 0, 0);
  }
  short* so = Sbuf + ((size_t)g * NC + c) * 4096;
#pragma unroll
  for (int mi = 0; mi < 4; ++mi)
#pragma unroll
    for (int ni = 0; ni < 4; ++ni)
#pragma unroll
      for (int r = 0; r < 4; ++r)
        so[(mi * 16 + lq * 4 + r) * 64 + ni * 16 + lr] = f2bf(acc[mi][ni][r]);
  if (l == 0) Pbuf[g * NC + c] = __expf(cumE);
}

// ---------------- chain (bf16 Sbuf, fp32 accumulate) ----------------
__global__ void scan_chain(short* __restrict__ Sbuf, const float* __restrict__ Pbuf) {
  const int idx = blockIdx.x * 256 + threadIdx.x;
  const int g = idx >> 12;
  const int e = idx & 4095;
  float run = 0.f;
  short* base = Sbuf + (size_t)g * NC * 4096 + e;
  for (int c = 0; c < NC; ++c) {
    const float sc = bf2f(base[(size_t)c * 4096]);
    const float pc = Pbuf[g * NC + c];
    base[(size_t)c * 4096] = f2bf(run);
    run = pc * run + sc;
  }
}

// ---------------- scanC -> bf16 yraw ----------------
__global__ __launch_bounds__(64) void scanC_mfma(
    const short* __restrict__ xconv, const float* __restrict__ dtb,
    const float* __restrict__ ldab, const short* __restrict__ G,
    const short* __restrict__ Sbuf, short* __restrict__ yraw) {
  __shared__ short XT[64 * XTS];
  __shared__ float cumL[64];
  const int g = blockIdx.x, c = blockIdx.y;
  const int l = threadIdx.x, lr = l & 15, lq = l >> 4;
  const int hh = g & 15, db = g >> 4;
  const size_t base_row = (size_t)db * L + c * 64;
  const float dt_l = dtb[(base_row + l) * NH + hh];
  float cum = ldab[(base_row + l) * NH + hh];
#pragma unroll
  for (int off = 1; off < 64; off <<= 1) {
    float t = __shfl_up(cum, off);
    if (l >= off) cum += t;
  }
  cumL[l] = cum;
  const short* xrow = xconv + (base_row + l) * CONVC + hh * 64;
#pragma unroll
  for (int q = 0; q < 8; ++q) {
    const bf16x8 xv = *(const bf16x8*)&xrow[q * 8];
#pragma unroll
    for (int e = 0; e < 8; ++e) XT[(q * 8 + e) * XTS + l] = f2bf(bf2f(xv[e]) * dt_l);
  }
  __syncthreads();
  const short* Sin = Sbuf + ((size_t)g * NC + c) * 4096;
  const short* Gp = G + ((size_t)(db * NC + c) << 12);
  float sc[4], ci[4];
#pragma unroll
  for (int mi = 0; mi < 4; ++mi) {
    ci[mi] = cumL[mi * 16 + lr];
    sc[mi] = __expf(ci[mi]);
  }
  f32x4 acc[4][4] = {};
#pragma unroll
  for (int ks2 = 0; ks2 < 2; ++ks2) {
    const int n0 = ks2 * 32 + lq * 8;
    {
      bf16x8 pf[4], qf[4];
#pragma unroll
      for (int mi = 0; mi < 4; ++mi) {
        const bf16x8 cv = *(const bf16x8*)&xconv[(base_row + mi * 16 + lr) * CONVC + DI + DS + n0];
#pragma unroll
        for (int e = 0; e < 8; ++e) pf[mi][e] = f2bf(bf2f(cv[e]) * sc[mi]);
      }
#pragma unroll
      for (int ni = 0; ni < 4; ++ni)
        qf[ni] = *(const bf16x8*)&Sin[(ni * 16 + lr) * 64 + n0];
#pragma unroll
      for (int mi = 0; mi < 4; ++mi)
#pragma unroll
        for (int ni = 0; ni < 4; ++ni)
          acc[mi][ni] = __builtin_amdgcn_mfma_f32_16x16x32_bf16(pf[mi], qf[ni], acc[mi][ni], 0, 0, 0);
    }
    {
      const float4 c0 = *(const float4*)&cumL[n0];
      const float4 c1 = *(const float4*)&cumL[n0 + 4];
      const float cj[8] = {c0.x, c0.y, c0.z, c0.w, c1.x, c1.y, c1.z, c1.w};
      bf16x8 pf[4], qf[4];
#pragma unroll
      for (int mi = 0; mi < 4; ++mi) {
        const int i = mi * 16 + lr;
        const bf16x8 gv = *(const bf16x8*)&Gp[i * 64 + n0];
#pragma unroll
        for (int jj = 0; jj < 8; ++jj) {
          const float m = (n0 + jj <= i) ? __expf(ci[mi] - cj[jj]) : 0.f;
          pf[mi][jj] = f2bf(bf2f(gv[jj]) * m);
        }
      }
#pragma unroll
      for (int ni = 0; ni < 4; ++ni)
        qf[ni] = *(const bf16x8*)&XT[(ni * 16 + lr) * XTS + n0];
#pragma unroll
      for (int mi = 0; mi < 4; ++mi)
#pragma unroll
        for (int ni = 0; ni < 4; ++ni)
          acc[mi][ni] = __builtin_amdgcn_mfma_f32_16x16x32_bf16(pf[mi], qf[ni], acc[mi][ni], 0, 0, 0);
    }
  }
#pragma unroll
  for (int mi = 0; mi < 4; ++mi)
#pragma unroll
    for (int ni = 0; ni < 4; ++ni)
#pragma unroll
      for (int r = 0; r < 4; ++r)
        yraw[(base_row + mi * 16 + lq * 4 + r) * DI + hh * 64 + ni * 16 + lr] = f2bf(acc[mi][ni][r]);
}

// ---------------- gate + D*x + RMSNorm + combine ----------------
__global__ __launch_bounds__(256) void gate_norm(
    const short* __restrict__ zx, const short* __restrict__ yraw,
    const short* __restrict__ xconv, const float* __restrict__ Dpar,
    const float* __restrict__ nw, float* __restrict__ ycomb) {
  const int bt = blockIdx.x;
  const int b = bt / L, t = bt % L;
  const int tid = threadIdx.x;
  const int c0 = tid * 4;
  const float dp = Dpar[c0 >> 6];
  const s16x4 zv4 = *(const s16x4*)&zx[(size_t)bt * DPROJ + c0];
  const s16x4 y04 = *(const s16x4*)&yraw[((size_t)b * L + t) * DI + c0];
  const s16x4 y14 = *(const s16x4*)&yraw[((size_t)(B + b) * L + (L - 1 - t)) * DI + c0];
  const s16x4 x04 = *(const s16x4*)&xconv[((size_t)b * L + t) * CONVC + c0];
  const s16x4 x14 = *(const s16x4*)&xconv[((size_t)(B + b) * L + (L - 1 - t)) * CONVC + c0];
  float a0[4], a1[4];
  float s0 = 0.f, s1 = 0.f;
#pragma unroll
  for (int r = 0; r < 4; ++r) {
    const float zv = bf2f(zv4[r]);
    const float gz = zv / (1.f + expf(-zv));
    a0[r] = (bf2f(y04[r]) + dp * bf2f(x04[r])) * gz;
    a1[r] = (bf2f(y14[r]) + dp * bf2f(x14[r])) * gz;
    s0 += a0[r] * a0[r];
    s1 += a1[r] * a1[r];
  }
#pragma unroll
  for (int off = 32; off > 0; off >>= 1) {
    s0 += __shfl_down(s0, off);
    s1 += __shfl_down(s1, off);
  }
  __shared__ float rs0[4], rs1[4];
  const int w = tid >> 6;
  if ((tid & 63) == 0) { rs0[w] = s0; rs1[w] = s1; }
  __syncthreads();
  s0 = rs0[0] + rs0[1] + rs0[2] + rs0[3];
  s1 = rs1[0] + rs1[1] + rs1[2] + rs1[3];
  const float r0 = rsqrtf(s0 * (1.f / DI) + 1e-5f);
  const float r1 = rsqrtf(s1 * (1.f / DI) + 1e-5f);
  float4 o;
  o.x = nw[c0 + 0] * (a0[0] * r0 + a1[0] * r1);
  o.y = nw[c0 + 1] * (a0[1] * r0 + a1[1] * r1);
  o.z = nw[c0 + 2] * (a0[2] * r0 + a1[2] * r1);
  o.w = nw[c0 + 3] * (a0[3] * r0 + a1[3] * r1);
  *(float4*)&ycomb[(size_t)bt * DI + c0] = o;
}

extern "C" void kernel_launch(void* const* d_in, const int* in_sizes, int n_in,
                              void* d_out, int out_size, void* d_ws, size_t ws_size,
                              hipStream_t stream) {
  const float* x       = (const float*)d_in[0];
  const float* Wp_in   = (const float*)d_in[1];
  const float* bp_in   = (const float*)d_in[2];
  const float* W_in    = (const float*)d_in[3];
  const float* b_in    = (const float*)d_in[4];
  const float* conv_w  = (const float*)d_in[5];
  const float* conv_b  = (const float*)d_in[6];
  const float* dt_bias = (const float*)d_in[7];
  const float* A_log   = (const float*)d_in[8];
  const float* Dpar    = (const float*)d_in[9];
  const float* norm_w  = (const float*)d_in[10];
  const float* W_out   = (const float*)d_in[11];
  const float* Wp_out  = (const float*)d_in[12];
  const float* bp_out  = (const float*)d_in[13];
  float* out = (float*)d_out;

  char* p = (char*)d_ws;
  short* zx    = (short*)p; p += (size_t)BL * DPROJ * 2;
  short* xconv = (short*)p; p += (size_t)2 * BL * CONVC * 2;
  float* dtb   = (float*)p; p += (size_t)2 * BL * NH * 4;
  float* ldab  = (float*)p; p += (size_t)2 * BL * NH * 4;
  short* Sbuf  = (short*)p; p += (size_t)NG * NC * HD * DS * 2;
  float* Pbuf  = (float*)p; p += (size_t)NG * NC * 4;
  short* yraw  = (short*)p; p += (size_t)2 * BL * DI * 2;
  float* ycomb = (float*)p; p += (size_t)BL * DI * 4;
  float* Wc    = (float*)p; p += (size_t)DI * DIN * 4;
  short* G     = (short*)p; p += (size_t)2 * B * NC * 64 * 64 * 2;
  float* WtT   = (float*)p; p += (size_t)NPAD * DM * 4;
  float* Bmx   = (float*)p; p += (size_t)DM * KF * 4;
  short* WtF   = (short*)p; p += (size_t)NPAD * KF * 2;
  short* xpad  = (short*)p; p += (size_t)BL * KF * 2;
  float* partW = (float*)p; p += (size_t)KSPLITW * NPAD * KF * 4;
  float* part2 = (float*)p; p += (size_t)KSPLIT2 * DI * DIN * 4;
  float* part  = (float*)p; p += (size_t)KSPLIT * BL * DIN * 4;
  (void)ws_size; (void)in_sizes; (void)n_in; (void)out_size;

  // 0. fold input projection: WtF = ((Wp_in@W_in) with bp_in col)^T, bf16
  prep_wtT<<<dim3(NPAD / 64, DM / 64), 256, 0, stream>>>(W_in, WtT);
  prep_bmx<<<(DM * KF + 255) / 256, 256, 0, stream>>>(Wp_in, bp_in, Bmx);
  gemm_skinny_splitk<KF><<<dim3(NPAD / 64, KSPLITW), 256, 0, stream>>>(
      WtT, Bmx, partW, DM, NPAD);
  reduce_bf16<<<(NPAD * KF + 255) / 256, 256, 0, stream>>>(partW, WtF, NPAD * KF, KSPLITW);
  prep_xpad<<<(BL * KF + 255) / 256, 256, 0, stream>>>(x, xpad);
  // 1. zxbcdt = xpad @ WtF^T + b_in (bf16 MFMA, K=96)
  gemm_mfma_bt<<<dim3(BL / 128, NPAD / 128), 256, 0, stream>>>(
      xpad, WtF, b_in, zx, BL, DPROJ, KF);
  // 2. dt/log-dA; conv + silu
  prep_dt<<<(2 * BL * NH + 255) / 256, 256, 0, stream>>>(zx, dt_bias, A_log, dtb, ldab);
  prep_conv3<<<dim3(CONVC / 128, L / TSEG, B), 128, 0, stream>>>(zx, conv_w, conv_b, xconv);
  // 3. chunked scan via MFMA
  gprep<<<dim3(2 * B, NC), 64, 0, stream>>>(xconv, G);
  scanA_mfma<<<dim3(NG, NC), 64, 0, stream>>>(xconv, dtb, ldab, Sbuf, Pbuf);
  scan_chain<<<(NG * HD * DS) / 256, 256, 0, stream>>>(Sbuf, Pbuf);
  scanC_mfma<<<dim3(NG, NC), 64, 0, stream>>>(xconv, dtb, ldab, G, Sbuf, yraw);
  // 4. gate + D*x + RMSNorm + combine
  gate_norm<<<BL, 256, 0, stream>>>(zx, yraw, xconv, Dpar, norm_w, ycomb);
  // 5. Wc = W_out @ Wp_out (split-K)
  gemm_skinny_splitk<DIN><<<dim3(DI / 64, KSPLIT2), 256, 0, stream>>>(W_out, Wp_out, part2, DM, DI);
  reduce_splitk<<<(DI * DIN + 255) / 256, 256, 0, stream>>>(part2, nullptr, Wc, DI * DIN, KSPLIT2, DIN);
  // 6. out = ycomb @ Wc + bp_out (split-K)
  gemm_skinny_splitk<DIN><<<dim3(BL / 64, KSPLIT), 256, 0, stream>>>(ycomb, Wc, part, DI, BL);
  reduce_splitk<<<(BL * DIN + 255) / 256, 256, 0, stream>>>(part, bp_out, out, BL * DIN, KSPLIT, DIN);
}

// Round 15
// 233.527 us; speedup vs baseline: 3.4291x; 1.0456x over previous
//
#include <hip/hip_runtime.h>
#include <hip/hip_bf16.h>

constexpr int B = 2;
constexpr int L = 2048;
constexpr int DIN = 80;
constexpr int DM = 512;
constexpr int DI = 1024;
constexpr int DS = 64;
constexpr int KC = 7;
constexpr int HD = 64;
constexpr int NH = 16;                    // DI/HD
constexpr int CONVC = DI + 2 * DS;        // 1152
constexpr int DPROJ = 2 * DI + 2 * DS + NH; // 2192
constexpr int NPAD = 2304;                // DPROJ padded to 18*128
constexpr int BL = B * L;                 // 4096
constexpr int CHUNK = 64;
constexpr int NC = L / CHUNK;             // 32
constexpr int NG = 2 * B * NH;            // 64 scan groups (dir,b,head)
constexpr int KF = 96;                    // folded K (80 feats + 1 bias + pad)
constexpr int KSPLITF = 8;                // final GEMM K-split (K=1024, 2 tiles/block)
constexpr int KSPLIT2 = 8;                // Wc GEMM K-split (K=512)
constexpr int KSPLITW = 8;                // Wfold GEMM K-split (K=512)
constexpr int XTS = 72;                   // LDS transposed-tile row stride (bf16)
constexpr int TSEG = 32;                  // conv time-segment per block

typedef __attribute__((ext_vector_type(8))) short bf16x8;
typedef __attribute__((ext_vector_type(4))) short s16x4;
typedef __attribute__((ext_vector_type(4))) float f32x4;

__device__ inline short f2bf(float f) {
  union { float f; unsigned u; } v; v.f = f;
  unsigned r = (v.u + 0x7FFF + ((v.u >> 16) & 1)) >> 16;  // RNE
  return (short)r;
}
__device__ inline float bf2f(short s) {
  union { unsigned u; float f; } v; v.u = ((unsigned)(unsigned short)s) << 16;
  return v.f;
}

// ---------------- W_in -> transposed fp32 [NPAD][DM] (LDS tile transpose) ------
__global__ __launch_bounds__(256) void prep_wtT(const float* __restrict__ W_in,
                                                float* __restrict__ WtT) {
  __shared__ float tile[64][65];
  const int n0 = blockIdx.x * 64;
  const int k0 = blockIdx.y * 64;
  const int tx = threadIdx.x & 63, ty = threadIdx.x >> 6;
#pragma unroll
  for (int i = 0; i < 16; ++i) {
    const int r = ty * 16 + i;
    const int n = n0 + tx;
    tile[r][tx] = (n < DPROJ) ? W_in[(size_t)(k0 + r) * DPROJ + n] : 0.f;
  }
  __syncthreads();
#pragma unroll
  for (int i = 0; i < 16; ++i) {
    const int r = ty * 16 + i;
    WtT[(size_t)(n0 + r) * DM + k0 + tx] = tile[tx][r];
  }
}

// ---------------- Bmx [DM][KF]: cols 0-79 = Wp_in^T, col 80 = bp_in ------------
__global__ void prep_bmx(const float* __restrict__ Wp_in, const float* __restrict__ bp_in,
                         float* __restrict__ Bmx) {
  const int idx = blockIdx.x * 256 + threadIdx.x;
  if (idx >= DM * KF) return;
  const int m = idx / KF, k = idx % KF;
  float v = 0.f;
  if (k < DIN) v = Wp_in[(size_t)k * DM + m];
  else if (k == DIN) v = bp_in[m];
  Bmx[idx] = v;
}

// ---------------- xpad bf16 [BL][KF]: x cols + 1.0 bias col --------------------
__global__ void prep_xpad(const float* __restrict__ x, short* __restrict__ xpad) {
  const int idx = blockIdx.x * 256 + threadIdx.x;
  if (idx >= BL * KF) return;
  const int r = idx / KF, k = idx % KF;
  float v = 0.f;
  if (k < DIN) v = x[(size_t)r * DIN + k];
  else if (k == DIN) v = 1.f;
  xpad[idx] = f2bf(v);
}

// ------- skinny GEMM split-K (fp32 A): part[sk][M][NCOLS] ----------------------
template <int NCOLS>
__global__ __launch_bounds__(256) void gemm_skinny_splitk(
    const float* __restrict__ A, const float* __restrict__ Bm,
    float* __restrict__ part, int Astride, int Mtotal) {
  __shared__ float As[64][65];
  __shared__ float Bs[64][NCOLS];
  constexpr int CPT = NCOLS / 16;
  const int tid = threadIdx.x;
  const int m0 = blockIdx.x * 64;
  const int k0 = blockIdx.y * 64;
  {
    const int r = tid >> 2, q = tid & 3;
#pragma unroll
    for (int j = 0; j < 4; ++j) {
      const int col = q * 16 + j * 4;
      float4 v = *(const float4*)(A + (size_t)(m0 + r) * Astride + k0 + col);
      As[r][col + 0] = v.x; As[r][col + 1] = v.y;
      As[r][col + 2] = v.z; As[r][col + 3] = v.w;
    }
#pragma unroll
    for (int j = 0; j < CPT; ++j) {
      const int col = (q * CPT + j) * 4;
      float4 v = *(const float4*)(Bm + (size_t)(k0 + r) * NCOLS + col);
      *(float4*)&Bs[r][col] = v;
    }
  }
  __syncthreads();
  const int r0 = (tid >> 4) * 4;
  const int n0 = (tid & 15) * CPT;
  float acc[4][CPT] = {};
  for (int k = 0; k < 64; ++k) {
    float a[4];
#pragma unroll
    for (int i = 0; i < 4; ++i) a[i] = As[r0 + i][k];
#pragma unroll
    for (int j = 0; j < CPT; ++j) {
      const float bv = Bs[k][n0 + j];
#pragma unroll
      for (int i = 0; i < 4; ++i) acc[i][j] = fmaf(a[i], bv, acc[i][j]);
    }
  }
#pragma unroll
  for (int i = 0; i < 4; ++i) {
    float* o = part + ((size_t)blockIdx.y * Mtotal + m0 + r0 + i) * NCOLS + n0;
#pragma unroll
    for (int j = 0; j < CPT; ++j) o[j] = acc[i][j];
  }
}

// ------- skinny GEMM split-K (bf16 A, KPB k-tiles per block) -------------------
template <int NCOLS, int KPB>
__global__ __launch_bounds__(256) void gemm_skinny_splitk_b(
    const short* __restrict__ A, const float* __restrict__ Bm,
    float* __restrict__ part, int Astride, int Mtotal) {
  __shared__ float As[64][65];
  __shared__ float Bs[64][NCOLS];
  constexpr int CPT = NCOLS / 16;
  const int tid = threadIdx.x;
  const int m0 = blockIdx.x * 64;
  const int r0 = (tid >> 4) * 4;
  const int n0 = (tid & 15) * CPT;
  float acc[4][CPT] = {};
  for (int kt = 0; kt < KPB; ++kt) {
    const int k0 = (blockIdx.y * KPB + kt) * 64;
    {
      const int r = tid >> 2, q = tid & 3;
#pragma unroll
      for (int j = 0; j < 4; ++j) {
        const int col = q * 16 + j * 4;
        s16x4 v = *(const s16x4*)(A + (size_t)(m0 + r) * Astride + k0 + col);
        As[r][col + 0] = bf2f(v[0]); As[r][col + 1] = bf2f(v[1]);
        As[r][col + 2] = bf2f(v[2]); As[r][col + 3] = bf2f(v[3]);
      }
#pragma unroll
      for (int j = 0; j < CPT; ++j) {
        const int col = (q * CPT + j) * 4;
        float4 v = *(const float4*)(Bm + (size_t)(k0 + r) * NCOLS + col);
        *(float4*)&Bs[r][col] = v;
      }
    }
    __syncthreads();
    for (int k = 0; k < 64; ++k) {
      float a[4];
#pragma unroll
      for (int i = 0; i < 4; ++i) a[i] = As[r0 + i][k];
#pragma unroll
      for (int j = 0; j < CPT; ++j) {
        const float bv = Bs[k][n0 + j];
#pragma unroll
        for (int i = 0; i < 4; ++i) acc[i][j] = fmaf(a[i], bv, acc[i][j]);
      }
    }
    __syncthreads();
  }
#pragma unroll
  for (int i = 0; i < 4; ++i) {
    float* o = part + ((size_t)blockIdx.y * Mtotal + m0 + r0 + i) * NCOLS + n0;
#pragma unroll
    for (int j = 0; j < CPT; ++j) o[j] = acc[i][j];
  }
}

__global__ __launch_bounds__(256) void reduce_splitk(
    const float* __restrict__ part, const float* __restrict__ bias,
    float* __restrict__ out, int total, int nsl, int ncols) {
  const int idx = blockIdx.x * 256 + threadIdx.x;
  if (idx >= total) return;
  float acc = bias ? bias[idx % ncols] : 0.f;
  for (int s = 0; s < nsl; ++s) acc += part[(size_t)s * total + idx];
  out[idx] = acc;
}

__global__ __launch_bounds__(256) void reduce_bf16(
    const float* __restrict__ part, short* __restrict__ out, int total, int nsl) {
  const int idx = blockIdx.x * 256 + threadIdx.x;
  if (idx >= total) return;
  float acc = 0.f;
  for (int s = 0; s < nsl; ++s) acc += part[(size_t)s * total + idx];
  out[idx] = f2bf(acc);
}

// ---------------- bf16 MFMA GEMM -> bf16 C: C = A * Bt^T + bias ----------------
__global__ __launch_bounds__(256) void gemm_mfma_bt(
    const short* __restrict__ A, const short* __restrict__ Bt,
    const float* __restrict__ bias, short* __restrict__ C,
    int M, int N, int K) {
  __shared__ short As[4 * 128 * 8];
  __shared__ short Bs[4 * 128 * 8];
  const int tid = threadIdx.x;
  const int l = tid & 63;
  const int wv = tid >> 6;
  const int wr = wv >> 1, wc = wv & 1;
  const int m0 = blockIdx.x * 128;
  const int n0 = blockIdx.y * 128;
  const int ks = l >> 4, lr = l & 15;
  f32x4 acc[4][4] = {};
  for (int k0 = 0; k0 < K; k0 += 32) {
#pragma unroll
    for (int i = 0; i < 2; ++i) {
      const int t = (wv * 2 + i) * 64 + l;
      const int tks = t >> 7, trow = t & 127;
      __builtin_amdgcn_global_load_lds(
          (const __attribute__((address_space(1))) unsigned int*)(A + (size_t)(m0 + trow) * K + k0 + tks * 8),
          (__attribute__((address_space(3))) unsigned int*)(As + (size_t)(wv * 2 + i) * 512),
          16, 0, 0);
      __builtin_amdgcn_global_load_lds(
          (const __attribute__((address_space(1))) unsigned int*)(Bt + (size_t)(n0 + trow) * K + k0 + tks * 8),
          (__attribute__((address_space(3))) unsigned int*)(Bs + (size_t)(wv * 2 + i) * 512),
          16, 0, 0);
    }
    __syncthreads();
    bf16x8 af[4], bfr[4];
#pragma unroll
    for (int mi = 0; mi < 4; ++mi)
      af[mi] = *(const bf16x8*)&As[(size_t)(ks * 128 + wr * 64 + mi * 16 + lr) * 8];
#pragma unroll
    for (int ni = 0; ni < 4; ++ni)
      bfr[ni] = *(const bf16x8*)&Bs[(size_t)(ks * 128 + wc * 64 + ni * 16 + lr) * 8];
#pragma unroll
    for (int mi = 0; mi < 4; ++mi)
#pragma unroll
      for (int ni = 0; ni < 4; ++ni)
        acc[mi][ni] = __builtin_amdgcn_mfma_f32_16x16x32_bf16(af[mi], bfr[ni], acc[mi][ni], 0, 0, 0);
    __syncthreads();
  }
#pragma unroll
  for (int mi = 0; mi < 4; ++mi) {
    const int row = m0 + wr * 64 + mi * 16 + (l >> 4) * 4;
#pragma unroll
    for (int ni = 0; ni < 4; ++ni) {
      const int col = n0 + wc * 64 + ni * 16 + lr;
      if (col < N) {
        const float bv = bias[col];
#pragma unroll
        for (int r = 0; r < 4; ++r)
          C[(size_t)(row + r) * N + col] = f2bf(acc[mi][ni][r] + bv);
      }
    }
  }
}

// ---------------- dt / log(dA) ----------------
__global__ void prep_dt(const short* __restrict__ zx, const float* __restrict__ dt_bias,
                        const float* __restrict__ A_log, float* __restrict__ dtb,
                        float* __restrict__ ldab) {
  const int idx = blockIdx.x * 256 + threadIdx.x;
  if (idx >= 2 * BL * NH) return;
  const int h = idx % NH;
  int rest = idx / NH;
  const int s = rest % L;
  rest /= L;
  const int bb = rest % B;
  const int d = rest / B;
  const int torig = d ? (L - 1 - s) : s;
  const float raw = bf2f(zx[((size_t)(bb * L + torig)) * DPROJ + DI + CONVC + h]) + dt_bias[h];
  const float dt = (raw > 20.f) ? raw : log1pf(expf(raw));
  dtb[idx] = dt;
  ldab[idx] = -expf(A_log[h]) * dt;   // log(dA), always <= 0
}

// ------- conv both dirs + silu -> bf16 xconv; bf16 LDS window (11.25 KB) -------
__global__ __launch_bounds__(128) void prep_conv3(
    const short* __restrict__ zx, const float* __restrict__ cw,
    const float* __restrict__ cb, short* __restrict__ xconv) {
  __shared__ short Z[TSEG + 12][128];
  const int tid = threadIdx.x;
  const int c = blockIdx.x * 128 + tid;   // 0..1151
  const int b = blockIdx.z;
  const int t0 = blockIdx.y * TSEG;
  const short* src = zx + (size_t)b * L * DPROJ + DI + c;
#pragma unroll
  for (int r = 0; r < TSEG + 12; ++r) {
    const int t = t0 - 6 + r;
    short v = 0;
    if (t >= 0 && t < L) v = src[(size_t)t * DPROJ];
    Z[r][tid] = v;
  }
  const float wt0 = cw[c * KC + 0], wt1 = cw[c * KC + 1], wt2 = cw[c * KC + 2],
              wt3 = cw[c * KC + 3], wt4 = cw[c * KC + 4], wt5 = cw[c * KC + 5],
              wt6 = cw[c * KC + 6];
  const float bias = cb[c];
  short* dstF = xconv + (size_t)b * L * CONVC + c;
  short* dstB = xconv + (size_t)(B + b) * L * CONVC + c;
  __syncthreads();
#pragma unroll 4
  for (int i = 0; i < TSEG; ++i) {
    const int t = t0 + i;
    float af = bias + wt0 * bf2f(Z[i + 0][tid]) + wt1 * bf2f(Z[i + 1][tid]) +
               wt2 * bf2f(Z[i + 2][tid]) + wt3 * bf2f(Z[i + 3][tid]) +
               wt4 * bf2f(Z[i + 4][tid]) + wt5 * bf2f(Z[i + 5][tid]) +
               wt6 * bf2f(Z[i + 6][tid]);
    float ab = bias + wt6 * bf2f(Z[i + 6][tid]) + wt5 * bf2f(Z[i + 7][tid]) +
               wt4 * bf2f(Z[i + 8][tid]) + wt3 * bf2f(Z[i + 9][tid]) +
               wt2 * bf2f(Z[i + 10][tid]) + wt1 * bf2f(Z[i + 11][tid]) +
               wt0 * bf2f(Z[i + 12][tid]);
    dstF[(size_t)t * CONVC] = f2bf(af / (1.f + expf(-af)));
    dstB[(size_t)(L - 1 - t) * CONVC] = f2bf(ab / (1.f + expf(-ab)));
  }
}

// ---------------- scanA (+ fused G-prep on hh==0 blocks) -----------------------
__global__ __launch_bounds__(64) void scanA_mfma(
    const short* __restrict__ xconv, const float* __restrict__ dtb,
    const float* __restrict__ ldab, short* __restrict__ Sbuf,
    float* __restrict__ Pbuf, short* __restrict__ G) {
  __shared__ short XT[64 * XTS];
  __shared__ short BT[64 * XTS];
  __shared__ float cumL[64];
  const int g = blockIdx.x, c = blockIdx.y;
  const int l = threadIdx.x, lr = l & 15, lq = l >> 4;
  const int hh = g & 15, db = g >> 4;
  const size_t base_row = (size_t)db * L + c * 64;
  const float dt_l = dtb[(base_row + l) * NH + hh];
  float cum = ldab[(base_row + l) * NH + hh];
#pragma unroll
  for (int off = 1; off < 64; off <<= 1) {
    float t = __shfl_up(cum, off);
    if (l >= off) cum += t;
  }
  cumL[l] = cum;
  const float cumE = __shfl(cum, 63);
  const short* xrow = xconv + (base_row + l) * CONVC + hh * 64;
  const short* brow = xconv + (base_row + l) * CONVC + DI;
#pragma unroll
  for (int q = 0; q < 8; ++q) {
    const bf16x8 xv = *(const bf16x8*)&xrow[q * 8];
    const bf16x8 bv = *(const bf16x8*)&brow[q * 8];
#pragma unroll
    for (int e = 0; e < 8; ++e) {
      XT[(q * 8 + e) * XTS + l] = f2bf(bf2f(xv[e]) * dt_l);
      BT[(q * 8 + e) * XTS + l] = bv[e];
    }
  }
  __syncthreads();
  f32x4 acc[4][4] = {};
#pragma unroll
  for (int ks2 = 0; ks2 < 2; ++ks2) {
    const int j0 = ks2 * 32 + lq * 8;
    const float4 c0 = *(const float4*)&cumL[j0];
    const float4 c1 = *(const float4*)&cumL[j0 + 4];
    float w[8] = {__expf(cumE - c0.x), __expf(cumE - c0.y), __expf(cumE - c0.z), __expf(cumE - c0.w),
                  __expf(cumE - c1.x), __expf(cumE - c1.y), __expf(cumE - c1.z), __expf(cumE - c1.w)};
    bf16x8 pf[4], qf[4];
#pragma unroll
    for (int mi = 0; mi < 4; ++mi) {
      const bf16x8 raw = *(const bf16x8*)&XT[(mi * 16 + lr) * XTS + j0];
#pragma unroll
      for (int jj = 0; jj < 8; ++jj) pf[mi][jj] = f2bf(bf2f(raw[jj]) * w[jj]);
    }
#pragma unroll
    for (int ni = 0; ni < 4; ++ni)
      qf[ni] = *(const bf16x8*)&BT[(ni * 16 + lr) * XTS + j0];
#pragma unroll
    for (int mi = 0; mi < 4; ++mi)
#pragma unroll
      for (int ni = 0; ni < 4; ++ni)
        acc[mi][ni] = __builtin_amdgcn_mfma_f32_16x16x32_bf16(pf[mi], qf[ni], acc[mi][ni], 0, 0, 0);
  }
  short* so = Sbuf + ((size_t)g * NC + c) * 4096;
#pragma unroll
  for (int mi = 0; mi < 4; ++mi)
#pragma unroll
    for (int ni = 0; ni < 4; ++ni)
#pragma unroll
      for (int r = 0; r < 4; ++r)
        so[(mi * 16 + lq * 4 + r) * 64 + ni * 16 + lr] = f2bf(acc[mi][ni][r]);
  if (l == 0) Pbuf[g * NC + c] = __expf(cumE);
  // ---- fused G-prep: one block per (db,c) does it (hh==0) ----
  if (hh == 0) {
    f32x4 gacc[4][4] = {};
#pragma unroll
    for (int ks2 = 0; ks2 < 2; ++ks2) {
      const int n0 = ks2 * 32 + lq * 8;
      bf16x8 pf[4], qf[4];
#pragma unroll
      for (int mi = 0; mi < 4; ++mi)
        pf[mi] = *(const bf16x8*)&xconv[(base_row + mi * 16 + lr) * CONVC + DI + DS + n0];
#pragma unroll
      for (int ni = 0; ni < 4; ++ni)
        qf[ni] = *(const bf16x8*)&xconv[(base_row + ni * 16 + lr) * CONVC + DI + n0];
#pragma unroll
      for (int mi = 0; mi < 4; ++mi)
#pragma unroll
        for (int ni = 0; ni < 4; ++ni)
          gacc[mi][ni] = __builtin_amdgcn_mfma_f32_16x16x32_bf16(pf[mi], qf[ni], gacc[mi][ni], 0, 0, 0);
    }
    short* gout = G + ((size_t)(db * NC + c) << 12);
#pragma unroll
    for (int mi = 0; mi < 4; ++mi)
#pragma unroll
      for (int ni = 0; ni < 4; ++ni)
#pragma unroll
        for (int r = 0; r < 4; ++r)
          gout[(mi * 16 + lq * 4 + r) * 64 + ni * 16 + lr] = f2bf(gacc[mi][ni][r]);
  }
}

// ---------------- chain (bf16 Sbuf, fp32 accumulate) ----------------
__global__ void scan_chain(short* __restrict__ Sbuf, const float* __restrict__ Pbuf) {
  const int idx = blockIdx.x * 256 + threadIdx.x;
  const int g = idx >> 12;
  const int e = idx & 4095;
  float run = 0.f;
  short* base = Sbuf + (size_t)g * NC * 4096 + e;
  for (int c = 0; c < NC; ++c) {
    const float sc = bf2f(base[(size_t)c * 4096]);
    const float pc = Pbuf[g * NC + c];
    base[(size_t)c * 4096] = f2bf(run);
    run = pc * run + sc;
  }
}

// ---------------- scanC -> bf16 yraw ----------------
__global__ __launch_bounds__(64) void scanC_mfma(
    const short* __restrict__ xconv, const float* __restrict__ dtb,
    const float* __restrict__ ldab, const short* __restrict__ G,
    const short* __restrict__ Sbuf, short* __restrict__ yraw) {
  __shared__ short XT[64 * XTS];
  __shared__ float cumL[64];
  const int g = blockIdx.x, c = blockIdx.y;
  const int l = threadIdx.x, lr = l & 15, lq = l >> 4;
  const int hh = g & 15, db = g >> 4;
  const size_t base_row = (size_t)db * L + c * 64;
  const float dt_l = dtb[(base_row + l) * NH + hh];
  float cum = ldab[(base_row + l) * NH + hh];
#pragma unroll
  for (int off = 1; off < 64; off <<= 1) {
    float t = __shfl_up(cum, off);
    if (l >= off) cum += t;
  }
  cumL[l] = cum;
  const short* xrow = xconv + (base_row + l) * CONVC + hh * 64;
#pragma unroll
  for (int q = 0; q < 8; ++q) {
    const bf16x8 xv = *(const bf16x8*)&xrow[q * 8];
#pragma unroll
    for (int e = 0; e < 8; ++e) XT[(q * 8 + e) * XTS + l] = f2bf(bf2f(xv[e]) * dt_l);
  }
  __syncthreads();
  const short* Sin = Sbuf + ((size_t)g * NC + c) * 4096;
  const short* Gp = G + ((size_t)(db * NC + c) << 12);
  float sc[4], ci[4];
#pragma unroll
  for (int mi = 0; mi < 4; ++mi) {
    ci[mi] = cumL[mi * 16 + lr];
    sc[mi] = __expf(ci[mi]);
  }
  f32x4 acc[4][4] = {};
#pragma unroll
  for (int ks2 = 0; ks2 < 2; ++ks2) {
    const int n0 = ks2 * 32 + lq * 8;
    {
      bf16x8 pf[4], qf[4];
#pragma unroll
      for (int mi = 0; mi < 4; ++mi) {
        const bf16x8 cv = *(const bf16x8*)&xconv[(base_row + mi * 16 + lr) * CONVC + DI + DS + n0];
#pragma unroll
        for (int e = 0; e < 8; ++e) pf[mi][e] = f2bf(bf2f(cv[e]) * sc[mi]);
      }
#pragma unroll
      for (int ni = 0; ni < 4; ++ni)
        qf[ni] = *(const bf16x8*)&Sin[(ni * 16 + lr) * 64 + n0];
#pragma unroll
      for (int mi = 0; mi < 4; ++mi)
#pragma unroll
        for (int ni = 0; ni < 4; ++ni)
          acc[mi][ni] = __builtin_amdgcn_mfma_f32_16x16x32_bf16(pf[mi], qf[ni], acc[mi][ni], 0, 0, 0);
    }
    {
      const float4 c0 = *(const float4*)&cumL[n0];
      const float4 c1 = *(const float4*)&cumL[n0 + 4];
      const float cj[8] = {c0.x, c0.y, c0.z, c0.w, c1.x, c1.y, c1.z, c1.w};
      bf16x8 pf[4], qf[4];
#pragma unroll
      for (int mi = 0; mi < 4; ++mi) {
        const int i = mi * 16 + lr;
        const bf16x8 gv = *(const bf16x8*)&Gp[i * 64 + n0];
#pragma unroll
        for (int jj = 0; jj < 8; ++jj) {
          const float m = (n0 + jj <= i) ? __expf(ci[mi] - cj[jj]) : 0.f;
          pf[mi][jj] = f2bf(bf2f(gv[jj]) * m);
        }
      }
#pragma unroll
      for (int ni = 0; ni < 4; ++ni)
        qf[ni] = *(const bf16x8*)&XT[(ni * 16 + lr) * XTS + n0];
#pragma unroll
      for (int mi = 0; mi < 4; ++mi)
#pragma unroll
        for (int ni = 0; ni < 4; ++ni)
          acc[mi][ni] = __builtin_amdgcn_mfma_f32_16x16x32_bf16(pf[mi], qf[ni], acc[mi][ni], 0, 0, 0);
    }
  }
#pragma unroll
  for (int mi = 0; mi < 4; ++mi)
#pragma unroll
    for (int ni = 0; ni < 4; ++ni)
#pragma unroll
      for (int r = 0; r < 4; ++r)
        yraw[(base_row + mi * 16 + lq * 4 + r) * DI + hh * 64 + ni * 16 + lr] = f2bf(acc[mi][ni][r]);
}

// ---------------- gate + D*x + RMSNorm + combine -> bf16 ycomb -----------------
__global__ __launch_bounds__(256) void gate_norm(
    const short* __restrict__ zx, const short* __restrict__ yraw,
    const short* __restrict__ xconv, const float* __restrict__ Dpar,
    const float* __restrict__ nw, short* __restrict__ ycomb) {
  const int bt = blockIdx.x;
  const int b = bt / L, t = bt % L;
  const int tid = threadIdx.x;
  const int c0 = tid * 4;
  const float dp = Dpar[c0 >> 6];
  const s16x4 zv4 = *(const s16x4*)&zx[(size_t)bt * DPROJ + c0];
  const s16x4 y04 = *(const s16x4*)&yraw[((size_t)b * L + t) * DI + c0];
  const s16x4 y14 = *(const s16x4*)&yraw[((size_t)(B + b) * L + (L - 1 - t)) * DI + c0];
  const s16x4 x04 = *(const s16x4*)&xconv[((size_t)b * L + t) * CONVC + c0];
  const s16x4 x14 = *(const s16x4*)&xconv[((size_t)(B + b) * L + (L - 1 - t)) * CONVC + c0];
  float a0[4], a1[4];
  float s0 = 0.f, s1 = 0.f;
#pragma unroll
  for (int r = 0; r < 4; ++r) {
    const float zv = bf2f(zv4[r]);
    const float gz = zv / (1.f + expf(-zv));
    a0[r] = (bf2f(y04[r]) + dp * bf2f(x04[r])) * gz;
    a1[r] = (bf2f(y14[r]) + dp * bf2f(x14[r])) * gz;
    s0 += a0[r] * a0[r];
    s1 += a1[r] * a1[r];
  }
#pragma unroll
  for (int off = 32; off > 0; off >>= 1) {
    s0 += __shfl_down(s0, off);
    s1 += __shfl_down(s1, off);
  }
  __shared__ float rs0[4], rs1[4];
  const int w = tid >> 6;
  if ((tid & 63) == 0) { rs0[w] = s0; rs1[w] = s1; }
  __syncthreads();
  s0 = rs0[0] + rs0[1] + rs0[2] + rs0[3];
  s1 = rs1[0] + rs1[1] + rs1[2] + rs1[3];
  const float r0 = rsqrtf(s0 * (1.f / DI) + 1e-5f);
  const float r1 = rsqrtf(s1 * (1.f / DI) + 1e-5f);
  s16x4 o;
  o[0] = f2bf(nw[c0 + 0] * (a0[0] * r0 + a1[0] * r1));
  o[1] = f2bf(nw[c0 + 1] * (a0[1] * r0 + a1[1] * r1));
  o[2] = f2bf(nw[c0 + 2] * (a0[2] * r0 + a1[2] * r1));
  o[3] = f2bf(nw[c0 + 3] * (a0[3] * r0 + a1[3] * r1));
  *(s16x4*)&ycomb[(size_t)bt * DI + c0] = o;
}

extern "C" void kernel_launch(void* const* d_in, const int* in_sizes, int n_in,
                              void* d_out, int out_size, void* d_ws, size_t ws_size,
                              hipStream_t stream) {
  const float* x       = (const float*)d_in[0];
  const float* Wp_in   = (const float*)d_in[1];
  const float* bp_in   = (const float*)d_in[2];
  const float* W_in    = (const float*)d_in[3];
  const float* b_in    = (const float*)d_in[4];
  const float* conv_w  = (const float*)d_in[5];
  const float* conv_b  = (const float*)d_in[6];
  const float* dt_bias = (const float*)d_in[7];
  const float* A_log   = (const float*)d_in[8];
  const float* Dpar    = (const float*)d_in[9];
  const float* norm_w  = (const float*)d_in[10];
  const float* W_out   = (const float*)d_in[11];
  const float* Wp_out  = (const float*)d_in[12];
  const float* bp_out  = (const float*)d_in[13];
  float* out = (float*)d_out;

  char* p = (char*)d_ws;
  short* zx    = (short*)p; p += (size_t)BL * DPROJ * 2;
  short* xconv = (short*)p; p += (size_t)2 * BL * CONVC * 2;
  float* dtb   = (float*)p; p += (size_t)2 * BL * NH * 4;
  float* ldab  = (float*)p; p += (size_t)2 * BL * NH * 4;
  short* Sbuf  = (short*)p; p += (size_t)NG * NC * HD * DS * 2;
  float* Pbuf  = (float*)p; p += (size_t)NG * NC * 4;
  short* yraw  = (short*)p; p += (size_t)2 * BL * DI * 2;
  short* ycomb = (short*)p; p += (size_t)BL * DI * 2;
  float* Wc    = (float*)p; p += (size_t)DI * DIN * 4;
  short* G     = (short*)p; p += (size_t)2 * B * NC * 64 * 64 * 2;
  float* WtT   = (float*)p; p += (size_t)NPAD * DM * 4;
  float* Bmx   = (float*)p; p += (size_t)DM * KF * 4;
  short* WtF   = (short*)p; p += (size_t)NPAD * KF * 2;
  short* xpad  = (short*)p; p += (size_t)BL * KF * 2;
  float* partW = (float*)p; p += (size_t)KSPLITW * NPAD * KF * 4;
  float* part2 = (float*)p; p += (size_t)KSPLIT2 * DI * DIN * 4;
  float* part  = (float*)p; p += (size_t)KSPLITF * BL * DIN * 4;
  (void)ws_size; (void)in_sizes; (void)n_in; (void)out_size;

  // 0. fold input projection: WtF = ((Wp_in@W_in) with bp_in col)^T, bf16
  prep_wtT<<<dim3(NPAD / 64, DM / 64), 256, 0, stream>>>(W_in, WtT);
  prep_bmx<<<(DM * KF + 255) / 256, 256, 0, stream>>>(Wp_in, bp_in, Bmx);
  gemm_skinny_splitk<KF><<<dim3(NPAD / 64, KSPLITW), 256, 0, stream>>>(
      WtT, Bmx, partW, DM, NPAD);
  reduce_bf16<<<(NPAD * KF + 255) / 256, 256, 0, stream>>>(partW, WtF, NPAD * KF, KSPLITW);
  prep_xpad<<<(BL * KF + 255) / 256, 256, 0, stream>>>(x, xpad);
  // 1. zxbcdt = xpad @ WtF^T + b_in (bf16 MFMA, K=96)
  gemm_mfma_bt<<<dim3(BL / 128, NPAD / 128), 256, 0, stream>>>(
      xpad, WtF, b_in, zx, BL, DPROJ, KF);
  // 2. dt/log-dA; conv + silu
  prep_dt<<<(2 * BL * NH + 255) / 256, 256, 0, stream>>>(zx, dt_bias, A_log, dtb, ldab);
  prep_conv3<<<dim3(CONVC / 128, L / TSEG, B), 128, 0, stream>>>(zx, conv_w, conv_b, xconv);
  // 3. chunked scan via MFMA (G fused into scanA)
  scanA_mfma<<<dim3(NG, NC), 64, 0, stream>>>(xconv, dtb, ldab, Sbuf, Pbuf, G);
  scan_chain<<<(NG * HD * DS) / 256, 256, 0, stream>>>(Sbuf, Pbuf);
  scanC_mfma<<<dim3(NG, NC), 64, 0, stream>>>(xconv, dtb, ldab, G, Sbuf, yraw);
  // 4. gate + D*x + RMSNorm + combine -> bf16
  gate_norm<<<BL, 256, 0, stream>>>(zx, yraw, xconv, Dpar, norm_w, ycomb);
  // 5. Wc = W_out @ Wp_out (split-K)
  gemm_skinny_splitk<DIN><<<dim3(DI / 64, KSPLIT2), 256, 0, stream>>>(W_out, Wp_out, part2, DM, DI);
  reduce_splitk<<<(DI * DIN + 255) / 256, 256, 0, stream>>>(part2, nullptr, Wc, DI * DIN, KSPLIT2, DIN);
  // 6. out = ycomb @ Wc + bp_out (bf16 A, split-K 8 x 2 tiles)
  gemm_skinny_splitk_b<DIN, 2><<<dim3(BL / 64, KSPLITF), 256, 0, stream>>>(
      ycomb, Wc, part, DI, BL);
  reduce_splitk<<<(BL * DIN + 255) / 256, 256, 0, stream>>>(part, bp_out, out, BL * DIN, KSPLITF, DIN);
}